// Round 1
// baseline (5669.403 us; speedup 1.0000x reference)
//
#include <hip/hip_runtime.h>
#include <math.h>

#define BB 64
#define TT 256
#define NNODE 21
#define HID 128
#define DMODEL 256
#define DINNER 512
#define NSIGNS 2000
#define BTT (BB*TT)   // 16384

__device__ __forceinline__ float softplusf(float x){ return fmaxf(x,0.f) + log1pf(expf(-fabsf(x))); }
__device__ __forceinline__ float siluf(float x){ return x/(1.f+expf(-x)); }

// ---------- prep: transpose w_gat (4,128,32) -> Bp[i][h*32+o] ----------
__global__ void prep_wgat_kernel(const float* __restrict__ wg, float* __restrict__ bp){
  int idx = blockIdx.x*256 + threadIdx.x;           // 16384
  int i = idx >> 7, ho = idx & 127;
  bp[idx] = wg[(((ho>>5)*128) + i)*32 + (ho&31)];
}
// ---------- prep: pdm_w (4,256,64) -> Wbig[d][k*64+c] ----------
__global__ void prep_pdmw_kernel(const float* __restrict__ pw, float* __restrict__ wb){
  int idx = blockIdx.x*256 + threadIdx.x;           // 65536
  int d = idx >> 8, kc = idx & 255;
  wb[idx] = pw[(((kc>>6)*256) + d)*64 + (kc&63)];
}

// ---------- AGAN: per (b,t) graph attention; writes featsum*(1/21) [BT,128] ----------
__global__ __launch_bounds__(256) void agan_kernel(
    const float* __restrict__ x, const float* __restrict__ w_in, const float* __restrict__ b_in,
    const float* __restrict__ bp, const float* __restrict__ a_src, const float* __restrict__ a_dst,
    float* __restrict__ fsum_out)
{
  int bt = blockIdx.x;
  int tid = threadIdx.x;
  __shared__ float xv[NNODE][4];
  __shared__ __align__(16) float h0s[NNODE][HID];
  __shared__ __align__(16) float hms[NNODE][HID];
  __shared__ float sd[2][NNODE][4];
  __shared__ float al[4][NNODE][NNODE];
  if (tid < NNODE*3) xv[tid/3][tid%3] = x[(size_t)bt*(NNODE*3) + tid];
  __syncthreads();
  for (int idx = tid; idx < NNODE*HID; idx += 256) {
    int n = idx >> 7, i = idx & 127;
    float v = b_in[i] + xv[n][0]*w_in[i] + xv[n][1]*w_in[HID+i] + xv[n][2]*w_in[2*HID+i];
    h0s[n][i] = fmaxf(v, 0.f);
  }
  __syncthreads();
  // hm = h0 @ Bp (Bp = reshaped w_gat, [128][128])
  {
    int ho = tid & 127;
    int half = tid >> 7;
    int n0 = half * 11;
    int cnt = half ? 10 : 11;
    float acc[11];
    #pragma unroll
    for (int j=0;j<11;++j) acc[j]=0.f;
    for (int i=0;i<HID;i+=4) {
      float b0 = bp[(i+0)*128 + ho];
      float b1 = bp[(i+1)*128 + ho];
      float b2 = bp[(i+2)*128 + ho];
      float b3 = bp[(i+3)*128 + ho];
      #pragma unroll
      for (int j=0;j<11;++j) {
        if (j < cnt) {
          float4 hv = *(const float4*)&h0s[n0+j][i];
          acc[j] += hv.x*b0 + hv.y*b1 + hv.z*b2 + hv.w*b3;
        }
      }
    }
    for (int j=0;j<cnt;++j) hms[n0+j][ho] = acc[j];
  }
  __syncthreads();
  // src/dst  (rotate o by lane to avoid 64-way LDS bank conflicts)
  if (tid < 2*NNODE*4) {
    int which = tid >= 84 ? 1 : 0;
    int r = tid - which*84;
    int n = r >> 2, h = r & 3;
    const float* av = (which ? a_dst : a_src) + h*32;
    const float* hr = &hms[n][h*32];
    float s = 0.f;
    #pragma unroll
    for (int o=0;o<32;++o) { int oo = (o + tid) & 31; s += hr[oo]*av[oo]; }
    sd[which][n][h] = s;
  }
  __syncthreads();
  // alpha = softmax_j(leaky_relu(src_i + dst_j))
  if (tid < 84) {
    int i = tid >> 2, h = tid & 3;
    float sv = sd[0][i][h];
    float ev[NNODE]; float m = -1e30f;
    #pragma unroll
    for (int j=0;j<NNODE;++j) {
      float e = sv + sd[1][j][h];
      e = (e >= 0.f) ? e : 0.2f*e;
      ev[j] = e; m = fmaxf(m, e);
    }
    float ss = 0.f;
    #pragma unroll
    for (int j=0;j<NNODE;++j){ float ex = expf(ev[j]-m); ev[j]=ex; ss+=ex; }
    float inv = 1.f/ss;
    #pragma unroll
    for (int j=0;j<NNODE;++j) al[h][i][j] = ev[j]*inv;
  }
  __syncthreads();
  // agg + relu(h0+agg)  (feat overwrites h0s)
  for (int idx = tid; idx < NNODE*HID; idx += 256) {
    int n = idx >> 7, ho = idx & 127, h = ho >> 5;
    float s = 0.f;
    #pragma unroll
    for (int j=0;j<NNODE;++j) s += al[h][n][j]*hms[j][ho];
    h0s[n][ho] = fmaxf(h0s[n][ho] + s, 0.f);
  }
  __syncthreads();
  if (tid < HID) {
    float s = 0.f;
    #pragma unroll
    for (int n=0;n<NNODE;++n) s += h0s[n][tid];
    fsum_out[(size_t)bt*HID + tid] = s * (1.f/21.f);
  }
}

// ---------- generic tiled fp32 GEMM: C[M,N] (+)= A[M,K]@B[K,N] (+bias)(relu) ----------
template<int ACC, int BIAS, int RELU>
__global__ __launch_bounds__(256) void gemm_kernel(const float* __restrict__ A,
    const float* __restrict__ B, const float* __restrict__ bias,
    float* __restrict__ C, int M, int N, int K)
{
  __shared__ __align__(16) float As[16][68];
  __shared__ __align__(16) float Bs[16][68];
  int tid = threadIdx.x;
  int tx = tid & 15, ty = tid >> 4;
  int row0 = blockIdx.y*64, col0 = blockIdx.x*64;
  int ar = tid >> 2, ac = (tid & 3)*4;
  int br = tid >> 4, bc = (tid & 15)*4;
  float acc[4][4] = {};
  for (int k0 = 0; k0 < K; k0 += 16) {
    float4 a4 = *(const float4*)(A + (size_t)(row0+ar)*K + k0 + ac);
    float4 b4 = make_float4(0.f,0.f,0.f,0.f);
    if (col0 + bc < N) b4 = *(const float4*)(B + (size_t)(k0+br)*N + col0 + bc);
    __syncthreads();
    As[ac+0][ar]=a4.x; As[ac+1][ar]=a4.y; As[ac+2][ar]=a4.z; As[ac+3][ar]=a4.w;
    *(float4*)&Bs[br][bc] = b4;
    __syncthreads();
    #pragma unroll
    for (int kk=0;kk<16;++kk) {
      float4 av = *(const float4*)&As[kk][ty*4];
      float4 bv = *(const float4*)&Bs[kk][tx*4];
      acc[0][0]+=av.x*bv.x; acc[0][1]+=av.x*bv.y; acc[0][2]+=av.x*bv.z; acc[0][3]+=av.x*bv.w;
      acc[1][0]+=av.y*bv.x; acc[1][1]+=av.y*bv.y; acc[1][2]+=av.y*bv.z; acc[1][3]+=av.y*bv.w;
      acc[2][0]+=av.z*bv.x; acc[2][1]+=av.z*bv.y; acc[2][2]+=av.z*bv.z; acc[2][3]+=av.z*bv.w;
      acc[3][0]+=av.w*bv.x; acc[3][1]+=av.w*bv.y; acc[3][2]+=av.w*bv.z; acc[3][3]+=av.w*bv.w;
    }
  }
  #pragma unroll
  for (int i=0;i<4;++i) {
    int row = row0 + ty*4 + i;
    #pragma unroll
    for (int j=0;j<4;++j) {
      int col = col0 + tx*4 + j;
      if (col < N) {
        float v = acc[i][j];
        if (BIAS) v += bias[col];
        if (RELU) v = fmaxf(v, 0.f);
        size_t o = (size_t)row*N + col;
        if (ACC) C[o] += v; else C[o] = v;
      }
    }
  }
}

// ---------- LayerNorm (per 256-row), one wave per row ----------
__global__ __launch_bounds__(256) void ln_kernel(const float* __restrict__ x,
    const float* __restrict__ w, float* __restrict__ o)
{
  int row = blockIdx.x*4 + (threadIdx.x>>6);
  int lane = threadIdx.x & 63;
  float4 v = *(const float4*)(x + (size_t)row*DMODEL + lane*4);
  float s = v.x+v.y+v.z+v.w;
  #pragma unroll
  for (int off=32;off>=1;off>>=1) s += __shfl_xor(s, off);
  float mu = s * (1.f/256.f);
  float d0=v.x-mu, d1=v.y-mu, d2=v.z-mu, d3=v.w-mu;
  float q = d0*d0+d1*d1+d2*d2+d3*d3;
  #pragma unroll
  for (int off=32;off>=1;off>>=1) q += __shfl_xor(q, off);
  float inv = 1.f/sqrtf(q*(1.f/256.f) + 1e-5f);
  float4 wv = *(const float4*)(w + lane*4);
  float4 r; r.x=d0*inv*wv.x; r.y=d1*inv*wv.y; r.z=d2*inv*wv.z; r.w=d3*inv*wv.w;
  *(float4*)(o + (size_t)row*DMODEL + lane*4) = r;
}

// ---------- causal/anticausal depthwise conv + silu ----------
__global__ __launch_bounds__(256) void conv_kernel(const float* __restrict__ xz,
    const float* __restrict__ cw, const float* __restrict__ cb,
    float* __restrict__ ucv, int dir)
{
  int idx = blockIdx.x*256 + threadIdx.x;          // BT*512
  int dd = idx & 511;
  int bt = idx >> 9;
  int t = bt & 255;
  const float* up = xz + (size_t)(bt - t)*1024 + dd;  // u at t=0 of this b
  float s = cb[dd];
  if (dir == 0) {
    #pragma unroll
    for (int k=0;k<4;++k) { int tk = t-3+k; if (tk >= 0) s += cw[dd*4+k]*up[(size_t)tk*1024]; }
  } else {
    #pragma unroll
    for (int j=0;j<4;++j) { int tk = t+j; if (tk < TT) s += cw[dd*4+3-j]*up[(size_t)tk*1024]; }
  }
  ucv[idx] = siluf(s);
}

// ---------- selective scan (fused dt-proj + softplus + silu(z) gate) ----------
// one wave per (b, 64-channel chunk); 16-step windows double-buffered in LDS
__global__ __launch_bounds__(64) void scan_kernel(
    const float* __restrict__ ucv, const float* __restrict__ xdbl, const float* __restrict__ xz,
    const float* __restrict__ dtw, const float* __restrict__ dtb,
    const float* __restrict__ alog, const float* __restrict__ dvec,
    float* __restrict__ yout, int dir)
{
  int b = blockIdx.x;
  int lane = threadIdx.x;
  int dd = blockIdx.y*64 + lane;
  float wdt[16], Av[16], h[16];
  #pragma unroll
  for (int s=0;s<16;++s){ wdt[s]=dtw[s*DINNER+dd]; Av[s]=-expf(alog[dd*16+s]); h[s]=0.f; }
  float bdt = dtb[dd], Dv = dvec[dd];
  __shared__ float sxd[2][16][48];
  __shared__ float su[2][16][64];
  __shared__ float sz[2][16][64];
  int t0 = dir ? TT-1 : 0;
  int stp = dir ? -1 : 1;
  #pragma unroll
  for (int q=0;q<16;++q) {
    size_t bt = (size_t)b*TT + (t0 + stp*q);
    if (lane < 48) sxd[0][q][lane] = xdbl[bt*48 + lane];
    su[0][q][lane] = ucv[bt*DINNER + dd];
    sz[0][q][lane] = xz[bt*1024 + DINNER + dd];
  }
  int buf = 0;
  for (int w = 0; w < 16; ++w) {
    __syncthreads();
    if (w+1 < 16) {
      #pragma unroll
      for (int q=0;q<16;++q) {
        size_t bt = (size_t)b*TT + (t0 + stp*((w+1)*16 + q));
        if (lane < 48) sxd[buf^1][q][lane] = xdbl[bt*48 + lane];
        su[buf^1][q][lane] = ucv[bt*DINNER + dd];
        sz[buf^1][q][lane] = xz[bt*1024 + DINNER + dd];
      }
    }
    #pragma unroll 1
    for (int q=0;q<16;++q) {
      const float* s48 = sxd[buf][q];
      float uc = su[buf][q][lane], zc = sz[buf][q][lane];
      float dtp = bdt;
      #pragma unroll
      for (int r=0;r<16;++r) dtp += s48[r]*wdt[r];
      float dt = softplusf(dtp);
      float dtu = dt*uc;
      float y = 0.f;
      #pragma unroll
      for (int s=0;s<16;++s) {
        float dA = expf(dt*Av[s]);
        h[s] = dA*h[s] + dtu*s48[16+s];
        y += h[s]*s48[32+s];
      }
      int t = t0 + stp*(w*16+q);
      yout[((size_t)b*TT+t)*DINNER + dd] = (y + uc*Dv)*siluf(zc);
    }
    buf ^= 1;
  }
}

// ---------- heads ----------
__global__ __launch_bounds__(256) void head_emb_kernel(const float* __restrict__ xx,
    const float* __restrict__ wsgn, const float* __restrict__ bsgn,
    float* __restrict__ embw, float* __restrict__ out_emb)
{
  int b = blockIdx.x, tid = threadIdx.x;
  __shared__ float mt[256];
  float s = 0.f;
  for (int t=0;t<TT;++t) s += xx[((size_t)b*TT+t)*DMODEL + tid];
  mt[tid] = s*(1.f/256.f);
  __syncthreads();
  float acc = bsgn[tid];
  for (int i=0;i<DMODEL;++i) acc += mt[i]*wsgn[i*DMODEL + tid];
  embw[b*DMODEL+tid] = acc;
  out_emb[b*DMODEL+tid] = acc;
}

__global__ __launch_bounds__(256) void logits_kernel(const float* __restrict__ embw,
    const float* __restrict__ protos, float* __restrict__ out)
{
  int b = blockIdx.x, tid = threadIdx.x;
  __shared__ __align__(16) float e[256];
  __shared__ float red[4];
  e[tid] = embw[b*256+tid];
  __syncthreads();
  float v = e[tid]*e[tid];
  #pragma unroll
  for (int off=32;off>=1;off>>=1) v += __shfl_xor(v, off);
  if ((tid&63)==0) red[tid>>6] = v;
  __syncthreads();
  float esc = 1.f/(sqrtf(red[0]+red[1]+red[2]+red[3]) + 1e-8f);
  for (int p = tid; p < NSIGNS; p += 256) {
    const float* pr = protos + (size_t)p*256;
    float dot=0.f, ps=0.f;
    for (int i=0;i<256;i+=4) {
      float4 pv = *(const float4*)(pr+i);
      float4 ev = *(const float4*)(e+i);
      dot += pv.x*ev.x + pv.y*ev.y + pv.z*ev.z + pv.w*ev.w;
      ps  += pv.x*pv.x + pv.y*pv.y + pv.z*pv.z + pv.w*pv.w;
    }
    out[(size_t)b*NSIGNS + p] = dot*esc/(sqrtf(ps)+1e-8f)*(1.f/0.07f);
  }
}

__global__ __launch_bounds__(256) void sims_kernel(const float* __restrict__ comps,
    const float* __restrict__ phs, const float* __restrict__ ploc,
    const float* __restrict__ pmov, const float* __restrict__ pori,
    float* __restrict__ out)
{
  int b = blockIdx.x, tid = threadIdx.x;
  __shared__ float pc[256];
  __shared__ float nk[4];
  float s = 0.f;
  for (int t=0;t<TT;++t) s += comps[((size_t)b*TT+t)*256 + tid];
  pc[tid] = s*(1.f/256.f);
  __syncthreads();
  if (tid < 4) {
    float ss = 0.f;
    for (int i=0;i<64;++i){ float q = pc[tid*64+i]; ss += q*q; }
    nk[tid] = 1.f/(sqrtf(ss)+1e-8f);
  }
  __syncthreads();
  if (tid < 88) {
    int k, pi; const float* P; size_t off; int npk;
    if (tid < 40)      { k=0; pi=tid;    P=phs;  off=144384; npk=40; }
    else if (tid < 60) { k=1; pi=tid-40; P=ploc; off=146944; npk=20; }
    else if (tid < 80) { k=2; pi=tid-60; P=pmov; off=148224; npk=20; }
    else               { k=3; pi=tid-80; P=pori; off=149504; npk=8;  }
    float dot=0.f, ps=0.f;
    for (int i=0;i<64;++i){ float pv = P[pi*64+i]; dot += pv*pc[k*64+i]; ps += pv*pv; }
    out[off + (size_t)b*npk + pi] = dot*nk[k]/(sqrtf(ps)+1e-8f)*(1.f/0.07f);
  }
}

extern "C" void kernel_launch(void* const* d_in, const int* in_sizes, int n_in,
                              void* d_out, int out_size, void* d_ws, size_t ws_size,
                              hipStream_t stream) {
  const float* x         = (const float*)d_in[0];
  const float* w_in      = (const float*)d_in[1];
  const float* b_in      = (const float*)d_in[2];
  const float* w_gat     = (const float*)d_in[3];
  const float* a_src     = (const float*)d_in[4];
  const float* a_dst     = (const float*)d_in[5];
  const float* w_out     = (const float*)d_in[6];
  const float* b_out     = (const float*)d_in[7];
  const float* pdm_w     = (const float*)d_in[8];
  const float* pdm_b     = (const float*)d_in[9];
  const float* w_fuse    = (const float*)d_in[10];
  const float* b_fuse    = (const float*)d_in[11];
  const float* ln_w      = (const float*)d_in[12];
  const float* in_proj   = (const float*)d_in[13];
  const float* conv_w    = (const float*)d_in[14];
  const float* conv_b    = (const float*)d_in[15];
  const float* x_proj    = (const float*)d_in[16];
  const float* dt_w      = (const float*)d_in[17];
  const float* dt_b      = (const float*)d_in[18];
  const float* A_log     = (const float*)d_in[19];
  const float* Dvec      = (const float*)d_in[20];
  const float* out_proj  = (const float*)d_in[21];
  const float* w_sign    = (const float*)d_in[22];
  const float* b_sign    = (const float*)d_in[23];
  const float* protos    = (const float*)d_in[24];
  const float* phs       = (const float*)d_in[25];
  const float* ploc      = (const float*)d_in[26];
  const float* pmov      = (const float*)d_in[27];
  const float* pori      = (const float*)d_in[28];
  float* out = (float*)d_out;
  float* ws  = (float*)d_ws;

  const size_t o_comps = 0;                       // 16384*256
  const size_t o_xx    = o_comps + (size_t)BTT*256;
  const size_t o_xn    = o_xx    + (size_t)BTT*256;
  const size_t o_xz    = o_xn    + (size_t)BTT*256;   // 16384*1024 (also aliases spatial)
  const size_t o_ucv   = o_xz    + (size_t)BTT*1024;
  const size_t o_xdbl  = o_ucv   + (size_t)BTT*512;
  const size_t o_y     = o_xdbl  + (size_t)BTT*48;
  const size_t o_emb   = o_y     + (size_t)BTT*512;
  const size_t o_wgT   = o_emb   + 64*256;
  const size_t o_wbig  = o_wgT   + 16384;
  const size_t o_fsum  = o_wbig  + 65536;             // 16384*128
  const size_t o_spat  = o_xz;                        // alias: spatial dead before xz is written

  prep_wgat_kernel<<<64, 256, 0, stream>>>(w_gat, ws + o_wgT);
  prep_pdmw_kernel<<<256, 256, 0, stream>>>(pdm_w, ws + o_wbig);
  agan_kernel<<<BTT, 256, 0, stream>>>(x, w_in, b_in, ws + o_wgT, a_src, a_dst, ws + o_fsum);
  // spatial = fsum @ w_out + b_out
  gemm_kernel<0,1,0><<<dim3(4,256), 256, 0, stream>>>(ws+o_fsum, w_out, b_out, ws+o_spat, BTT, 256, 128);
  // comps = relu(spatial @ Wbig + pdm_b)
  gemm_kernel<0,1,1><<<dim3(4,256), 256, 0, stream>>>(ws+o_spat, ws+o_wbig, pdm_b, ws+o_comps, BTT, 256, 256);
  // xx = comps @ w_fuse + b_fuse
  gemm_kernel<0,1,0><<<dim3(4,256), 256, 0, stream>>>(ws+o_comps, w_fuse, b_fuse, ws+o_xx, BTT, 256, 256);

  for (int l = 0; l < 4; ++l) {
    ln_kernel<<<BTT/4, 256, 0, stream>>>(ws+o_xx, ln_w + l*DMODEL, ws+o_xn);
    for (int d = 0; d < 2; ++d) {
      int ld = l*2 + d;
      gemm_kernel<0,0,0><<<dim3(16,256), 256, 0, stream>>>(ws+o_xn, in_proj + (size_t)ld*256*1024,
                                                           nullptr, ws+o_xz, BTT, 1024, 256);
      conv_kernel<<<BTT*512/256, 256, 0, stream>>>(ws+o_xz, conv_w + (size_t)ld*512*4,
                                                   conv_b + (size_t)ld*512, ws+o_ucv, d);
      gemm_kernel<0,0,0><<<dim3(1,256), 256, 0, stream>>>(ws+o_ucv, x_proj + (size_t)ld*512*48,
                                                          nullptr, ws+o_xdbl, BTT, 48, 512);
      scan_kernel<<<dim3(64,8), 64, 0, stream>>>(ws+o_ucv, ws+o_xdbl, ws+o_xz,
                                                 dt_w + (size_t)ld*16*512, dt_b + (size_t)ld*512,
                                                 A_log + (size_t)ld*512*16, Dvec + (size_t)ld*512,
                                                 ws+o_y, d);
      gemm_kernel<1,0,0><<<dim3(4,256), 256, 0, stream>>>(ws+o_y, out_proj + (size_t)ld*512*256,
                                                          nullptr, ws+o_xx, BTT, 256, 512);
    }
  }

  head_emb_kernel<<<64, 256, 0, stream>>>(ws+o_xx, w_sign, b_sign, ws+o_emb, out + 128000);
  logits_kernel<<<64, 256, 0, stream>>>(ws+o_emb, protos, out);
  sims_kernel<<<64, 256, 0, stream>>>(ws+o_comps, phs, ploc, pmov, pori, out);
  (void)in_sizes; (void)n_in; (void)out_size; (void)ws_size;
}

// Round 2
// 4328.179 us; speedup vs baseline: 1.3099x; 1.3099x over previous
//
#include <hip/hip_runtime.h>
#include <math.h>

#define BB 64
#define TT 256
#define NNODE 21
#define HID 128
#define DMODEL 256
#define DINNER 512
#define NSIGNS 2000
#define BTT (BB*TT)   // 16384

typedef unsigned short u16;
typedef unsigned int u32;
typedef __attribute__((ext_vector_type(8))) short short8;
typedef __attribute__((ext_vector_type(4))) float f32x4;

__device__ __forceinline__ float softplusf(float x){ return fmaxf(x,0.f) + log1pf(expf(-fabsf(x))); }
__device__ __forceinline__ float siluf(float x){ return x/(1.f+expf(-x)); }
__device__ __forceinline__ u16 f2bf(float x){ u32 u = __float_as_uint(x); u32 r = u + 0x7FFFu + ((u>>16)&1u); return (u16)(r>>16); }
__device__ __forceinline__ float bf2f(u16 u){ return __uint_as_float(((u32)u)<<16); }
__device__ __forceinline__ void gload16(const u16* g, u16* l){
  __builtin_amdgcn_global_load_lds((const __attribute__((address_space(1))) void*)g,
                                   (__attribute__((address_space(3))) void*)l, 16, 0, 0);
}

// ---------- prep: transpose w_gat (4,128,32) -> Bp[i][h*32+o] (fp32, for agan) ----------
__global__ void prep_wgat_kernel(const float* __restrict__ wg, float* __restrict__ bp){
  int idx = blockIdx.x*256 + threadIdx.x;           // 16384
  int i = idx >> 7, ho = idx & 127;
  bp[idx] = wg[(((ho>>5)*128) + i)*32 + (ho&31)];
}

// ---------- weights -> bf16 transposed [N][K] (one kernel, segmented) ----------
// seg0 in_projT : 8 x [1024][256]  (2,097,152)
// seg1 out_projT: 8 x [256][512]   (1,048,576)
// seg2 x_projT  : 8 x [128][512]   (524,288, rows 48..127 zero)
// seg3 w_outT   : [256][128]       (32,768)
// seg4 wbigT    : [256][256]       (65,536)  (kc major, d minor)
// seg5 w_fuseT  : [256][256]       (65,536)
__global__ void conv_weights_kernel(const float* __restrict__ in_proj, const float* __restrict__ out_proj,
    const float* __restrict__ x_proj, const float* __restrict__ w_out, const float* __restrict__ pdm_w,
    const float* __restrict__ w_fuse, u16* __restrict__ dst)
{
  int idx = blockIdx.x*256 + threadIdx.x;
  if (idx >= 3833856) return;
  float v;
  if (idx < 2097152) {
    int ld = idx >> 18, rem = idx & 262143, n = rem >> 8, k = rem & 255;
    v = in_proj[((size_t)ld*256 + k)*1024 + n];
  } else if (idx < 3145728) {
    int r = idx - 2097152; int ld = r >> 17, rem = r & 131071, n = rem >> 9, k = rem & 511;
    v = out_proj[((size_t)ld*512 + k)*256 + n];
  } else if (idx < 3670016) {
    int r = idx - 3145728; int ld = r >> 16, rem = r & 65535, n = rem >> 9, k = rem & 511;
    v = (n < 48) ? x_proj[((size_t)ld*512 + k)*48 + n] : 0.f;
  } else if (idx < 3702784) {
    int r = idx - 3670016; int n = r >> 7, k = r & 127;
    v = w_out[k*256 + n];
  } else if (idx < 3768320) {
    int r = idx - 3702784; int kc = r >> 8, d = r & 255;
    v = pdm_w[(size_t)((kc>>6)*256 + d)*64 + (kc&63)];
  } else {
    int r = idx - 3768320; int n = r >> 8, k = r & 255;
    v = w_fuse[k*256 + n];
  }
  dst[idx] = f2bf(v);
}

// ---------- AGAN (unchanged except bf16 fsum output) ----------
__global__ __launch_bounds__(256) void agan_kernel(
    const float* __restrict__ x, const float* __restrict__ w_in, const float* __restrict__ b_in,
    const float* __restrict__ bp, const float* __restrict__ a_src, const float* __restrict__ a_dst,
    u16* __restrict__ fsum_out)
{
  int bt = blockIdx.x;
  int tid = threadIdx.x;
  __shared__ float xv[NNODE][4];
  __shared__ __align__(16) float h0s[NNODE][HID];
  __shared__ __align__(16) float hms[NNODE][HID];
  __shared__ float sd[2][NNODE][4];
  __shared__ float al[4][NNODE][NNODE];
  if (tid < NNODE*3) xv[tid/3][tid%3] = x[(size_t)bt*(NNODE*3) + tid];
  __syncthreads();
  for (int idx = tid; idx < NNODE*HID; idx += 256) {
    int n = idx >> 7, i = idx & 127;
    float v = b_in[i] + xv[n][0]*w_in[i] + xv[n][1]*w_in[HID+i] + xv[n][2]*w_in[2*HID+i];
    h0s[n][i] = fmaxf(v, 0.f);
  }
  __syncthreads();
  {
    int ho = tid & 127;
    int half = tid >> 7;
    int n0 = half * 11;
    int cnt = half ? 10 : 11;
    float acc[11];
    #pragma unroll
    for (int j=0;j<11;++j) acc[j]=0.f;
    for (int i=0;i<HID;i+=4) {
      float b0 = bp[(i+0)*128 + ho];
      float b1 = bp[(i+1)*128 + ho];
      float b2 = bp[(i+2)*128 + ho];
      float b3 = bp[(i+3)*128 + ho];
      #pragma unroll
      for (int j=0;j<11;++j) {
        if (j < cnt) {
          float4 hv = *(const float4*)&h0s[n0+j][i];
          acc[j] += hv.x*b0 + hv.y*b1 + hv.z*b2 + hv.w*b3;
        }
      }
    }
    for (int j=0;j<cnt;++j) hms[n0+j][ho] = acc[j];
  }
  __syncthreads();
  if (tid < 2*NNODE*4) {
    int which = tid >= 84 ? 1 : 0;
    int r = tid - which*84;
    int n = r >> 2, h = r & 3;
    const float* av = (which ? a_dst : a_src) + h*32;
    const float* hr = &hms[n][h*32];
    float s = 0.f;
    #pragma unroll
    for (int o=0;o<32;++o) { int oo = (o + tid) & 31; s += hr[oo]*av[oo]; }
    sd[which][n][h] = s;
  }
  __syncthreads();
  if (tid < 84) {
    int i = tid >> 2, h = tid & 3;
    float sv = sd[0][i][h];
    float ev[NNODE]; float m = -1e30f;
    #pragma unroll
    for (int j=0;j<NNODE;++j) {
      float e = sv + sd[1][j][h];
      e = (e >= 0.f) ? e : 0.2f*e;
      ev[j] = e; m = fmaxf(m, e);
    }
    float ss = 0.f;
    #pragma unroll
    for (int j=0;j<NNODE;++j){ float ex = expf(ev[j]-m); ev[j]=ex; ss+=ex; }
    float inv = 1.f/ss;
    #pragma unroll
    for (int j=0;j<NNODE;++j) al[h][i][j] = ev[j]*inv;
  }
  __syncthreads();
  for (int idx = tid; idx < NNODE*HID; idx += 256) {
    int n = idx >> 7, ho = idx & 127, h = ho >> 5;
    float s = 0.f;
    #pragma unroll
    for (int j=0;j<NNODE;++j) s += al[h][n][j]*hms[j][ho];
    h0s[n][ho] = fmaxf(h0s[n][ho] + s, 0.f);
  }
  __syncthreads();
  if (tid < HID) {
    float s = 0.f;
    #pragma unroll
    for (int n=0;n<NNODE;++n) s += h0s[n][tid];
    fsum_out[(size_t)bt*HID + tid] = f2bf(s * (1.f/21.f));
  }
}

// ---------- bf16 MFMA GEMM: C[M,N] = A[M,K] @ BT[N][K]^T  (128x128 tile, 4 waves) ----------
// SM: 0 = fp32 C, 1 = bf16 C2, 2 = both. ACC: C += (fp32).
template<int ACC, int BIAS, int RELU, int SM>
__global__ __launch_bounds__(256) void gemm_bf16_kernel(
    const u16* __restrict__ A, const u16* __restrict__ BT, const float* __restrict__ bias,
    float* __restrict__ C, u16* __restrict__ C2, int M, int N, int K)
{
  __shared__ __align__(16) short Asl[4096];   // [128 rows][32 k]
  __shared__ __align__(16) short Bsl[4096];   // [128 cols][32 k]
  int tid = threadIdx.x;
  int lane = tid & 63, wid = tid >> 6;
  int wm = wid >> 1, wn = wid & 1;
  int row0 = blockIdx.y*128, col0 = blockIdx.x*128;
  const u16* Ab = A  + (size_t)row0*K;
  const u16* Bb = BT + (size_t)col0*K;
  f32x4 acc[4][4] = {};
  int c0 = tid;          // chunk ids for the two staging issues
  int c1 = 256 + tid;
  int lrow = lane & 15, lk = (lane>>4)*8;
  for (int k0 = 0; k0 < K; k0 += 32) {
    gload16(Ab + (size_t)(c0>>2)*K + k0 + (c0&3)*8, (u16*)Asl + (wid<<9));
    gload16(Ab + (size_t)(c1>>2)*K + k0 + (c1&3)*8, (u16*)Asl + 2048 + (wid<<9));
    gload16(Bb + (size_t)(c0>>2)*K + k0 + (c0&3)*8, (u16*)Bsl + (wid<<9));
    gload16(Bb + (size_t)(c1>>2)*K + k0 + (c1&3)*8, (u16*)Bsl + 2048 + (wid<<9));
    __syncthreads();
    short8 a[4], b[4];
    #pragma unroll
    for (int i=0;i<4;++i) a[i] = *(const short8*)&Asl[(wm*64 + i*16 + lrow)*32 + lk];
    #pragma unroll
    for (int j=0;j<4;++j) b[j] = *(const short8*)&Bsl[(wn*64 + j*16 + lrow)*32 + lk];
    #pragma unroll
    for (int i=0;i<4;++i)
      #pragma unroll
      for (int j=0;j<4;++j)
        acc[i][j] = __builtin_amdgcn_mfma_f32_16x16x32_bf16(a[i], b[j], acc[i][j], 0, 0, 0);
    __syncthreads();
  }
  #pragma unroll
  for (int i=0;i<4;++i) {
    int row = row0 + wm*64 + i*16 + (lane>>4)*4;
    #pragma unroll
    for (int j=0;j<4;++j) {
      int col = col0 + wn*64 + j*16 + (lane&15);
      if (col < N) {
        float bv = BIAS ? bias[col] : 0.f;
        #pragma unroll
        for (int r=0;r<4;++r) {
          float v = acc[i][j][r] + bv;
          if (RELU) v = fmaxf(v, 0.f);
          size_t o = (size_t)(row+r)*N + col;
          if (ACC)           C[o] += v;
          else if (SM == 0)  C[o]  = v;
          else if (SM == 1)  C2[o] = f2bf(v);
          else             { C[o]  = v; C2[o] = f2bf(v); }
        }
      }
    }
  }
}

// ---------- LayerNorm -> bf16 ----------
__global__ __launch_bounds__(256) void ln_kernel(const float* __restrict__ x,
    const float* __restrict__ w, u16* __restrict__ o)
{
  int row = blockIdx.x*4 + (threadIdx.x>>6);
  int lane = threadIdx.x & 63;
  float4 v = *(const float4*)(x + (size_t)row*DMODEL + lane*4);
  float s = v.x+v.y+v.z+v.w;
  #pragma unroll
  for (int off=32;off>=1;off>>=1) s += __shfl_xor(s, off);
  float mu = s * (1.f/256.f);
  float d0=v.x-mu, d1=v.y-mu, d2=v.z-mu, d3=v.w-mu;
  float q = d0*d0+d1*d1+d2*d2+d3*d3;
  #pragma unroll
  for (int off=32;off>=1;off>>=1) q += __shfl_xor(q, off);
  float inv = 1.f/sqrtf(q*(1.f/256.f) + 1e-5f);
  float4 wv = *(const float4*)(w + lane*4);
  u32 lo = (u32)f2bf(d0*inv*wv.x) | ((u32)f2bf(d1*inv*wv.y) << 16);
  u32 hi = (u32)f2bf(d2*inv*wv.z) | ((u32)f2bf(d3*inv*wv.w) << 16);
  uint2 pk; pk.x = lo; pk.y = hi;
  *(uint2*)(o + (size_t)row*DMODEL + lane*4) = pk;
}

// ---------- causal/anticausal depthwise conv + silu (bf16 in/out) ----------
__global__ __launch_bounds__(256) void conv_kernel(const u16* __restrict__ xz,
    const float* __restrict__ cw, const float* __restrict__ cb,
    u16* __restrict__ ucv, int dir)
{
  int idx = blockIdx.x*256 + threadIdx.x;          // BT*512
  int dd = idx & 511;
  int bt = idx >> 9;
  int t = bt & 255;
  const u16* up = xz + (size_t)(bt - t)*1024 + dd;
  float s = cb[dd];
  if (dir == 0) {
    #pragma unroll
    for (int k=0;k<4;++k) { int tk = t-3+k; if (tk >= 0) s += cw[dd*4+k]*bf2f(up[(size_t)tk*1024]); }
  } else {
    #pragma unroll
    for (int j=0;j<4;++j) { int tk = t+j; if (tk < TT) s += cw[dd*4+3-j]*bf2f(up[(size_t)tk*1024]); }
  }
  ucv[idx] = f2bf(siluf(s));
}

// ---------- selective scan (bf16 u/z inputs, bf16 y output) ----------
__global__ __launch_bounds__(64) void scan_kernel(
    const u16* __restrict__ ucv, const float* __restrict__ xdbl, const u16* __restrict__ xz,
    const float* __restrict__ dtw, const float* __restrict__ dtb,
    const float* __restrict__ alog, const float* __restrict__ dvec,
    u16* __restrict__ yout, int dir)
{
  int b = blockIdx.x;
  int lane = threadIdx.x;
  int dd = blockIdx.y*64 + lane;
  float wdt[16], Av[16], h[16];
  #pragma unroll
  for (int s=0;s<16;++s){ wdt[s]=dtw[s*DINNER+dd]; Av[s]=-expf(alog[dd*16+s]); h[s]=0.f; }
  float bdt = dtb[dd], Dv = dvec[dd];
  __shared__ float sxd[2][16][48];
  __shared__ float su[2][16][64];
  __shared__ float sz[2][16][64];
  int t0 = dir ? TT-1 : 0;
  int stp = dir ? -1 : 1;
  #pragma unroll
  for (int q=0;q<16;++q) {
    size_t bt = (size_t)b*TT + (t0 + stp*q);
    if (lane < 48) sxd[0][q][lane] = xdbl[bt*48 + lane];
    su[0][q][lane] = bf2f(ucv[bt*DINNER + dd]);
    sz[0][q][lane] = bf2f(xz[bt*1024 + DINNER + dd]);
  }
  int buf = 0;
  for (int w = 0; w < 16; ++w) {
    __syncthreads();
    if (w+1 < 16) {
      #pragma unroll
      for (int q=0;q<16;++q) {
        size_t bt = (size_t)b*TT + (t0 + stp*((w+1)*16 + q));
        if (lane < 48) sxd[buf^1][q][lane] = xdbl[bt*48 + lane];
        su[buf^1][q][lane] = bf2f(ucv[bt*DINNER + dd]);
        sz[buf^1][q][lane] = bf2f(xz[bt*1024 + DINNER + dd]);
      }
    }
    #pragma unroll 1
    for (int q=0;q<16;++q) {
      const float* s48 = sxd[buf][q];
      float uc = su[buf][q][lane], zc = sz[buf][q][lane];
      float dtp = bdt;
      #pragma unroll
      for (int r=0;r<16;++r) dtp += s48[r]*wdt[r];
      float dt = softplusf(dtp);
      float dtu = dt*uc;
      float y = 0.f;
      #pragma unroll
      for (int s=0;s<16;++s) {
        float dA = expf(dt*Av[s]);
        h[s] = dA*h[s] + dtu*s48[16+s];
        y += h[s]*s48[32+s];
      }
      int t = t0 + stp*(w*16+q);
      yout[((size_t)b*TT+t)*DINNER + dd] = f2bf((y + uc*Dv)*siluf(zc));
    }
    buf ^= 1;
  }
}

// ---------- heads (fp32) ----------
__global__ __launch_bounds__(256) void head_emb_kernel(const float* __restrict__ xx,
    const float* __restrict__ wsgn, const float* __restrict__ bsgn,
    float* __restrict__ embw, float* __restrict__ out_emb)
{
  int b = blockIdx.x, tid = threadIdx.x;
  __shared__ float mt[256];
  float s = 0.f;
  for (int t=0;t<TT;++t) s += xx[((size_t)b*TT+t)*DMODEL + tid];
  mt[tid] = s*(1.f/256.f);
  __syncthreads();
  float acc = bsgn[tid];
  for (int i=0;i<DMODEL;++i) acc += mt[i]*wsgn[i*DMODEL + tid];
  embw[b*DMODEL+tid] = acc;
  out_emb[b*DMODEL+tid] = acc;
}

__global__ __launch_bounds__(256) void logits_kernel(const float* __restrict__ embw,
    const float* __restrict__ protos, float* __restrict__ out)
{
  int b = blockIdx.x, tid = threadIdx.x;
  __shared__ __align__(16) float e[256];
  __shared__ float red[4];
  e[tid] = embw[b*256+tid];
  __syncthreads();
  float v = e[tid]*e[tid];
  #pragma unroll
  for (int off=32;off>=1;off>>=1) v += __shfl_xor(v, off);
  if ((tid&63)==0) red[tid>>6] = v;
  __syncthreads();
  float esc = 1.f/(sqrtf(red[0]+red[1]+red[2]+red[3]) + 1e-8f);
  for (int p = tid; p < NSIGNS; p += 256) {
    const float* pr = protos + (size_t)p*256;
    float dot=0.f, ps=0.f;
    for (int i=0;i<256;i+=4) {
      float4 pv = *(const float4*)(pr+i);
      float4 ev = *(const float4*)(e+i);
      dot += pv.x*ev.x + pv.y*ev.y + pv.z*ev.z + pv.w*ev.w;
      ps  += pv.x*pv.x + pv.y*pv.y + pv.z*pv.z + pv.w*pv.w;
    }
    out[(size_t)b*NSIGNS + p] = dot*esc/(sqrtf(ps)+1e-8f)*(1.f/0.07f);
  }
}

__global__ __launch_bounds__(256) void sims_kernel(const float* __restrict__ comps,
    const float* __restrict__ phs, const float* __restrict__ ploc,
    const float* __restrict__ pmov, const float* __restrict__ pori,
    float* __restrict__ out)
{
  int b = blockIdx.x, tid = threadIdx.x;
  __shared__ float pc[256];
  __shared__ float nk[4];
  float s = 0.f;
  for (int t=0;t<TT;++t) s += comps[((size_t)b*TT+t)*256 + tid];
  pc[tid] = s*(1.f/256.f);
  __syncthreads();
  if (tid < 4) {
    float ss = 0.f;
    for (int i=0;i<64;++i){ float q = pc[tid*64+i]; ss += q*q; }
    nk[tid] = 1.f/(sqrtf(ss)+1e-8f);
  }
  __syncthreads();
  if (tid < 88) {
    int k, pi; const float* P; size_t off; int npk;
    if (tid < 40)      { k=0; pi=tid;    P=phs;  off=144384; npk=40; }
    else if (tid < 60) { k=1; pi=tid-40; P=ploc; off=146944; npk=20; }
    else if (tid < 80) { k=2; pi=tid-60; P=pmov; off=148224; npk=20; }
    else               { k=3; pi=tid-80; P=pori; off=149504; npk=8;  }
    float dot=0.f, ps=0.f;
    for (int i=0;i<64;++i){ float pv = P[pi*64+i]; dot += pv*pc[k*64+i]; ps += pv*pv; }
    out[off + (size_t)b*npk + pi] = dot*nk[k]/(sqrtf(ps)+1e-8f)*(1.f/0.07f);
  }
}

extern "C" void kernel_launch(void* const* d_in, const int* in_sizes, int n_in,
                              void* d_out, int out_size, void* d_ws, size_t ws_size,
                              hipStream_t stream) {
  const float* x         = (const float*)d_in[0];
  const float* w_in      = (const float*)d_in[1];
  const float* b_in      = (const float*)d_in[2];
  const float* w_gat     = (const float*)d_in[3];
  const float* a_src     = (const float*)d_in[4];
  const float* a_dst     = (const float*)d_in[5];
  const float* w_out     = (const float*)d_in[6];
  const float* b_out     = (const float*)d_in[7];
  const float* pdm_w     = (const float*)d_in[8];
  const float* pdm_b     = (const float*)d_in[9];
  const float* w_fuse    = (const float*)d_in[10];
  const float* b_fuse    = (const float*)d_in[11];
  const float* ln_w      = (const float*)d_in[12];
  const float* in_proj   = (const float*)d_in[13];
  const float* conv_w    = (const float*)d_in[14];
  const float* conv_b    = (const float*)d_in[15];
  const float* x_proj    = (const float*)d_in[16];
  const float* dt_w      = (const float*)d_in[17];
  const float* dt_b      = (const float*)d_in[18];
  const float* A_log     = (const float*)d_in[19];
  const float* Dvec      = (const float*)d_in[20];
  const float* out_proj  = (const float*)d_in[21];
  const float* w_sign    = (const float*)d_in[22];
  const float* b_sign    = (const float*)d_in[23];
  const float* protos    = (const float*)d_in[24];
  const float* phs       = (const float*)d_in[25];
  const float* ploc      = (const float*)d_in[26];
  const float* pmov      = (const float*)d_in[27];
  const float* pori      = (const float*)d_in[28];
  float* out = (float*)d_out;

  // ---- ws layout ----
  float* wsf = (float*)d_ws;
  const size_t f_comps = 0;                          // 16384*256
  const size_t f_xx    = f_comps + 4194304;          // 16384*256
  const size_t f_xdbl  = f_xx    + 4194304;          // 16384*48
  const size_t f_emb   = f_xdbl  + 786432;           // 64*256
  const size_t f_wgT   = f_emb   + 16384;            // 16384
  const size_t f_end   = f_wgT   + 16384;
  u16* wsu = (u16*)(wsf + f_end);
  const size_t u_xz    = 0;                          // 16384*1024
  const size_t u_ucv   = u_xz    + 16777216;         // 16384*512
  const size_t u_xn    = u_ucv   + 8388608;          // 16384*256
  const size_t u_y     = u_xn    + 4194304;          // 16384*512
  const size_t u_fsum  = u_y     + 8388608;          // 16384*128
  const size_t u_spat  = u_fsum  + 2097152;          // 16384*256
  const size_t u_comps = u_spat  + 4194304;          // 16384*256
  const size_t u_w     = u_comps + 4194304;          // 3,833,856 weights
  u16* wiT = wsu + u_w;                // 8 x [1024][256]
  u16* woT = wiT + 2097152;            // 8 x [256][512]
  u16* wxT = woT + 1048576;            // 8 x [128][512]
  u16* wA  = wxT + 524288;             // [256][128]
  u16* wB  = wA  + 32768;              // [256][256]
  u16* wF  = wB  + 65536;              // [256][256]

  prep_wgat_kernel<<<64, 256, 0, stream>>>(w_gat, wsf + f_wgT);
  conv_weights_kernel<<<(3833856+255)/256, 256, 0, stream>>>(in_proj, out_proj, x_proj, w_out, pdm_w, w_fuse, wsu + u_w);
  agan_kernel<<<BTT, 256, 0, stream>>>(x, w_in, b_in, wsf + f_wgT, a_src, a_dst, wsu + u_fsum);
  // spatial(bf16) = fsum @ w_out + b_out
  gemm_bf16_kernel<0,1,0,1><<<dim3(2,128), 256, 0, stream>>>(wsu+u_fsum, wA, b_out, nullptr, wsu+u_spat, BTT, 256, 128);
  // comps(f32+bf16) = relu(spatial @ Wbig + pdm_b)
  gemm_bf16_kernel<0,1,1,2><<<dim3(2,128), 256, 0, stream>>>(wsu+u_spat, wB, pdm_b, wsf+f_comps, wsu+u_comps, BTT, 256, 256);
  // xx(f32) = comps @ w_fuse + b_fuse
  gemm_bf16_kernel<0,1,0,0><<<dim3(2,128), 256, 0, stream>>>(wsu+u_comps, wF, b_fuse, wsf+f_xx, nullptr, BTT, 256, 256);

  for (int l = 0; l < 4; ++l) {
    ln_kernel<<<BTT/4, 256, 0, stream>>>(wsf+f_xx, ln_w + l*DMODEL, wsu+u_xn);
    for (int d = 0; d < 2; ++d) {
      int ld = l*2 + d;
      // xz(bf16) = xn @ in_proj
      gemm_bf16_kernel<0,0,0,1><<<dim3(8,128), 256, 0, stream>>>(wsu+u_xn, wiT + (size_t)ld*262144,
          nullptr, nullptr, wsu+u_xz, BTT, 1024, 256);
      conv_kernel<<<BTT*512/256, 256, 0, stream>>>(wsu+u_xz, conv_w + (size_t)ld*512*4,
          conv_b + (size_t)ld*512, wsu+u_ucv, d);
      // xdbl(f32) = ucv @ x_proj
      gemm_bf16_kernel<0,0,0,0><<<dim3(1,128), 256, 0, stream>>>(wsu+u_ucv, wxT + (size_t)ld*65536,
          nullptr, wsf+f_xdbl, nullptr, BTT, 48, 512);
      scan_kernel<<<dim3(64,8), 64, 0, stream>>>(wsu+u_ucv, wsf+f_xdbl, wsu+u_xz,
          dt_w + (size_t)ld*16*512, dt_b + (size_t)ld*512,
          A_log + (size_t)ld*512*16, Dvec + (size_t)ld*512,
          wsu+u_y, d);
      // xx += y @ out_proj
      gemm_bf16_kernel<1,0,0,0><<<dim3(2,128), 256, 0, stream>>>(wsu+u_y, woT + (size_t)ld*131072,
          nullptr, wsf+f_xx, nullptr, BTT, 256, 512);
    }
  }

  head_emb_kernel<<<64, 256, 0, stream>>>(wsf+f_xx, w_sign, b_sign, wsf+f_emb, out + 128000);
  logits_kernel<<<64, 256, 0, stream>>>(wsf+f_emb, protos, out);
  sims_kernel<<<64, 256, 0, stream>>>(wsf+f_comps, phs, ploc, pmov, pori, out);
  (void)in_sizes; (void)n_in; (void)out_size; (void)ws_size;
}

// Round 3
// 2477.360 us; speedup vs baseline: 2.2885x; 1.7471x over previous
//
#include <hip/hip_runtime.h>
#include <math.h>

#define BB 64
#define TT 256
#define NNODE 21
#define HID 128
#define DMODEL 256
#define DINNER 512
#define NSIGNS 2000
#define BTT (BB*TT)   // 16384

typedef unsigned short u16;
typedef unsigned int u32;
typedef __attribute__((ext_vector_type(8))) short short8;
typedef __attribute__((ext_vector_type(4))) float f32x4;

__device__ __forceinline__ float siluf(float x){ return x/(1.f+expf(-x)); }
__device__ __forceinline__ u16 f2bf(float x){ u32 u = __float_as_uint(x); u32 r = u + 0x7FFFu + ((u>>16)&1u); return (u16)(r>>16); }
__device__ __forceinline__ float bf2f(u16 u){ return __uint_as_float(((u32)u)<<16); }
__device__ __forceinline__ void gload16(const u16* g, u16* l){
  __builtin_amdgcn_global_load_lds((const __attribute__((address_space(1))) void*)g,
                                   (__attribute__((address_space(3))) void*)l, 16, 0, 0);
}

// ---------- prep: transpose w_gat (4,128,32) -> Bp[i][h*32+o] (fp32, for agan) ----------
__global__ void prep_wgat_kernel(const float* __restrict__ wg, float* __restrict__ bp){
  int idx = blockIdx.x*256 + threadIdx.x;           // 16384
  int i = idx >> 7, ho = idx & 127;
  bp[idx] = wg[(((ho>>5)*128) + i)*32 + (ho&31)];
}

// ---------- weights -> bf16 transposed [N][K] ----------
__global__ void conv_weights_kernel(const float* __restrict__ in_proj, const float* __restrict__ out_proj,
    const float* __restrict__ x_proj, const float* __restrict__ w_out, const float* __restrict__ pdm_w,
    const float* __restrict__ w_fuse, u16* __restrict__ dst)
{
  int idx = blockIdx.x*256 + threadIdx.x;
  if (idx >= 3833856) return;
  float v;
  if (idx < 2097152) {
    int ld = idx >> 18, rem = idx & 262143, n = rem >> 8, k = rem & 255;
    v = in_proj[((size_t)ld*256 + k)*1024 + n];
  } else if (idx < 3145728) {
    int r = idx - 2097152; int ld = r >> 17, rem = r & 131071, n = rem >> 9, k = rem & 511;
    v = out_proj[((size_t)ld*512 + k)*256 + n];
  } else if (idx < 3670016) {
    int r = idx - 3145728; int ld = r >> 16, rem = r & 65535, n = rem >> 9, k = rem & 511;
    v = (n < 48) ? x_proj[((size_t)ld*512 + k)*48 + n] : 0.f;
  } else if (idx < 3702784) {
    int r = idx - 3670016; int n = r >> 7, k = r & 127;
    v = w_out[k*256 + n];
  } else if (idx < 3768320) {
    int r = idx - 3702784; int kc = r >> 8, d = r & 255;
    v = pdm_w[(size_t)((kc>>6)*256 + d)*64 + (kc&63)];
  } else {
    int r = idx - 3768320; int n = r >> 8, k = r & 255;
    v = w_fuse[k*256 + n];
  }
  dst[idx] = f2bf(v);
}

// ---------- AGAN ----------
__global__ __launch_bounds__(256) void agan_kernel(
    const float* __restrict__ x, const float* __restrict__ w_in, const float* __restrict__ b_in,
    const float* __restrict__ bp, const float* __restrict__ a_src, const float* __restrict__ a_dst,
    u16* __restrict__ fsum_out)
{
  int bt = blockIdx.x;
  int tid = threadIdx.x;
  __shared__ float xv[NNODE][4];
  __shared__ __align__(16) float h0s[NNODE][HID];
  __shared__ __align__(16) float hms[NNODE][HID];
  __shared__ float sd[2][NNODE][4];
  __shared__ float al[4][NNODE][NNODE];
  if (tid < NNODE*3) xv[tid/3][tid%3] = x[(size_t)bt*(NNODE*3) + tid];
  __syncthreads();
  for (int idx = tid; idx < NNODE*HID; idx += 256) {
    int n = idx >> 7, i = idx & 127;
    float v = b_in[i] + xv[n][0]*w_in[i] + xv[n][1]*w_in[HID+i] + xv[n][2]*w_in[2*HID+i];
    h0s[n][i] = fmaxf(v, 0.f);
  }
  __syncthreads();
  {
    int ho = tid & 127;
    int half = tid >> 7;
    int n0 = half * 11;
    int cnt = half ? 10 : 11;
    float acc[11];
    #pragma unroll
    for (int j=0;j<11;++j) acc[j]=0.f;
    for (int i=0;i<HID;i+=4) {
      float b0 = bp[(i+0)*128 + ho];
      float b1 = bp[(i+1)*128 + ho];
      float b2 = bp[(i+2)*128 + ho];
      float b3 = bp[(i+3)*128 + ho];
      #pragma unroll
      for (int j=0;j<11;++j) {
        if (j < cnt) {
          float4 hv = *(const float4*)&h0s[n0+j][i];
          acc[j] += hv.x*b0 + hv.y*b1 + hv.z*b2 + hv.w*b3;
        }
      }
    }
    for (int j=0;j<cnt;++j) hms[n0+j][ho] = acc[j];
  }
  __syncthreads();
  if (tid < 2*NNODE*4) {
    int which = tid >= 84 ? 1 : 0;
    int r = tid - which*84;
    int n = r >> 2, h = r & 3;
    const float* av = (which ? a_dst : a_src) + h*32;
    const float* hr = &hms[n][h*32];
    float s = 0.f;
    #pragma unroll
    for (int o=0;o<32;++o) { int oo = (o + tid) & 31; s += hr[oo]*av[oo]; }
    sd[which][n][h] = s;
  }
  __syncthreads();
  if (tid < 84) {
    int i = tid >> 2, h = tid & 3;
    float sv = sd[0][i][h];
    float ev[NNODE]; float m = -1e30f;
    #pragma unroll
    for (int j=0;j<NNODE;++j) {
      float e = sv + sd[1][j][h];
      e = (e >= 0.f) ? e : 0.2f*e;
      ev[j] = e; m = fmaxf(m, e);
    }
    float ss = 0.f;
    #pragma unroll
    for (int j=0;j<NNODE;++j){ float ex = expf(ev[j]-m); ev[j]=ex; ss+=ex; }
    float inv = 1.f/ss;
    #pragma unroll
    for (int j=0;j<NNODE;++j) al[h][i][j] = ev[j]*inv;
  }
  __syncthreads();
  for (int idx = tid; idx < NNODE*HID; idx += 256) {
    int n = idx >> 7, ho = idx & 127, h = ho >> 5;
    float s = 0.f;
    #pragma unroll
    for (int j=0;j<NNODE;++j) s += al[h][n][j]*hms[j][ho];
    h0s[n][ho] = fmaxf(h0s[n][ho] + s, 0.f);
  }
  __syncthreads();
  if (tid < HID) {
    float s = 0.f;
    #pragma unroll
    for (int n=0;n<NNODE;++n) s += h0s[n][tid];
    fsum_out[(size_t)bt*HID + tid] = f2bf(s * (1.f/21.f));
  }
}

// ---------- bf16 MFMA GEMM: C[M,N] = A[M,K] @ BT[N][K]^T ----------
template<int ACC, int BIAS, int RELU, int SM>
__global__ __launch_bounds__(256) void gemm_bf16_kernel(
    const u16* __restrict__ A, const u16* __restrict__ BT, const float* __restrict__ bias,
    float* __restrict__ C, u16* __restrict__ C2, int M, int N, int K)
{
  __shared__ __align__(16) short Asl[4096];
  __shared__ __align__(16) short Bsl[4096];
  int tid = threadIdx.x;
  int lane = tid & 63, wid = tid >> 6;
  int wm = wid >> 1, wn = wid & 1;
  int row0 = blockIdx.y*128, col0 = blockIdx.x*128;
  const u16* Ab = A  + (size_t)row0*K;
  const u16* Bb = BT + (size_t)col0*K;
  f32x4 acc[4][4] = {};
  int c0 = tid;
  int c1 = 256 + tid;
  int lrow = lane & 15, lk = (lane>>4)*8;
  for (int k0 = 0; k0 < K; k0 += 32) {
    gload16(Ab + (size_t)(c0>>2)*K + k0 + (c0&3)*8, (u16*)Asl + (wid<<9));
    gload16(Ab + (size_t)(c1>>2)*K + k0 + (c1&3)*8, (u16*)Asl + 2048 + (wid<<9));
    gload16(Bb + (size_t)(c0>>2)*K + k0 + (c0&3)*8, (u16*)Bsl + (wid<<9));
    gload16(Bb + (size_t)(c1>>2)*K + k0 + (c1&3)*8, (u16*)Bsl + 2048 + (wid<<9));
    __syncthreads();
    short8 a[4], b[4];
    #pragma unroll
    for (int i=0;i<4;++i) a[i] = *(const short8*)&Asl[(wm*64 + i*16 + lrow)*32 + lk];
    #pragma unroll
    for (int j=0;j<4;++j) b[j] = *(const short8*)&Bsl[(wn*64 + j*16 + lrow)*32 + lk];
    #pragma unroll
    for (int i=0;i<4;++i)
      #pragma unroll
      for (int j=0;j<4;++j)
        acc[i][j] = __builtin_amdgcn_mfma_f32_16x16x32_bf16(a[i], b[j], acc[i][j], 0, 0, 0);
    __syncthreads();
  }
  #pragma unroll
  for (int i=0;i<4;++i) {
    int row = row0 + wm*64 + i*16 + (lane>>4)*4;
    #pragma unroll
    for (int j=0;j<4;++j) {
      int col = col0 + wn*64 + j*16 + (lane&15);
      if (col < N) {
        float bv = BIAS ? bias[col] : 0.f;
        #pragma unroll
        for (int r=0;r<4;++r) {
          float v = acc[i][j][r] + bv;
          if (RELU) v = fmaxf(v, 0.f);
          size_t o = (size_t)(row+r)*N + col;
          if (ACC)           C[o] += v;
          else if (SM == 0)  C[o]  = v;
          else if (SM == 1)  C2[o] = f2bf(v);
          else             { C[o]  = v; C2[o] = f2bf(v); }
        }
      }
    }
  }
}

// ---------- LayerNorm -> bf16 ----------
__global__ __launch_bounds__(256) void ln_kernel(const float* __restrict__ x,
    const float* __restrict__ w, u16* __restrict__ o)
{
  int row = blockIdx.x*4 + (threadIdx.x>>6);
  int lane = threadIdx.x & 63;
  float4 v = *(const float4*)(x + (size_t)row*DMODEL + lane*4);
  float s = v.x+v.y+v.z+v.w;
  #pragma unroll
  for (int off=32;off>=1;off>>=1) s += __shfl_xor(s, off);
  float mu = s * (1.f/256.f);
  float d0=v.x-mu, d1=v.y-mu, d2=v.z-mu, d3=v.w-mu;
  float q = d0*d0+d1*d1+d2*d2+d3*d3;
  #pragma unroll
  for (int off=32;off>=1;off>>=1) q += __shfl_xor(q, off);
  float inv = 1.f/sqrtf(q*(1.f/256.f) + 1e-5f);
  float4 wv = *(const float4*)(w + lane*4);
  u32 lo = (u32)f2bf(d0*inv*wv.x) | ((u32)f2bf(d1*inv*wv.y) << 16);
  u32 hi = (u32)f2bf(d2*inv*wv.z) | ((u32)f2bf(d3*inv*wv.w) << 16);
  uint2 pk; pk.x = lo; pk.y = hi;
  *(uint2*)(o + (size_t)row*DMODEL + lane*4) = pk;
}

// ---------- causal/anticausal depthwise conv + silu (bf16 in/out) ----------
__global__ __launch_bounds__(256) void conv_kernel(const u16* __restrict__ xz,
    const float* __restrict__ cw, const float* __restrict__ cb,
    u16* __restrict__ ucv, int dir)
{
  int idx = blockIdx.x*256 + threadIdx.x;          // BT*512
  int dd = idx & 511;
  int bt = idx >> 9;
  int t = bt & 255;
  const u16* up = xz + (size_t)(bt - t)*1024 + dd;
  float s = cb[dd];
  if (dir == 0) {
    #pragma unroll
    for (int k=0;k<4;++k) { int tk = t-3+k; if (tk >= 0) s += cw[dd*4+k]*bf2f(up[(size_t)tk*1024]); }
  } else {
    #pragma unroll
    for (int j=0;j<4;++j) { int tk = t+j; if (tk < TT) s += cw[dd*4+3-j]*bf2f(up[(size_t)tk*1024]); }
  }
  ucv[idx] = f2bf(siluf(s));
}

// ---------- 3-phase chunked selective scan ----------
// Phase A (FINAL=0): per 32-step chunk, local scan (h=0), store Sdt=sum(dt), hend.
// Phase C (FINAL=1): local scan seeded with hin, compute y, gate with silu(z).
template<int FINAL>
__global__ __launch_bounds__(64) void scan_phase_kernel(
    const u16* __restrict__ ucv, const float* __restrict__ xdbl, const u16* __restrict__ xz,
    const float* __restrict__ dtw, const float* __restrict__ dtb,
    const float* __restrict__ alog, const float* __restrict__ dvec,
    const float* __restrict__ hin, float* __restrict__ Sdt, float* __restrict__ hend,
    u16* __restrict__ yout, int dir)
{
  int b = blockIdx.x, c = blockIdx.y, g = blockIdx.z;
  int lane = threadIdx.x;
  int dd = (g<<6) + lane;
  float wdt[16], Av[16], h[16];
  #pragma unroll
  for (int s=0;s<16;++s){
    wdt[s] = dtw[s*DINNER+dd];
    Av[s]  = -__expf(alog[dd*16+s]);
  }
  float bdt = dtb[dd];
  size_t co = ((size_t)b*8+c)*DINNER + dd;
  if (FINAL) {
    #pragma unroll
    for (int s=0;s<16;++s) h[s] = hin[co*16+s];
  } else {
    #pragma unroll
    for (int s=0;s<16;++s) h[s] = 0.f;
  }
  __shared__ float sxd[32][48];
  __shared__ u16 su[32][64];
  __shared__ u16 sz[(FINAL?32:1)][64];
  #pragma unroll 4
  for (int q=0;q<32;++q) {
    int p = (c<<5)+q;
    int t = dir ? 255-p : p;
    size_t bt = (size_t)b*TT + t;
    if (lane < 48) sxd[q][lane] = xdbl[bt*48 + lane];
    su[q][lane] = ucv[bt*DINNER + dd];
    if (FINAL) sz[q][lane] = xz[bt*1024 + DINNER + dd];
  }
  __syncthreads();
  float S = 0.f;
  float Dv = FINAL ? dvec[dd] : 0.f;
  #pragma unroll 1
  for (int q=0;q<32;++q) {
    const float* sr = sxd[q];
    float p0=0.f,p1=0.f,p2=0.f,p3=0.f;
    #pragma unroll
    for (int r=0;r<16;r+=4){
      p0 = fmaf(sr[r+0],wdt[r+0],p0);
      p1 = fmaf(sr[r+1],wdt[r+1],p1);
      p2 = fmaf(sr[r+2],wdt[r+2],p2);
      p3 = fmaf(sr[r+3],wdt[r+3],p3);
    }
    float dtp = bdt + ((p0+p1)+(p2+p3));
    float dt = fmaxf(dtp,0.f) + __logf(1.f + __expf(-fabsf(dtp)));
    float uc = bf2f(su[q][lane]);
    float dtu = dt*uc;
    if (!FINAL) S += dt;
    float y0=0.f, y1=0.f;
    #pragma unroll
    for (int s=0;s<16;s+=2){
      float dA0 = __expf(dt*Av[s]);
      float dA1 = __expf(dt*Av[s+1]);
      h[s]   = fmaf(dA0, h[s],   dtu*sr[16+s]);
      h[s+1] = fmaf(dA1, h[s+1], dtu*sr[16+s+1]);
      if (FINAL){ y0 = fmaf(h[s],sr[32+s],y0); y1 = fmaf(h[s+1],sr[32+s+1],y1); }
    }
    if (FINAL){
      float zc = bf2f(sz[q][lane]);
      float yv = (y0+y1) + uc*Dv;
      float sg = zc / (1.f + __expf(-zc));
      int p4 = (c<<5)+q;
      int t4 = dir ? 255-p4 : p4;
      yout[((size_t)b*TT+t4)*DINNER + dd] = f2bf(yv*sg);
    }
  }
  if (!FINAL){
    Sdt[co] = S;
    #pragma unroll
    for (int s=0;s<16;++s) hend[co*16+s] = h[s];
  }
}

// Phase B: serial combine across 8 chunks; in-place hend -> hin.
__global__ __launch_bounds__(256) void scanB_kernel(
    const float* __restrict__ Sdt, float* __restrict__ hst, const float* __restrict__ alog)
{
  int idx = blockIdx.x*256 + threadIdx.x;   // 32768 = b*512+dd
  int b = idx >> 9, dd = idx & 511;
  float Av[16];
  #pragma unroll
  for (int s=0;s<16;++s) Av[s] = -__expf(alog[dd*16+s]);
  float h[16];
  #pragma unroll
  for (int s=0;s<16;++s) h[s] = 0.f;
  for (int c=0;c<8;++c){
    size_t o = (((size_t)b*8+c)*DINNER + dd)*16;
    float S = Sdt[((size_t)b*8+c)*DINNER + dd];
    float he[16];
    #pragma unroll
    for (int s=0;s<16;++s) he[s] = hst[o+s];
    #pragma unroll
    for (int s=0;s<16;++s) hst[o+s] = h[s];
    #pragma unroll
    for (int s=0;s<16;++s) h[s] = fmaf(__expf(Av[s]*S), h[s], he[s]);
  }
}

// ---------- heads (fp32) ----------
__global__ __launch_bounds__(256) void head_emb_kernel(const float* __restrict__ xx,
    const float* __restrict__ wsgn, const float* __restrict__ bsgn,
    float* __restrict__ embw, float* __restrict__ out_emb)
{
  int b = blockIdx.x, tid = threadIdx.x;
  __shared__ float mt[256];
  float s = 0.f;
  for (int t=0;t<TT;++t) s += xx[((size_t)b*TT+t)*DMODEL + tid];
  mt[tid] = s*(1.f/256.f);
  __syncthreads();
  float acc = bsgn[tid];
  for (int i=0;i<DMODEL;++i) acc += mt[i]*wsgn[i*DMODEL + tid];
  embw[b*DMODEL+tid] = acc;
  out_emb[b*DMODEL+tid] = acc;
}

__global__ __launch_bounds__(256) void logits_kernel(const float* __restrict__ embw,
    const float* __restrict__ protos, float* __restrict__ out)
{
  int b = blockIdx.x, tid = threadIdx.x;
  __shared__ __align__(16) float e[256];
  __shared__ float red[4];
  e[tid] = embw[b*256+tid];
  __syncthreads();
  float v = e[tid]*e[tid];
  #pragma unroll
  for (int off=32;off>=1;off>>=1) v += __shfl_xor(v, off);
  if ((tid&63)==0) red[tid>>6] = v;
  __syncthreads();
  float esc = 1.f/(sqrtf(red[0]+red[1]+red[2]+red[3]) + 1e-8f);
  for (int p = tid; p < NSIGNS; p += 256) {
    const float* pr = protos + (size_t)p*256;
    float dot=0.f, ps=0.f;
    for (int i=0;i<256;i+=4) {
      float4 pv = *(const float4*)(pr+i);
      float4 ev = *(const float4*)(e+i);
      dot += pv.x*ev.x + pv.y*ev.y + pv.z*ev.z + pv.w*ev.w;
      ps  += pv.x*pv.x + pv.y*pv.y + pv.z*pv.z + pv.w*pv.w;
    }
    out[(size_t)b*NSIGNS + p] = dot*esc/(sqrtf(ps)+1e-8f)*(1.f/0.07f);
  }
}

__global__ __launch_bounds__(256) void sims_kernel(const float* __restrict__ comps,
    const float* __restrict__ phs, const float* __restrict__ ploc,
    const float* __restrict__ pmov, const float* __restrict__ pori,
    float* __restrict__ out)
{
  int b = blockIdx.x, tid = threadIdx.x;
  __shared__ float pc[256];
  __shared__ float nk[4];
  float s = 0.f;
  for (int t=0;t<TT;++t) s += comps[((size_t)b*TT+t)*256 + tid];
  pc[tid] = s*(1.f/256.f);
  __syncthreads();
  if (tid < 4) {
    float ss = 0.f;
    for (int i=0;i<64;++i){ float q = pc[tid*64+i]; ss += q*q; }
    nk[tid] = 1.f/(sqrtf(ss)+1e-8f);
  }
  __syncthreads();
  if (tid < 88) {
    int k, pi; const float* P; size_t off; int npk;
    if (tid < 40)      { k=0; pi=tid;    P=phs;  off=144384; npk=40; }
    else if (tid < 60) { k=1; pi=tid-40; P=ploc; off=146944; npk=20; }
    else if (tid < 80) { k=2; pi=tid-60; P=pmov; off=148224; npk=20; }
    else               { k=3; pi=tid-80; P=pori; off=149504; npk=8;  }
    float dot=0.f, ps=0.f;
    for (int i=0;i<64;++i){ float pv = P[pi*64+i]; dot += pv*pc[k*64+i]; ps += pv*pv; }
    out[off + (size_t)b*npk + pi] = dot*nk[k]/(sqrtf(ps)+1e-8f)*(1.f/0.07f);
  }
}

extern "C" void kernel_launch(void* const* d_in, const int* in_sizes, int n_in,
                              void* d_out, int out_size, void* d_ws, size_t ws_size,
                              hipStream_t stream) {
  const float* x         = (const float*)d_in[0];
  const float* w_in      = (const float*)d_in[1];
  const float* b_in      = (const float*)d_in[2];
  const float* w_gat     = (const float*)d_in[3];
  const float* a_src     = (const float*)d_in[4];
  const float* a_dst     = (const float*)d_in[5];
  const float* w_out     = (const float*)d_in[6];
  const float* b_out     = (const float*)d_in[7];
  const float* pdm_w     = (const float*)d_in[8];
  const float* pdm_b     = (const float*)d_in[9];
  const float* w_fuse    = (const float*)d_in[10];
  const float* b_fuse    = (const float*)d_in[11];
  const float* ln_w      = (const float*)d_in[12];
  const float* in_proj   = (const float*)d_in[13];
  const float* conv_w    = (const float*)d_in[14];
  const float* conv_b    = (const float*)d_in[15];
  const float* x_proj    = (const float*)d_in[16];
  const float* dt_w      = (const float*)d_in[17];
  const float* dt_b      = (const float*)d_in[18];
  const float* A_log     = (const float*)d_in[19];
  const float* Dvec      = (const float*)d_in[20];
  const float* out_proj  = (const float*)d_in[21];
  const float* w_sign    = (const float*)d_in[22];
  const float* b_sign    = (const float*)d_in[23];
  const float* protos    = (const float*)d_in[24];
  const float* phs       = (const float*)d_in[25];
  const float* ploc      = (const float*)d_in[26];
  const float* pmov      = (const float*)d_in[27];
  const float* pori      = (const float*)d_in[28];
  float* out = (float*)d_out;

  // ---- ws layout ----
  float* wsf = (float*)d_ws;
  const size_t f_comps = 0;                          // 16384*256
  const size_t f_xx    = f_comps + 4194304;          // 16384*256
  const size_t f_xdbl  = f_xx    + 4194304;          // 16384*48
  const size_t f_emb   = f_xdbl  + 786432;           // 64*256
  const size_t f_wgT   = f_emb   + 16384;            // 16384
  const size_t f_end   = f_wgT   + 16384;
  u16* wsu = (u16*)(wsf + f_end);
  const size_t u_xz    = 0;                          // 16384*1024
  const size_t u_ucv   = u_xz    + 16777216;         // 16384*512
  const size_t u_xn    = u_ucv   + 8388608;          // 16384*256
  const size_t u_y     = u_xn    + 4194304;          // 16384*512
  const size_t u_fsum  = u_y     + 8388608;          // 16384*128
  const size_t u_spat  = u_fsum  + 2097152;          // 16384*256
  const size_t u_comps = u_spat  + 4194304;          // 16384*256
  const size_t u_w     = u_comps + 4194304;          // 3,833,856 weights
  u16* wiT = wsu + u_w;                // 8 x [1024][256]
  u16* woT = wiT + 2097152;            // 8 x [256][512]
  u16* wxT = woT + 1048576;            // 8 x [128][512]
  u16* wA  = wxT + 524288;             // [256][128]
  u16* wB  = wA  + 32768;              // [256][256]
  u16* wF  = wB  + 65536;              // [256][256]
  // scan scratch ALIASES the dead-after-front fsum/spat/comps bf16 region:
  // need 64*8*512*16 f32 (hstate, 16.8MB) + 64*8*512 f32 (Sdt, 1MB) <= 21MB avail
  float* hstate = (float*)(wsu + u_fsum);
  float* sdt    = hstate + (size_t)64*8*512*16;

  prep_wgat_kernel<<<64, 256, 0, stream>>>(w_gat, wsf + f_wgT);
  conv_weights_kernel<<<(3833856+255)/256, 256, 0, stream>>>(in_proj, out_proj, x_proj, w_out, pdm_w, w_fuse, wsu + u_w);
  agan_kernel<<<BTT, 256, 0, stream>>>(x, w_in, b_in, wsf + f_wgT, a_src, a_dst, wsu + u_fsum);
  gemm_bf16_kernel<0,1,0,1><<<dim3(2,128), 256, 0, stream>>>(wsu+u_fsum, wA, b_out, nullptr, wsu+u_spat, BTT, 256, 128);
  gemm_bf16_kernel<0,1,1,2><<<dim3(2,128), 256, 0, stream>>>(wsu+u_spat, wB, pdm_b, wsf+f_comps, wsu+u_comps, BTT, 256, 256);
  gemm_bf16_kernel<0,1,0,0><<<dim3(2,128), 256, 0, stream>>>(wsu+u_comps, wF, b_fuse, wsf+f_xx, nullptr, BTT, 256, 256);

  for (int l = 0; l < 4; ++l) {
    ln_kernel<<<BTT/4, 256, 0, stream>>>(wsf+f_xx, ln_w + l*DMODEL, wsu+u_xn);
    for (int d = 0; d < 2; ++d) {
      int ld = l*2 + d;
      gemm_bf16_kernel<0,0,0,1><<<dim3(8,128), 256, 0, stream>>>(wsu+u_xn, wiT + (size_t)ld*262144,
          nullptr, nullptr, wsu+u_xz, BTT, 1024, 256);
      conv_kernel<<<BTT*512/256, 256, 0, stream>>>(wsu+u_xz, conv_w + (size_t)ld*512*4,
          conv_b + (size_t)ld*512, wsu+u_ucv, d);
      gemm_bf16_kernel<0,0,0,0><<<dim3(1,128), 256, 0, stream>>>(wsu+u_ucv, wxT + (size_t)ld*65536,
          nullptr, wsf+f_xdbl, nullptr, BTT, 48, 512);
      scan_phase_kernel<0><<<dim3(64,8,8), 64, 0, stream>>>(wsu+u_ucv, wsf+f_xdbl, nullptr,
          dt_w + (size_t)ld*16*512, dt_b + (size_t)ld*512,
          A_log + (size_t)ld*512*16, nullptr, nullptr, sdt, hstate, nullptr, d);
      scanB_kernel<<<128, 256, 0, stream>>>(sdt, hstate, A_log + (size_t)ld*512*16);
      scan_phase_kernel<1><<<dim3(64,8,8), 64, 0, stream>>>(wsu+u_ucv, wsf+f_xdbl, wsu+u_xz,
          dt_w + (size_t)ld*16*512, dt_b + (size_t)ld*512,
          A_log + (size_t)ld*512*16, Dvec + (size_t)ld*512,
          hstate, nullptr, nullptr, wsu+u_y, d);
      gemm_bf16_kernel<1,0,0,0><<<dim3(2,128), 256, 0, stream>>>(wsu+u_y, woT + (size_t)ld*131072,
          nullptr, wsf+f_xx, nullptr, BTT, 256, 512);
    }
  }

  head_emb_kernel<<<64, 256, 0, stream>>>(wsf+f_xx, w_sign, b_sign, wsf+f_emb, out + 128000);
  logits_kernel<<<64, 256, 0, stream>>>(wsf+f_emb, protos, out);
  sims_kernel<<<64, 256, 0, stream>>>(wsf+f_comps, phs, ploc, pmov, pori, out);
  (void)in_sizes; (void)n_in; (void)out_size; (void)ws_size;
}

// Round 4
// 2272.822 us; speedup vs baseline: 2.4944x; 1.0900x over previous
//
#include <hip/hip_runtime.h>
#include <math.h>

#define BB 64
#define TT 256
#define NNODE 21
#define HID 128
#define DMODEL 256
#define DINNER 512
#define NSIGNS 2000
#define BTT (BB*TT)   // 16384

typedef unsigned short u16;
typedef unsigned int u32;
typedef __attribute__((ext_vector_type(8))) short short8;
typedef __attribute__((ext_vector_type(4))) float f32x4;

__device__ __forceinline__ float siluf(float x){ return x/(1.f+expf(-x)); }
__device__ __forceinline__ u16 f2bf(float x){ u32 u = __float_as_uint(x); u32 r = u + 0x7FFFu + ((u>>16)&1u); return (u16)(r>>16); }
__device__ __forceinline__ float bf2f(u16 u){ return __uint_as_float(((u32)u)<<16); }
__device__ __forceinline__ void gload16(const u16* g, u16* l){
  __builtin_amdgcn_global_load_lds((const __attribute__((address_space(1))) void*)g,
                                   (__attribute__((address_space(3))) void*)l, 16, 0, 0);
}

// ---------- weights -> bf16 transposed [N][K] (one kernel, segmented) ----------
// seg0 in_projT : 4 x [2048][256]   n: 0-511 u0, 512-1023 u1, 1024-1535 z0, 1536-2047 z1
// seg1 out_projT: 4 x [256][1024]   k: 0-511 d0, 512-1023 d1
// seg2 x_projT  : 4 x [128][1024]   n<64: d0 rows (48 real), n>=64: d1; k-half matching d, else 0
// seg3 w_outT   : [256][128]
// seg4 wbigT    : [256][256]
// seg5 w_fuseT  : [256][256]
// seg6 BpT      : [128][128]  BpT[ho][i] = w_gat[ho>>5][i][ho&31]
__global__ void conv_weights_kernel(const float* __restrict__ in_proj, const float* __restrict__ out_proj,
    const float* __restrict__ x_proj, const float* __restrict__ w_out, const float* __restrict__ pdm_w,
    const float* __restrict__ w_fuse, const float* __restrict__ w_gat, u16* __restrict__ dst)
{
  int idx = blockIdx.x*256 + threadIdx.x;
  if (idx >= 3850240) return;
  float v;
  if (idx < 2097152) {
    int l = idx >> 19, rem = idx & 524287, n = rem >> 8, k = rem & 255;
    int d = (n >> 9) & 1, col = (n & 511) + ((n >> 10) << 9);
    v = in_proj[((size_t)(l*2+d)*256 + k)*1024 + col];
  } else if (idx < 3145728) {
    int r = idx - 2097152; int l = r >> 18, rem = r & 262143, n = rem >> 10, k = rem & 1023;
    int d = k >> 9, kk = k & 511;
    v = out_proj[((size_t)(l*2+d)*512 + kk)*256 + n];
  } else if (idx < 3670016) {
    int r = idx - 3145728; int l = r >> 17, rem = r & 131071, n = rem >> 10, k = rem & 1023;
    int d = n >> 6, nn = n & 63, kd = k >> 9, kk = k & 511;
    v = (nn < 48 && kd == d) ? x_proj[((size_t)(l*2+d)*512 + kk)*48 + nn] : 0.f;
  } else if (idx < 3702784) {
    int r = idx - 3670016; int n = r >> 7, k = r & 127;
    v = w_out[k*256 + n];
  } else if (idx < 3768320) {
    int r = idx - 3702784; int kc = r >> 8, d = r & 255;
    v = pdm_w[(size_t)((kc>>6)*256 + d)*64 + (kc&63)];
  } else if (idx < 3833856) {
    int r = idx - 3768320; int n = r >> 8, k = r & 255;
    v = w_fuse[k*256 + n];
  } else {
    int r = idx - 3833856; int ho = r >> 7, i = r & 127;
    v = w_gat[((size_t)(ho>>5)*128 + i)*32 + (ho&31)];
  }
  dst[idx] = f2bf(v);
}

// ---------- AGAN: per (b,t) graph attention, hm via MFMA ----------
__global__ __launch_bounds__(256) void agan_kernel(
    const float* __restrict__ x, const float* __restrict__ w_in, const float* __restrict__ b_in,
    const u16* __restrict__ bpt, const float* __restrict__ a_src, const float* __restrict__ a_dst,
    u16* __restrict__ fsum_out)
{
  int bt = blockIdx.x;
  int tid = threadIdx.x;
  int lane = tid & 63, wid = tid >> 6;
  __shared__ float xv[NNODE][4];
  __shared__ __align__(16) short sh0[32*136];     // h0 bf16, padded stride 136
  __shared__ __align__(16) short sbp[128*136];    // BpT bf16, padded stride 136
  __shared__ __align__(16) float hms[NNODE][128];
  __shared__ float sd[2][NNODE][4];
  __shared__ float al[4][NNODE][NNODE];
  // issue BpT global loads early (regs), LDS-write later with padding
  const u16* bpg = bpt + (tid>>1)*128 + (tid&1)*64;
  short8 breg[8];
  #pragma unroll
  for (int j=0;j<8;++j) breg[j] = *(const short8*)(bpg + j*8);
  if (tid < NNODE*3) xv[tid/3][tid%3] = x[(size_t)bt*(NNODE*3) + tid];
  __syncthreads();
  for (int idx = tid; idx < 32*128; idx += 256) {
    int n = idx >> 7, i = idx & 127;
    float v = 0.f;
    if (n < NNODE)
      v = fmaxf(b_in[i] + xv[n][0]*w_in[i] + xv[n][1]*w_in[HID+i] + xv[n][2]*w_in[2*HID+i], 0.f);
    sh0[n*136 + i] = (short)f2bf(v);
  }
  {
    short* dstp = sbp + (tid>>1)*136 + (tid&1)*64;
    #pragma unroll
    for (int j=0;j<8;++j) *(short8*)(dstp + j*8) = breg[j];
  }
  __syncthreads();
  // hm[32][128] = h0 @ Bp  (wave wid covers cols wid*32..wid*32+31)
  {
    f32x4 acc[2][2] = {};
    int lr = lane & 15, lk = (lane>>4)*8;
    #pragma unroll
    for (int ks=0;ks<4;++ks){
      short8 a0 = *(const short8*)&sh0[(lr     )*136 + ks*32 + lk];
      short8 a1 = *(const short8*)&sh0[(16 + lr)*136 + ks*32 + lk];
      short8 b0 = *(const short8*)&sbp[(wid*32      + lr)*136 + ks*32 + lk];
      short8 b1 = *(const short8*)&sbp[(wid*32 + 16 + lr)*136 + ks*32 + lk];
      acc[0][0] = __builtin_amdgcn_mfma_f32_16x16x32_bf16(a0,b0,acc[0][0],0,0,0);
      acc[0][1] = __builtin_amdgcn_mfma_f32_16x16x32_bf16(a0,b1,acc[0][1],0,0,0);
      acc[1][0] = __builtin_amdgcn_mfma_f32_16x16x32_bf16(a1,b0,acc[1][0],0,0,0);
      acc[1][1] = __builtin_amdgcn_mfma_f32_16x16x32_bf16(a1,b1,acc[1][1],0,0,0);
    }
    #pragma unroll
    for (int mt=0;mt<2;++mt)
      #pragma unroll
      for (int ntl=0;ntl<2;++ntl)
        #pragma unroll
        for (int r=0;r<4;++r){
          int row = mt*16 + (lane>>4)*4 + r;
          if (row < NNODE) hms[row][wid*32 + ntl*16 + lr] = acc[mt][ntl][r];
        }
  }
  __syncthreads();
  // src/dst
  if (tid < 2*NNODE*4) {
    int which = tid >= 84 ? 1 : 0;
    int r = tid - which*84;
    int n = r >> 2, h = r & 3;
    const float* av = (which ? a_dst : a_src) + h*32;
    const float* hr = &hms[n][h*32];
    float s = 0.f;
    #pragma unroll
    for (int o=0;o<32;++o) { int oo = (o + tid) & 31; s += hr[oo]*av[oo]; }
    sd[which][n][h] = s;
  }
  __syncthreads();
  // alpha = softmax_j(leaky_relu(src_i + dst_j))
  if (tid < 84) {
    int i = tid >> 2, h = tid & 3;
    float sv = sd[0][i][h];
    float ev[NNODE]; float m = -1e30f;
    #pragma unroll
    for (int j=0;j<NNODE;++j) {
      float e = sv + sd[1][j][h];
      e = (e >= 0.f) ? e : 0.2f*e;
      ev[j] = e; m = fmaxf(m, e);
    }
    float ss = 0.f;
    #pragma unroll
    for (int j=0;j<NNODE;++j){ float ex = expf(ev[j]-m); ev[j]=ex; ss+=ex; }
    float inv = 1.f/ss;
    #pragma unroll
    for (int j=0;j<NNODE;++j) al[h][i][j] = ev[j]*inv;
  }
  __syncthreads();
  // agg + feat = relu(h0+agg)  (feat into sfeat aliasing sbp, dead after MFMA)
  float* sfeat = (float*)sbp;
  for (int idx = tid; idx < NNODE*HID; idx += 256) {
    int n = idx >> 7, ho = idx & 127, h = ho >> 5;
    float s = 0.f;
    #pragma unroll
    for (int j=0;j<NNODE;++j) s += al[h][n][j]*hms[j][ho];
    sfeat[n*128 + ho] = fmaxf(bf2f((u16)sh0[n*136 + ho]) + s, 0.f);
  }
  __syncthreads();
  if (tid < HID) {
    float s = 0.f;
    #pragma unroll
    for (int n=0;n<NNODE;++n) s += sfeat[n*128 + tid];
    fsum_out[(size_t)bt*HID + tid] = f2bf(s * (1.f/21.f));
  }
}

// ---------- bf16 MFMA GEMM: C[M,N] = A[M,K(lda)] @ BT[N][K]^T ----------
// SM: 0 = fp32 C, 1 = bf16 C2, 2 = both. ACC: C += fp32. POOL: per-block col partials -> pool
template<int ACC, int BIAS, int RELU, int SM, int POOL>
__global__ __launch_bounds__(256) void gemm_bf16_kernel(
    const u16* __restrict__ A, const u16* __restrict__ BT, const float* __restrict__ bias,
    float* __restrict__ C, u16* __restrict__ C2, float* __restrict__ pool,
    int M, int N, int K, int lda)
{
  __shared__ __align__(16) short Asl[4096];
  __shared__ __align__(16) short Bsl[4096];
  int tid = threadIdx.x;
  int lane = tid & 63, wid = tid >> 6;
  int wm = wid >> 1, wn = wid & 1;
  int row0 = blockIdx.y*128, col0 = blockIdx.x*128;
  const u16* Ab = A  + (size_t)row0*lda;
  const u16* Bb = BT + (size_t)col0*K;
  f32x4 acc[4][4] = {};
  int c0 = tid;
  int c1 = 256 + tid;
  int lrow = lane & 15, lk = (lane>>4)*8;
  for (int k0 = 0; k0 < K; k0 += 32) {
    gload16(Ab + (size_t)(c0>>2)*lda + k0 + (c0&3)*8, (u16*)Asl + (wid<<9));
    gload16(Ab + (size_t)(c1>>2)*lda + k0 + (c1&3)*8, (u16*)Asl + 2048 + (wid<<9));
    gload16(Bb + (size_t)(c0>>2)*K + k0 + (c0&3)*8, (u16*)Bsl + (wid<<9));
    gload16(Bb + (size_t)(c1>>2)*K + k0 + (c1&3)*8, (u16*)Bsl + 2048 + (wid<<9));
    __syncthreads();
    short8 a[4], b[4];
    #pragma unroll
    for (int i=0;i<4;++i) a[i] = *(const short8*)&Asl[(wm*64 + i*16 + lrow)*32 + lk];
    #pragma unroll
    for (int j=0;j<4;++j) b[j] = *(const short8*)&Bsl[(wn*64 + j*16 + lrow)*32 + lk];
    #pragma unroll
    for (int i=0;i<4;++i)
      #pragma unroll
      for (int j=0;j<4;++j)
        acc[i][j] = __builtin_amdgcn_mfma_f32_16x16x32_bf16(a[i], b[j], acc[i][j], 0, 0, 0);
    __syncthreads();
  }
  float colsum[4] = {0.f,0.f,0.f,0.f};
  #pragma unroll
  for (int i=0;i<4;++i) {
    int row = row0 + wm*64 + i*16 + (lane>>4)*4;
    #pragma unroll
    for (int j=0;j<4;++j) {
      int col = col0 + wn*64 + j*16 + (lane&15);
      if (col < N) {
        float bv = BIAS ? bias[col] : 0.f;
        #pragma unroll
        for (int r=0;r<4;++r) {
          float v = acc[i][j][r] + bv;
          if (RELU) v = fmaxf(v, 0.f);
          size_t o = (size_t)(row+r)*N + col;
          if (ACC)           C[o] += v;
          else if (SM == 0)  C[o]  = v;
          else if (SM == 1)  C2[o] = f2bf(v);
          else             { C[o]  = v; C2[o] = f2bf(v); }
          if (POOL) colsum[j] += v;
        }
      }
    }
  }
  if (POOL) {
    float* red = (float*)Asl;   // 2048 floats avail
    #pragma unroll
    for (int j=0;j<4;++j) red[tid*4+j] = colsum[j];
    __syncthreads();
    if (tid < 128) {
      int wn_ = tid >> 6, j_ = (tid >> 4) & 3, l15 = tid & 15;
      float s = 0.f;
      #pragma unroll
      for (int wm_=0;wm_<2;++wm_)
        #pragma unroll
        for (int g=0;g<4;++g)
          s += red[(((wm_*2+wn_)*64) + g*16 + l15)*4 + j_];
      pool[(size_t)blockIdx.y*256 + blockIdx.x*128 + tid] = s * (1.f/256.f);
    }
  }
}

// ---------- LayerNorm -> bf16 ----------
__global__ __launch_bounds__(256) void ln_kernel(const float* __restrict__ x,
    const float* __restrict__ w, u16* __restrict__ o)
{
  int row = blockIdx.x*4 + (threadIdx.x>>6);
  int lane = threadIdx.x & 63;
  float4 v = *(const float4*)(x + (size_t)row*DMODEL + lane*4);
  float s = v.x+v.y+v.z+v.w;
  #pragma unroll
  for (int off=32;off>=1;off>>=1) s += __shfl_xor(s, off);
  float mu = s * (1.f/256.f);
  float d0=v.x-mu, d1=v.y-mu, d2=v.z-mu, d3=v.w-mu;
  float q = d0*d0+d1*d1+d2*d2+d3*d3;
  #pragma unroll
  for (int off=32;off>=1;off>>=1) q += __shfl_xor(q, off);
  float inv = 1.f/sqrtf(q*(1.f/256.f) + 1e-5f);
  float4 wv = *(const float4*)(w + lane*4);
  u32 lo = (u32)f2bf(d0*inv*wv.x) | ((u32)f2bf(d1*inv*wv.y) << 16);
  u32 hi = (u32)f2bf(d2*inv*wv.z) | ((u32)f2bf(d3*inv*wv.w) << 16);
  uint2 pk; pk.x = lo; pk.y = hi;
  *(uint2*)(o + (size_t)row*DMODEL + lane*4) = pk;
}

// ---------- depthwise conv + silu, both dirs (xz layout [u0 u1 z0 z1]) ----------
__global__ __launch_bounds__(256) void conv_kernel(const u16* __restrict__ xz,
    const float* __restrict__ cw, const float* __restrict__ cb,
    u16* __restrict__ ucv)
{
  int idx = blockIdx.x*256 + threadIdx.x;          // BT*1024
  int du = idx & 1023, dir = du >> 9, dd = du & 511;
  int bt = idx >> 10, t = bt & 255;
  const u16* up = xz + (size_t)(bt - t)*2048 + dir*512 + dd;
  const float* cwd = cw + (size_t)dir*2048 + dd*4;
  float s = cb[dir*512 + dd];
  if (dir == 0) {
    #pragma unroll
    for (int k=0;k<4;++k) { int tk = t-3+k; if (tk >= 0) s += cwd[k]*bf2f(up[(size_t)tk*2048]); }
  } else {
    #pragma unroll
    for (int j=0;j<4;++j) { int tk = t+j; if (tk < TT) s += cwd[3-j]*bf2f(up[(size_t)tk*2048]); }
  }
  ucv[(size_t)bt*1024 + dir*512 + dd] = f2bf(siluf(s));
}

// ---------- 3-phase chunked selective scan ----------
template<int FINAL>
__global__ __launch_bounds__(64) void scan_phase_kernel(
    const u16* __restrict__ u, const float* __restrict__ xd, const u16* __restrict__ z,
    const float* __restrict__ dtw, const float* __restrict__ dtb,
    const float* __restrict__ alog, const float* __restrict__ dvec,
    const float* __restrict__ hin, float* __restrict__ Sdt, float* __restrict__ hend,
    u16* __restrict__ yout, int rev)
{
  int b = blockIdx.x, c = blockIdx.y, g = blockIdx.z;
  int lane = threadIdx.x;
  int dd = (g<<6) + lane;                 // [0,512)
  float wdt[16], Av[16], h[16];
  #pragma unroll
  for (int s=0;s<16;++s){
    wdt[s] = dtw[s*DINNER+dd];
    Av[s]  = -__expf(alog[dd*16+s]);
  }
  float bdt = dtb[dd];
  size_t co = ((size_t)b*8+c)*DINNER + dd;
  if (FINAL) {
    #pragma unroll
    for (int s=0;s<16;++s) h[s] = hin[co*16+s];
  } else {
    #pragma unroll
    for (int s=0;s<16;++s) h[s] = 0.f;
  }
  __shared__ float sxd[32][48];
  __shared__ u16 su[32][64];
  __shared__ u16 sz[(FINAL?32:1)][64];
  #pragma unroll 4
  for (int q=0;q<32;++q) {
    int p = (c<<5)+q;
    int t = rev ? 255-p : p;
    size_t row = (size_t)b*TT + t;
    if (lane < 48) sxd[q][lane] = xd[row*128 + lane];
    su[q][lane] = u[row*1024 + dd];
    if (FINAL) sz[q][lane] = z[row*2048 + dd];
  }
  __syncthreads();
  float S = 0.f;
  float Dv = FINAL ? dvec[dd] : 0.f;
  #pragma unroll 1
  for (int q=0;q<32;++q) {
    const float* sr = sxd[q];
    float p0=0.f,p1=0.f,p2=0.f,p3=0.f;
    #pragma unroll
    for (int r=0;r<16;r+=4){
      p0 = fmaf(sr[r+0],wdt[r+0],p0);
      p1 = fmaf(sr[r+1],wdt[r+1],p1);
      p2 = fmaf(sr[r+2],wdt[r+2],p2);
      p3 = fmaf(sr[r+3],wdt[r+3],p3);
    }
    float dtp = bdt + ((p0+p1)+(p2+p3));
    float dt = fmaxf(dtp,0.f) + __logf(1.f + __expf(-fabsf(dtp)));
    float uc = bf2f(su[q][lane]);
    float dtu = dt*uc;
    if (!FINAL) S += dt;
    float y0=0.f, y1=0.f;
    #pragma unroll
    for (int s=0;s<16;s+=2){
      float dA0 = __expf(dt*Av[s]);
      float dA1 = __expf(dt*Av[s+1]);
      h[s]   = fmaf(dA0, h[s],   dtu*sr[16+s]);
      h[s+1] = fmaf(dA1, h[s+1], dtu*sr[16+s+1]);
      if (FINAL){ y0 = fmaf(h[s],sr[32+s],y0); y1 = fmaf(h[s+1],sr[32+s+1],y1); }
    }
    if (FINAL){
      float zc = bf2f(sz[q][lane]);
      float yv = (y0+y1) + uc*Dv;
      float sg = zc / (1.f + __expf(-zc));
      int p4 = (c<<5)+q;
      int t4 = rev ? 255-p4 : p4;
      yout[((size_t)b*TT+t4)*2048 + dd] = f2bf(yv*sg);
    }
  }
  if (!FINAL){
    Sdt[co] = S;
    #pragma unroll
    for (int s=0;s<16;++s) hend[co*16+s] = h[s];
  }
}

// Phase B: serial combine across 8 chunks; in-place hend -> hin.
__global__ __launch_bounds__(256) void scanB_kernel(
    const float* __restrict__ Sdt, float* __restrict__ hst, const float* __restrict__ alog)
{
  int idx = blockIdx.x*256 + threadIdx.x;   // 32768 = b*512+dd
  int b = idx >> 9, dd = idx & 511;
  float Av[16];
  #pragma unroll
  for (int s=0;s<16;++s) Av[s] = -__expf(alog[dd*16+s]);
  float h[16];
  #pragma unroll
  for (int s=0;s<16;++s) h[s] = 0.f;
  for (int c=0;c<8;++c){
    size_t o = (((size_t)b*8+c)*DINNER + dd)*16;
    float S = Sdt[((size_t)b*8+c)*DINNER + dd];
    float he[16];
    #pragma unroll
    for (int s=0;s<16;++s) he[s] = hst[o+s];
    #pragma unroll
    for (int s=0;s<16;++s) hst[o+s] = h[s];
    #pragma unroll
    for (int s=0;s<16;++s) h[s] = fmaf(__expf(Av[s]*S), h[s], he[s]);
  }
}

// ---------- heads (fp32) ----------
__global__ __launch_bounds__(256) void head_emb_kernel(const float* __restrict__ xx,
    const float* __restrict__ wsgn, const float* __restrict__ bsgn,
    float* __restrict__ embw, float* __restrict__ out_emb)
{
  int b = blockIdx.x, tid = threadIdx.x;
  __shared__ float mt[256];
  float s = 0.f;
  for (int t=0;t<TT;++t) s += xx[((size_t)b*TT+t)*DMODEL + tid];
  mt[tid] = s*(1.f/256.f);
  __syncthreads();
  float acc = bsgn[tid];
  for (int i=0;i<DMODEL;++i) acc += mt[i]*wsgn[i*DMODEL + tid];
  embw[b*DMODEL+tid] = acc;
  out_emb[b*DMODEL+tid] = acc;
}

__global__ __launch_bounds__(256) void logits_kernel(const float* __restrict__ embw,
    const float* __restrict__ protos, float* __restrict__ out)
{
  int b = blockIdx.x, tid = threadIdx.x;
  __shared__ __align__(16) float e[256];
  __shared__ float red[4];
  e[tid] = embw[b*256+tid];
  __syncthreads();
  float v = e[tid]*e[tid];
  #pragma unroll
  for (int off=32;off>=1;off>>=1) v += __shfl_xor(v, off);
  if ((tid&63)==0) red[tid>>6] = v;
  __syncthreads();
  float esc = 1.f/(sqrtf(red[0]+red[1]+red[2]+red[3]) + 1e-8f);
  for (int p = tid; p < NSIGNS; p += 256) {
    const float* pr = protos + (size_t)p*256;
    float dot=0.f, ps=0.f;
    for (int i=0;i<256;i+=4) {
      float4 pv = *(const float4*)(pr+i);
      float4 ev = *(const float4*)(e+i);
      dot += pv.x*ev.x + pv.y*ev.y + pv.z*ev.z + pv.w*ev.w;
      ps  += pv.x*pv.x + pv.y*pv.y + pv.z*pv.z + pv.w*pv.w;
    }
    out[(size_t)b*NSIGNS + p] = dot*esc/(sqrtf(ps)+1e-8f)*(1.f/0.07f);
  }
}

__global__ __launch_bounds__(256) void sims_kernel(const float* __restrict__ part,
    const float* __restrict__ phs, const float* __restrict__ ploc,
    const float* __restrict__ pmov, const float* __restrict__ pori,
    float* __restrict__ out)
{
  int b = blockIdx.x, tid = threadIdx.x;
  __shared__ float pc[256];
  __shared__ float nk[4];
  pc[tid] = part[(size_t)(2*b)*256 + tid] + part[(size_t)(2*b+1)*256 + tid];
  __syncthreads();
  if (tid < 4) {
    float ss = 0.f;
    for (int i=0;i<64;++i){ float q = pc[tid*64+i]; ss += q*q; }
    nk[tid] = 1.f/(sqrtf(ss)+1e-8f);
  }
  __syncthreads();
  if (tid < 88) {
    int k, pi; const float* P; size_t off; int npk;
    if (tid < 40)      { k=0; pi=tid;    P=phs;  off=144384; npk=40; }
    else if (tid < 60) { k=1; pi=tid-40; P=ploc; off=146944; npk=20; }
    else if (tid < 80) { k=2; pi=tid-60; P=pmov; off=148224; npk=20; }
    else               { k=3; pi=tid-80; P=pori; off=149504; npk=8;  }
    float dot=0.f, ps=0.f;
    for (int i=0;i<64;++i){ float pv = P[pi*64+i]; dot += pv*pc[k*64+i]; ps += pv*pv; }
    out[off + (size_t)b*npk + pi] = dot*nk[k]/(sqrtf(ps)+1e-8f)*(1.f/0.07f);
  }
}

extern "C" void kernel_launch(void* const* d_in, const int* in_sizes, int n_in,
                              void* d_out, int out_size, void* d_ws, size_t ws_size,
                              hipStream_t stream) {
  const float* x         = (const float*)d_in[0];
  const float* w_in      = (const float*)d_in[1];
  const float* b_in      = (const float*)d_in[2];
  const float* w_gat     = (const float*)d_in[3];
  const float* a_src     = (const float*)d_in[4];
  const float* a_dst     = (const float*)d_in[5];
  const float* w_out     = (const float*)d_in[6];
  const float* b_out     = (const float*)d_in[7];
  const float* pdm_w     = (const float*)d_in[8];
  const float* pdm_b     = (const float*)d_in[9];
  const float* w_fuse    = (const float*)d_in[10];
  const float* b_fuse    = (const float*)d_in[11];
  const float* ln_w      = (const float*)d_in[12];
  const float* in_proj   = (const float*)d_in[13];
  const float* conv_w    = (const float*)d_in[14];
  const float* conv_b    = (const float*)d_in[15];
  const float* x_proj    = (const float*)d_in[16];
  const float* dt_w      = (const float*)d_in[17];
  const float* dt_b      = (const float*)d_in[18];
  const float* A_log     = (const float*)d_in[19];
  const float* Dvec      = (const float*)d_in[20];
  const float* out_proj  = (const float*)d_in[21];
  const float* w_sign    = (const float*)d_in[22];
  const float* b_sign    = (const float*)d_in[23];
  const float* protos    = (const float*)d_in[24];
  const float* phs       = (const float*)d_in[25];
  const float* ploc      = (const float*)d_in[26];
  const float* pmov      = (const float*)d_in[27];
  const float* pori      = (const float*)d_in[28];
  float* out = (float*)d_out;

  // ---- ws layout ----
  float* wsf = (float*)d_ws;
  const size_t f_xx    = 0;                          // 16384*256
  const size_t f_xdbl  = f_xx   + 4194304;           // 16384*128
  const size_t f_part  = f_xdbl + 2097152;           // 128*256
  const size_t f_emb   = f_part + 32768;             // 64*256
  const size_t f_end   = f_emb  + 16384;
  u16* wsu = (u16*)(wsf + f_end);
  const size_t u_xn    = 0;                          // 16384*256
  const size_t u_xz    = u_xn   + 4194304;           // 16384*2048 [u0 u1 z0 z1]; y -> u slots
  const size_t u_ucv   = u_xz   + 33554432;          // 16384*1024
  const size_t u_fsum  = u_ucv  + 16777216;          // 16384*128
  const size_t u_spat  = u_fsum + 2097152;           // 16384*256
  const size_t u_comps = u_spat + 4194304;           // 16384*256
  const size_t u_w     = u_comps+ 4194304;           // 3,850,240 weights
  u16* wiT = wsu + u_w;                // 4 x [2048][256]
  u16* woT = wiT + 2097152;            // 4 x [256][1024]
  u16* wxT = woT + 1048576;            // 4 x [128][1024]
  u16* wA  = wxT + 524288;             // [256][128]
  u16* wB  = wA  + 32768;              // [256][256]
  u16* wF  = wB  + 65536;              // [256][256]
  u16* wBp = wF  + 65536;              // [128][128]
  // scan scratch aliases fsum/spat/comps (dead during SSM loop):
  float* hstate = (float*)(wsu + u_fsum);            // 64*8*512*16 = 4,194,304 f32
  float* sdt    = hstate + 4194304;                  // 64*8*512   =   262,144 f32

  conv_weights_kernel<<<(3850240+255)/256, 256, 0, stream>>>(in_proj, out_proj, x_proj, w_out, pdm_w, w_fuse, w_gat, wsu + u_w);
  agan_kernel<<<BTT, 256, 0, stream>>>(x, w_in, b_in, wBp, a_src, a_dst, wsu + u_fsum);
  gemm_bf16_kernel<0,1,0,1,0><<<dim3(2,128), 256, 0, stream>>>(wsu+u_fsum, wA, b_out, nullptr, wsu+u_spat, nullptr, BTT, 256, 128, 128);
  gemm_bf16_kernel<0,1,1,1,1><<<dim3(2,128), 256, 0, stream>>>(wsu+u_spat, wB, pdm_b, nullptr, wsu+u_comps, wsf+f_part, BTT, 256, 256, 256);
  gemm_bf16_kernel<0,1,0,0,0><<<dim3(2,128), 256, 0, stream>>>(wsu+u_comps, wF, b_fuse, wsf+f_xx, nullptr, nullptr, BTT, 256, 256, 256);

  for (int l = 0; l < 4; ++l) {
    ln_kernel<<<BTT/4, 256, 0, stream>>>(wsf+f_xx, ln_w + l*DMODEL, wsu+u_xn);
    gemm_bf16_kernel<0,0,0,1,0><<<dim3(16,128), 256, 0, stream>>>(wsu+u_xn, wiT + (size_t)l*524288,
        nullptr, nullptr, wsu+u_xz, nullptr, BTT, 2048, 256, 256);
    conv_kernel<<<BTT*1024/256, 256, 0, stream>>>(wsu+u_xz, conv_w + (size_t)l*4096,
        conv_b + (size_t)l*1024, wsu+u_ucv);
    gemm_bf16_kernel<0,0,0,0,0><<<dim3(1,128), 256, 0, stream>>>(wsu+u_ucv, wxT + (size_t)l*131072,
        nullptr, wsf+f_xdbl, nullptr, nullptr, BTT, 128, 1024, 1024);
    for (int d = 0; d < 2; ++d) {
      int ld = l*2 + d;
      const u16*  ud  = wsu + u_ucv + d*512;
      const u16*  zd  = wsu + u_xz + 1024 + d*512;
      u16*        yd  = wsu + u_xz + d*512;
      const float* xdd = wsf + f_xdbl + d*64;
      scan_phase_kernel<0><<<dim3(64,8,8), 64, 0, stream>>>(ud, xdd, nullptr,
          dt_w + (size_t)ld*8192, dt_b + (size_t)ld*512,
          A_log + (size_t)ld*8192, nullptr, nullptr, sdt, hstate, nullptr, d);
      scanB_kernel<<<128, 256, 0, stream>>>(sdt, hstate, A_log + (size_t)ld*8192);
      scan_phase_kernel<1><<<dim3(64,8,8), 64, 0, stream>>>(ud, xdd, zd,
          dt_w + (size_t)ld*8192, dt_b + (size_t)ld*512,
          A_log + (size_t)ld*8192, Dvec + (size_t)ld*512,
          hstate, nullptr, nullptr, yd, d);
    }
    gemm_bf16_kernel<1,0,0,0,0><<<dim3(2,128), 256, 0, stream>>>(wsu+u_xz, woT + (size_t)l*262144,
        nullptr, wsf+f_xx, nullptr, nullptr, BTT, 256, 1024, 2048);
  }

  head_emb_kernel<<<64, 256, 0, stream>>>(wsf+f_xx, w_sign, b_sign, wsf+f_emb, out + 128000);
  logits_kernel<<<64, 256, 0, stream>>>(wsf+f_emb, protos, out);
  sims_kernel<<<64, 256, 0, stream>>>(wsf+f_part, phs, ploc, pmov, pori, out);
  (void)in_sizes; (void)n_in; (void)out_size; (void)ws_size;
}

// Round 5
// 1880.164 us; speedup vs baseline: 3.0154x; 1.2088x over previous
//
#include <hip/hip_runtime.h>
#include <math.h>

#define BB 64
#define TT 256
#define NNODE 21
#define HID 128
#define DMODEL 256
#define DINNER 512
#define NSIGNS 2000
#define BTT (BB*TT)   // 16384

typedef unsigned short u16;
typedef unsigned int u32;
typedef __attribute__((ext_vector_type(8))) short short8;
typedef __attribute__((ext_vector_type(4))) float f32x4;

__device__ __forceinline__ float siluf(float x){ return x/(1.f+expf(-x)); }
__device__ __forceinline__ u16 f2bf(float x){ u32 u = __float_as_uint(x); u32 r = u + 0x7FFFu + ((u>>16)&1u); return (u16)(r>>16); }
__device__ __forceinline__ float bf2f(u16 u){ return __uint_as_float(((u32)u)<<16); }
__device__ __forceinline__ void gload16(const u16* g, u16* l){
  __builtin_amdgcn_global_load_lds((const __attribute__((address_space(1))) void*)g,
                                   (__attribute__((address_space(3))) void*)l, 16, 0, 0);
}

// ---------- tiled weight transpose -> bf16 [N][K] layouts (coalesced both sides) ----------
// dst layout (u16 offsets): wiT 0 (4x[2048][256]) | woT 2097152 (4x[256][1024]) |
// wxT 3145728 (4x[128][1024]) | wA 3670016 ([256][128]) | wB 3702784 ([256][256]) |
// wF 3768320 ([256][256]) | wBp 3833856 ([128][128])
__global__ __launch_bounds__(256) void transpose_w_kernel(
    const float* __restrict__ in_proj, const float* __restrict__ out_proj,
    const float* __restrict__ x_proj, const float* __restrict__ w_out,
    const float* __restrict__ pdm_w, const float* __restrict__ w_fuse,
    const float* __restrict__ w_gat, u16* __restrict__ dst)
{
  __shared__ short tl[64*66];
  int bx = blockIdx.x, tid = threadIdx.x;
  const float* S = nullptr; size_t soff = 0; int lds = 0, Nsrc = 0;
  size_t doff = 0; int ldd = 0, Nout = 0;
  int tn = 0, tk = 0;
  bool zero = false;
  if (bx < 512) {                       // in_projT
    int j = bx >> 5, tt = bx & 31;
    int l = j >> 2, d = j & 1, zh = (j >> 1) & 1;
    tn = tt >> 2; tk = tt & 3;
    S = in_proj; soff = ((size_t)(l*2+d)*256)*1024 + zh*512; lds = 1024; Nsrc = 512;
    doff = (size_t)l*524288 + (size_t)(zh*1024 + d*512)*256; ldd = 256; Nout = 512;
  } else if (bx < 768) {                // out_projT
    int j = (bx-512) >> 5, tt = (bx-512) & 31;
    int l = j >> 1, d = j & 1;
    tn = tt >> 3; tk = tt & 7;
    S = out_proj; soff = (size_t)(l*2+d)*512*256; lds = 256; Nsrc = 256;
    doff = 2097152 + (size_t)l*262144 + d*512; ldd = 1024; Nout = 256;
  } else if (bx < 896) {                // x_projT (+ zero-fill of off-d k-half)
    int j = (bx-768) >> 3, tt = (bx-768) & 7;
    int l = j >> 2, sub = j & 3;
    tn = 0; tk = tt;
    if (sub < 2) {
      int d = sub;
      S = x_proj; soff = (size_t)(l*2+d)*512*48; lds = 48; Nsrc = 48;
      doff = 3145728 + (size_t)l*131072 + (size_t)(d*64)*1024 + d*512; ldd = 1024; Nout = 64;
    } else {
      int d = sub-2; zero = true;
      doff = 3145728 + (size_t)l*131072 + (size_t)(d*64)*1024 + (1-d)*512; ldd = 1024; Nout = 64;
    }
  } else if (bx < 904) {                // w_outT
    int tt = bx-896; tn = tt>>1; tk = tt&1;
    S = w_out; soff = 0; lds = 256; Nsrc = 256;
    doff = 3670016; ldd = 128; Nout = 256;
  } else if (bx < 920) {                // wbigT (pdm_w)
    int j = (bx-904)>>2, tt = (bx-904)&3;
    tn = 0; tk = tt;
    S = pdm_w; soff = (size_t)j*16384; lds = 64; Nsrc = 64;
    doff = 3702784 + (size_t)j*16384; ldd = 256; Nout = 64;
  } else if (bx < 936) {                // w_fuseT
    int tt = bx-920; tn = tt>>2; tk = tt&3;
    S = w_fuse; soff = 0; lds = 256; Nsrc = 256;
    doff = 3768320; ldd = 256; Nout = 256;
  } else {                              // BpT
    int j = (bx-936)>>1, tt = (bx-936)&1;
    tn = 0; tk = tt;
    S = w_gat; soff = (size_t)j*4096; lds = 32; Nsrc = 32;
    doff = 3833856 + (size_t)j*4096; ldd = 128; Nout = 32;
  }
  int n0 = tn*64, k0 = tk*64;
  if (!zero) {
    #pragma unroll
    for (int i=0;i<16;++i){
      int kk = i*4 + (tid>>6), nn = tid&63;
      float v = (n0+nn < Nsrc) ? S[soff + (size_t)(k0+kk)*lds + n0+nn] : 0.f;
      tl[nn*66+kk] = (short)f2bf(v);
    }
    __syncthreads();
    #pragma unroll
    for (int i=0;i<16;++i){
      int nn = i*4 + (tid>>6), kk = tid&63;
      if (n0+nn < Nout) dst[doff + (size_t)(n0+nn)*ldd + k0+kk] = (u16)tl[nn*66+kk];
    }
  } else {
    #pragma unroll
    for (int i=0;i<16;++i){
      int nn = i*4 + (tid>>6), kk = tid&63;
      if (n0+nn < Nout) dst[doff + (size_t)(n0+nn)*ldd + k0+kk] = 0;
    }
  }
}

// ---------- AGAN v3: hm and agg via MFMA, Bp in regs, fsum from acc regs ----------
__global__ __launch_bounds__(256) void agan_kernel(
    const float* __restrict__ x, const float* __restrict__ w_in, const float* __restrict__ b_in,
    const u16* __restrict__ bpt, const float* __restrict__ a_src, const float* __restrict__ a_dst,
    u16* __restrict__ fsum_out)
{
  int bt = blockIdx.x;
  int tid = threadIdx.x;
  int lane = tid & 63, wid = tid >> 6;
  int lr = lane & 15, lq = lane >> 4;
  __shared__ float xv[NNODE][4];
  __shared__ __align__(16) short sh0[32*136];     // h0 bf16 [32 n][128 i] pad136
  __shared__ __align__(16) short hmT[128*40];     // hm^T bf16 [128 ho][32 n] pad40
  __shared__ __align__(16) short alb[4*32*40];    // alpha bf16 [h][32 i][32 j] pad40
  __shared__ float sd[2][NNODE][4];
  __shared__ float sm[4][NNODE];
  // Bp B-fragments in regs (same for all blocks, L2-resident)
  short8 bp[4][2];
  #pragma unroll
  for (int ks=0;ks<4;++ks)
    #pragma unroll
    for (int ct=0;ct<2;++ct)
      bp[ks][ct] = *(const short8*)(bpt + (size_t)(wid*32+ct*16+lr)*128 + ks*32 + lq*8);
  if (tid < NNODE*3) xv[tid/3][tid%3] = x[(size_t)bt*63 + tid];
  __syncthreads();
  // h0 = relu(x @ w_in + b_in), rows >=21 zeroed
  for (int idx = tid; idx < 32*128; idx += 256) {
    int n = idx >> 7, i = idx & 127;
    float v = 0.f;
    if (n < NNODE)
      v = fmaxf(b_in[i] + xv[n][0]*w_in[i] + xv[n][1]*w_in[128+i] + xv[n][2]*w_in[256+i], 0.f);
    sh0[n*136 + i] = (short)f2bf(v);
  }
  __syncthreads();
  // hm = h0 @ Bp -> hmT (bf16)
  {
    f32x4 g00={},g01={},g10={},g11={};
    #pragma unroll
    for (int ks=0;ks<4;++ks){
      short8 a0 = *(const short8*)&sh0[(lr   )*136 + ks*32 + lq*8];
      short8 a1 = *(const short8*)&sh0[(16+lr)*136 + ks*32 + lq*8];
      g00 = __builtin_amdgcn_mfma_f32_16x16x32_bf16(a0, bp[ks][0], g00, 0,0,0);
      g01 = __builtin_amdgcn_mfma_f32_16x16x32_bf16(a0, bp[ks][1], g01, 0,0,0);
      g10 = __builtin_amdgcn_mfma_f32_16x16x32_bf16(a1, bp[ks][0], g10, 0,0,0);
      g11 = __builtin_amdgcn_mfma_f32_16x16x32_bf16(a1, bp[ks][1], g11, 0,0,0);
    }
    f32x4 gg[2][2] = {{g00,g01},{g10,g11}};
    #pragma unroll
    for (int mt=0;mt<2;++mt)
      #pragma unroll
      for (int ct=0;ct<2;++ct){
        int col = wid*32 + ct*16 + lr;
        int row0 = mt*16 + lq*4;
        u32 w0 = (u32)f2bf(gg[mt][ct][0]) | ((u32)f2bf(gg[mt][ct][1])<<16);
        u32 w1 = (u32)f2bf(gg[mt][ct][2]) | ((u32)f2bf(gg[mt][ct][3])<<16);
        *(uint2*)&hmT[col*40 + row0] = make_uint2(w0,w1);
      }
  }
  __syncthreads();
  // src/dst dots
  if (tid < 168) {
    int which = tid >= 84;
    int r = tid - which*84;
    int n = r >> 2, h = r & 3;
    const float* av = (which ? a_dst : a_src) + h*32;
    float s = 0.f;
    #pragma unroll
    for (int o=0;o<32;++o){ int oo=(o+tid)&31; s += bf2f((u16)hmT[(h*32+oo)*40 + n])*av[oo]; }
    sd[which][n][h] = s;
  }
  __syncthreads();
  // row max
  if (tid < 84) {
    int i = tid >> 2, h = tid & 3;
    float sv = sd[0][i][h], m = -1e30f;
    #pragma unroll
    for (int j=0;j<NNODE;++j){
      float e = sv + sd[1][j][h];
      e = e>=0.f ? e : 0.2f*e;
      m = fmaxf(m,e);
    }
    sm[h][i] = m;
  }
  __syncthreads();
  // exp (parallel over all threads), j padded to 32 with 0
  for (int idx = tid; idx < 84*32; idx += 256) {
    int j = idx & 31, ih = idx >> 5;
    int i = ih >> 2, h = ih & 3;
    float ex = 0.f;
    if (j < NNODE){
      float e = sd[0][i][h] + sd[1][j][h];
      e = e>=0.f ? e : 0.2f*e;
      ex = __expf(e - sm[h][i]);
    }
    alb[(h*32+i)*40 + j] = (short)f2bf(ex);
  }
  __syncthreads();
  // normalize rows
  if (tid < 84) {
    int i = tid >> 2, h = tid & 3;
    short* row = &alb[(h*32+i)*40];
    float s = 0.f;
    #pragma unroll
    for (int j=0;j<NNODE;++j) s += bf2f((u16)row[j]);
    float inv = 1.f/s;
    #pragma unroll
    for (int j=0;j<NNODE;++j) row[j] = (short)f2bf(bf2f((u16)row[j])*inv);
  }
  __syncthreads();
  // agg = alpha_h @ hm_h via MFMA (wave wid = head), fused feat+fsum epilogue
  {
    int h = wid;
    short8 a0 = *(const short8*)&alb[(h*32 + lr     )*40 + lq*8];
    short8 a1 = *(const short8*)&alb[(h*32 + 16 + lr)*40 + lq*8];
    short8 b0 = *(const short8*)&hmT[(h*32 + lr     )*40 + lq*8];
    short8 b1 = *(const short8*)&hmT[(h*32 + 16 + lr)*40 + lq*8];
    f32x4 c00={},c01={},c10={},c11={};
    c00 = __builtin_amdgcn_mfma_f32_16x16x32_bf16(a0,b0,c00,0,0,0);
    c01 = __builtin_amdgcn_mfma_f32_16x16x32_bf16(a0,b1,c01,0,0,0);
    c10 = __builtin_amdgcn_mfma_f32_16x16x32_bf16(a1,b0,c10,0,0,0);
    c11 = __builtin_amdgcn_mfma_f32_16x16x32_bf16(a1,b1,c11,0,0,0);
    f32x4 cc[2][2] = {{c00,c01},{c10,c11}};
    #pragma unroll
    for (int ct=0; ct<2; ++ct){
      int col = h*32 + ct*16 + lr;
      float s = 0.f;
      #pragma unroll
      for (int mt=0; mt<2; ++mt)
        #pragma unroll
        for (int r=0;r<4;++r){
          int n = mt*16 + lq*4 + r;
          if (n < NNODE)
            s += fmaxf(bf2f((u16)sh0[n*136+col]) + cc[mt][ct][r], 0.f);
        }
      s += __shfl_xor(s, 16);
      s += __shfl_xor(s, 32);
      if (lq == 0) fsum_out[(size_t)bt*128 + col] = f2bf(s*(1.f/21.f));
    }
  }
}

// ---------- bf16 MFMA GEMM: C[M,N] = A[M,K(lda)] @ BT[N][K]^T ----------
template<int ACC, int BIAS, int RELU, int SM, int POOL>
__global__ __launch_bounds__(256) void gemm_bf16_kernel(
    const u16* __restrict__ A, const u16* __restrict__ BT, const float* __restrict__ bias,
    float* __restrict__ C, u16* __restrict__ C2, float* __restrict__ pool,
    int M, int N, int K, int lda)
{
  __shared__ __align__(16) short Asl[4096];
  __shared__ __align__(16) short Bsl[4096];
  int tid = threadIdx.x;
  int lane = tid & 63, wid = tid >> 6;
  int wm = wid >> 1, wn = wid & 1;
  int row0 = blockIdx.y*128, col0 = blockIdx.x*128;
  const u16* Ab = A  + (size_t)row0*lda;
  const u16* Bb = BT + (size_t)col0*K;
  f32x4 acc[4][4] = {};
  int c0 = tid;
  int c1 = 256 + tid;
  int lrow = lane & 15, lk = (lane>>4)*8;
  for (int k0 = 0; k0 < K; k0 += 32) {
    gload16(Ab + (size_t)(c0>>2)*lda + k0 + (c0&3)*8, (u16*)Asl + (wid<<9));
    gload16(Ab + (size_t)(c1>>2)*lda + k0 + (c1&3)*8, (u16*)Asl + 2048 + (wid<<9));
    gload16(Bb + (size_t)(c0>>2)*K + k0 + (c0&3)*8, (u16*)Bsl + (wid<<9));
    gload16(Bb + (size_t)(c1>>2)*K + k0 + (c1&3)*8, (u16*)Bsl + 2048 + (wid<<9));
    __syncthreads();
    short8 a[4], b[4];
    #pragma unroll
    for (int i=0;i<4;++i) a[i] = *(const short8*)&Asl[(wm*64 + i*16 + lrow)*32 + lk];
    #pragma unroll
    for (int j=0;j<4;++j) b[j] = *(const short8*)&Bsl[(wn*64 + j*16 + lrow)*32 + lk];
    #pragma unroll
    for (int i=0;i<4;++i)
      #pragma unroll
      for (int j=0;j<4;++j)
        acc[i][j] = __builtin_amdgcn_mfma_f32_16x16x32_bf16(a[i], b[j], acc[i][j], 0, 0, 0);
    __syncthreads();
  }
  float colsum[4] = {0.f,0.f,0.f,0.f};
  #pragma unroll
  for (int i=0;i<4;++i) {
    int row = row0 + wm*64 + i*16 + (lane>>4)*4;
    #pragma unroll
    for (int j=0;j<4;++j) {
      int col = col0 + wn*64 + j*16 + (lane&15);
      if (col < N) {
        float bv = BIAS ? bias[col] : 0.f;
        #pragma unroll
        for (int r=0;r<4;++r) {
          float v = acc[i][j][r] + bv;
          if (RELU) v = fmaxf(v, 0.f);
          size_t o = (size_t)(row+r)*N + col;
          if (ACC)           C[o] += v;
          else if (SM == 0)  C[o]  = v;
          else if (SM == 1)  C2[o] = f2bf(v);
          else             { C[o]  = v; C2[o] = f2bf(v); }
          if (POOL) colsum[j] += v;
        }
      }
    }
  }
  if (POOL) {
    float* red = (float*)Asl;
    #pragma unroll
    for (int j=0;j<4;++j) red[tid*4+j] = colsum[j];
    __syncthreads();
    if (tid < 128) {
      int wn_ = tid >> 6, j_ = (tid >> 4) & 3, l15 = tid & 15;
      float s = 0.f;
      #pragma unroll
      for (int wm_=0;wm_<2;++wm_)
        #pragma unroll
        for (int g=0;g<4;++g)
          s += red[(((wm_*2+wn_)*64) + g*16 + l15)*4 + j_];
      pool[(size_t)blockIdx.y*256 + blockIdx.x*128 + tid] = s * (1.f/256.f);
    }
  }
}

// ---------- LayerNorm -> bf16 ----------
__global__ __launch_bounds__(256) void ln_kernel(const float* __restrict__ x,
    const float* __restrict__ w, u16* __restrict__ o)
{
  int row = blockIdx.x*4 + (threadIdx.x>>6);
  int lane = threadIdx.x & 63;
  float4 v = *(const float4*)(x + (size_t)row*DMODEL + lane*4);
  float s = v.x+v.y+v.z+v.w;
  #pragma unroll
  for (int off=32;off>=1;off>>=1) s += __shfl_xor(s, off);
  float mu = s * (1.f/256.f);
  float d0=v.x-mu, d1=v.y-mu, d2=v.z-mu, d3=v.w-mu;
  float q = d0*d0+d1*d1+d2*d2+d3*d3;
  #pragma unroll
  for (int off=32;off>=1;off>>=1) q += __shfl_xor(q, off);
  float inv = 1.f/sqrtf(q*(1.f/256.f) + 1e-5f);
  float4 wv = *(const float4*)(w + lane*4);
  u32 lo = (u32)f2bf(d0*inv*wv.x) | ((u32)f2bf(d1*inv*wv.y) << 16);
  u32 hi = (u32)f2bf(d2*inv*wv.z) | ((u32)f2bf(d3*inv*wv.w) << 16);
  uint2 pk; pk.x = lo; pk.y = hi;
  *(uint2*)(o + (size_t)row*DMODEL + lane*4) = pk;
}

// ---------- depthwise conv + silu, both dirs (xz layout [u0 u1 z0 z1]) ----------
__global__ __launch_bounds__(256) void conv_kernel(const u16* __restrict__ xz,
    const float* __restrict__ cw, const float* __restrict__ cb,
    u16* __restrict__ ucv)
{
  int idx = blockIdx.x*256 + threadIdx.x;          // BT*1024
  int du = idx & 1023, dir = du >> 9, dd = du & 511;
  int bt = idx >> 10, t = bt & 255;
  const u16* up = xz + (size_t)(bt - t)*2048 + dir*512 + dd;
  const float* cwd = cw + (size_t)dir*2048 + dd*4;
  float s = cb[dir*512 + dd];
  if (dir == 0) {
    #pragma unroll
    for (int k=0;k<4;++k) { int tk = t-3+k; if (tk >= 0) s += cwd[k]*bf2f(up[(size_t)tk*2048]); }
  } else {
    #pragma unroll
    for (int j=0;j<4;++j) { int tk = t+j; if (tk < TT) s += cwd[3-j]*bf2f(up[(size_t)tk*2048]); }
  }
  ucv[(size_t)bt*1024 + dir*512 + dd] = f2bf(siluf(s));
}

// ---------- 3-phase chunked selective scan, both dirs in one dispatch ----------
// grid (64 b, 8 c, 16 = d*8+g); h-state stored bf16
template<int FINAL>
__global__ __launch_bounds__(64) void scan_phase_kernel(
    const u16* __restrict__ ucv, const float* __restrict__ xd, const u16* __restrict__ xz,
    const float* __restrict__ dtw, const float* __restrict__ dtb,
    const float* __restrict__ alog, const float* __restrict__ dvec,
    const u16* __restrict__ hin, float* __restrict__ Sdt, u16* __restrict__ hend,
    u16* __restrict__ yout)
{
  int b = blockIdx.x, c = blockIdx.y, gz = blockIdx.z;
  int d = gz >> 3, g = gz & 7;
  int lane = threadIdx.x;
  int dd = (g<<6) + lane;
  float wdt[16], Av[16], h[16];
  #pragma unroll
  for (int s=0;s<16;++s){
    wdt[s] = dtw[d*8192 + s*512 + dd];
    Av[s]  = -__expf(alog[d*8192 + dd*16 + s]);
  }
  float bdt = dtb[d*512 + dd];
  size_t co = (((size_t)b*8+c)*2 + d)*512 + dd;
  if (FINAL) {
    #pragma unroll
    for (int s=0;s<16;++s) h[s] = bf2f(hin[co*16+s]);
  } else {
    #pragma unroll
    for (int s=0;s<16;++s) h[s] = 0.f;
  }
  __shared__ float sxd[32][48];
  __shared__ u16 su[32][64];
  __shared__ u16 sz[(FINAL?32:1)][64];
  #pragma unroll 4
  for (int q=0;q<32;++q) {
    int p = (c<<5)+q;
    int t = d ? 255-p : p;
    size_t row = (size_t)b*TT + t;
    if (lane < 48) sxd[q][lane] = xd[row*128 + d*64 + lane];
    su[q][lane] = ucv[row*1024 + d*512 + dd];
    if (FINAL) sz[q][lane] = xz[row*2048 + 1024 + d*512 + dd];
  }
  __syncthreads();
  float S = 0.f;
  float Dv = FINAL ? dvec[d*512 + dd] : 0.f;
  #pragma unroll 1
  for (int q=0;q<32;++q) {
    const float* sr = sxd[q];
    float p0=0.f,p1=0.f,p2=0.f,p3=0.f;
    #pragma unroll
    for (int r=0;r<16;r+=4){
      p0 = fmaf(sr[r+0],wdt[r+0],p0);
      p1 = fmaf(sr[r+1],wdt[r+1],p1);
      p2 = fmaf(sr[r+2],wdt[r+2],p2);
      p3 = fmaf(sr[r+3],wdt[r+3],p3);
    }
    float dtp = bdt + ((p0+p1)+(p2+p3));
    float dt = fmaxf(dtp,0.f) + __logf(1.f + __expf(-fabsf(dtp)));
    float uc = bf2f(su[q][lane]);
    float dtu = dt*uc;
    if (!FINAL) S += dt;
    float y0=0.f, y1=0.f;
    #pragma unroll
    for (int s=0;s<16;s+=2){
      float dA0 = __expf(dt*Av[s]);
      float dA1 = __expf(dt*Av[s+1]);
      h[s]   = fmaf(dA0, h[s],   dtu*sr[16+s]);
      h[s+1] = fmaf(dA1, h[s+1], dtu*sr[16+s+1]);
      if (FINAL){ y0 = fmaf(h[s],sr[32+s],y0); y1 = fmaf(h[s+1],sr[32+s+1],y1); }
    }
    if (FINAL){
      float zc = bf2f(sz[q][lane]);
      float yv = (y0+y1) + uc*Dv;
      float sg = zc / (1.f + __expf(-zc));
      int p4 = (c<<5)+q;
      int t4 = d ? 255-p4 : p4;
      yout[((size_t)b*TT+t4)*2048 + d*512 + dd] = f2bf(yv*sg);
    }
  }
  if (!FINAL){
    Sdt[co] = S;
    #pragma unroll
    for (int s=0;s<16;++s) hend[co*16+s] = f2bf(h[s]);
  }
}

// Phase B: serial combine across 8 chunks (both dirs), in-place hend -> hin.
__global__ __launch_bounds__(256) void scanB_kernel(
    const float* __restrict__ Sdt, u16* __restrict__ hst, const float* __restrict__ alog)
{
  int idx = blockIdx.x*256 + threadIdx.x;   // 65536 = b*1024 + d*512 + dd
  int b = idx >> 10, d = (idx >> 9) & 1, dd = idx & 511;
  float Av[16];
  #pragma unroll
  for (int s=0;s<16;++s) Av[s] = -__expf(alog[d*8192 + dd*16 + s]);
  float h[16];
  #pragma unroll
  for (int s=0;s<16;++s) h[s] = 0.f;
  for (int c=0;c<8;++c){
    size_t o = ((((size_t)b*8+c)*2 + d)*512 + dd)*16;
    float S = Sdt[(((size_t)b*8+c)*2 + d)*512 + dd];
    float he[16];
    #pragma unroll
    for (int s=0;s<16;++s) he[s] = bf2f(hst[o+s]);
    #pragma unroll
    for (int s=0;s<16;++s) hst[o+s] = f2bf(h[s]);
    #pragma unroll
    for (int s=0;s<16;++s) h[s] = fmaf(__expf(Av[s]*S), h[s], he[s]);
  }
}

// ---------- fused head: temporal mean -> emb (to out) -> sign logits ----------
__global__ __launch_bounds__(256) void head_kernel(const float* __restrict__ xx,
    const float* __restrict__ wsgn, const float* __restrict__ bsgn,
    const float* __restrict__ protos, float* __restrict__ out)
{
  int b = blockIdx.x, tid = threadIdx.x;
  __shared__ float mt[256];
  __shared__ __align__(16) float e[256];
  __shared__ float red[4];
  float s0=0.f,s1=0.f,s2=0.f,s3=0.f;
  for (int t=0;t<TT;t+=4){
    s0 += xx[((size_t)b*TT+t  )*DMODEL + tid];
    s1 += xx[((size_t)b*TT+t+1)*DMODEL + tid];
    s2 += xx[((size_t)b*TT+t+2)*DMODEL + tid];
    s3 += xx[((size_t)b*TT+t+3)*DMODEL + tid];
  }
  mt[tid] = (s0+s1+s2+s3)*(1.f/256.f);
  __syncthreads();
  float acc = bsgn[tid];
  for (int i=0;i<DMODEL;++i) acc += mt[i]*wsgn[i*DMODEL + tid];
  e[tid] = acc;
  out[128000 + b*DMODEL + tid] = acc;
  __syncthreads();
  float v = acc*acc;
  #pragma unroll
  for (int off=32;off>=1;off>>=1) v += __shfl_xor(v, off);
  if ((tid&63)==0) red[tid>>6] = v;
  __syncthreads();
  float esc = 1.f/(sqrtf(red[0]+red[1]+red[2]+red[3]) + 1e-8f);
  for (int p = tid; p < NSIGNS; p += 256) {
    const float* pr = protos + (size_t)p*256;
    float dot=0.f, ps=0.f;
    for (int i=0;i<256;i+=4) {
      float4 pv = *(const float4*)(pr+i);
      float4 ev = *(const float4*)(e+i);
      dot += pv.x*ev.x + pv.y*ev.y + pv.z*ev.z + pv.w*ev.w;
      ps  += pv.x*pv.x + pv.y*pv.y + pv.z*pv.z + pv.w*pv.w;
    }
    out[(size_t)b*NSIGNS + p] = dot*esc/(sqrtf(ps)+1e-8f)*(1.f/0.07f);
  }
}

__global__ __launch_bounds__(256) void sims_kernel(const float* __restrict__ part,
    const float* __restrict__ phs, const float* __restrict__ ploc,
    const float* __restrict__ pmov, const float* __restrict__ pori,
    float* __restrict__ out)
{
  int b = blockIdx.x, tid = threadIdx.x;
  __shared__ float pc[256];
  __shared__ float nk[4];
  pc[tid] = part[(size_t)(2*b)*256 + tid] + part[(size_t)(2*b+1)*256 + tid];
  __syncthreads();
  if (tid < 4) {
    float ss = 0.f;
    for (int i=0;i<64;++i){ float q = pc[tid*64+i]; ss += q*q; }
    nk[tid] = 1.f/(sqrtf(ss)+1e-8f);
  }
  __syncthreads();
  if (tid < 88) {
    int k, pi; const float* P; size_t off; int npk;
    if (tid < 40)      { k=0; pi=tid;    P=phs;  off=144384; npk=40; }
    else if (tid < 60) { k=1; pi=tid-40; P=ploc; off=146944; npk=20; }
    else if (tid < 80) { k=2; pi=tid-60; P=pmov; off=148224; npk=20; }
    else               { k=3; pi=tid-80; P=pori; off=149504; npk=8;  }
    float dot=0.f, ps=0.f;
    for (int i=0;i<64;++i){ float pv = P[pi*64+i]; dot += pv*pc[k*64+i]; ps += pv*pv; }
    out[off + (size_t)b*npk + pi] = dot*nk[k]/(sqrtf(ps)+1e-8f)*(1.f/0.07f);
  }
}

extern "C" void kernel_launch(void* const* d_in, const int* in_sizes, int n_in,
                              void* d_out, int out_size, void* d_ws, size_t ws_size,
                              hipStream_t stream) {
  const float* x         = (const float*)d_in[0];
  const float* w_in      = (const float*)d_in[1];
  const float* b_in      = (const float*)d_in[2];
  const float* w_gat     = (const float*)d_in[3];
  const float* a_src     = (const float*)d_in[4];
  const float* a_dst     = (const float*)d_in[5];
  const float* w_out     = (const float*)d_in[6];
  const float* b_out     = (const float*)d_in[7];
  const float* pdm_w     = (const float*)d_in[8];
  const float* pdm_b     = (const float*)d_in[9];
  const float* w_fuse    = (const float*)d_in[10];
  const float* b_fuse    = (const float*)d_in[11];
  const float* ln_w      = (const float*)d_in[12];
  const float* in_proj   = (const float*)d_in[13];
  const float* conv_w    = (const float*)d_in[14];
  const float* conv_b    = (const float*)d_in[15];
  const float* x_proj    = (const float*)d_in[16];
  const float* dt_w      = (const float*)d_in[17];
  const float* dt_b      = (const float*)d_in[18];
  const float* A_log     = (const float*)d_in[19];
  const float* Dvec      = (const float*)d_in[20];
  const float* out_proj  = (const float*)d_in[21];
  const float* w_sign    = (const float*)d_in[22];
  const float* b_sign    = (const float*)d_in[23];
  const float* protos    = (const float*)d_in[24];
  const float* phs       = (const float*)d_in[25];
  const float* ploc      = (const float*)d_in[26];
  const float* pmov      = (const float*)d_in[27];
  const float* pori      = (const float*)d_in[28];
  float* out = (float*)d_out;

  // ---- ws layout ----
  float* wsf = (float*)d_ws;
  const size_t f_xx    = 0;                          // 16384*256
  const size_t f_xdbl  = f_xx   + 4194304;           // 16384*128
  const size_t f_part  = f_xdbl + 2097152;           // 128*256
  const size_t f_end   = f_part + 32768;
  u16* wsu = (u16*)(wsf + f_end);
  const size_t u_xn    = 0;                          // 16384*256
  const size_t u_xz    = u_xn   + 4194304;           // 16384*2048 [u0 u1 z0 z1]; y -> u slots
  const size_t u_ucv   = u_xz   + 33554432;          // 16384*1024
  const size_t u_fsum  = u_ucv  + 16777216;          // 16384*128
  const size_t u_spat  = u_fsum + 2097152;           // 16384*256
  const size_t u_comps = u_spat + 4194304;           // 16384*256
  const size_t u_w     = u_comps+ 4194304;           // 3,850,240 weights
  u16* wiT = wsu + u_w;
  u16* woT = wiT + 2097152;
  u16* wxT = woT + 1048576;
  u16* wA  = wxT + 524288;
  u16* wB  = wA  + 32768;
  u16* wF  = wB  + 65536;
  u16* wBp = wF  + 65536;
  // scan scratch aliases fsum/spat/comps (dead during SSM loop): 16.8MB bf16 hstate + 2MB f32 Sdt
  u16*   hstate = wsu + u_fsum;                      // 64*8*2*512*16 u16
  float* sdt    = (float*)(wsu + u_fsum + 8388608);  // 64*8*2*512 f32

  transpose_w_kernel<<<944, 256, 0, stream>>>(in_proj, out_proj, x_proj, w_out, pdm_w, w_fuse, w_gat, wsu + u_w);
  agan_kernel<<<BTT, 256, 0, stream>>>(x, w_in, b_in, wBp, a_src, a_dst, wsu + u_fsum);
  gemm_bf16_kernel<0,1,0,1,0><<<dim3(2,128), 256, 0, stream>>>(wsu+u_fsum, wA, b_out, nullptr, wsu+u_spat, nullptr, BTT, 256, 128, 128);
  gemm_bf16_kernel<0,1,1,1,1><<<dim3(2,128), 256, 0, stream>>>(wsu+u_spat, wB, pdm_b, nullptr, wsu+u_comps, wsf+f_part, BTT, 256, 256, 256);
  gemm_bf16_kernel<0,1,0,0,0><<<dim3(2,128), 256, 0, stream>>>(wsu+u_comps, wF, b_fuse, wsf+f_xx, nullptr, nullptr, BTT, 256, 256, 256);

  for (int l = 0; l < 4; ++l) {
    ln_kernel<<<BTT/4, 256, 0, stream>>>(wsf+f_xx, ln_w + l*DMODEL, wsu+u_xn);
    gemm_bf16_kernel<0,0,0,1,0><<<dim3(16,128), 256, 0, stream>>>(wsu+u_xn, wiT + (size_t)l*524288,
        nullptr, nullptr, wsu+u_xz, nullptr, BTT, 2048, 256, 256);
    conv_kernel<<<BTT*1024/256, 256, 0, stream>>>(wsu+u_xz, conv_w + (size_t)l*4096,
        conv_b + (size_t)l*1024, wsu+u_ucv);
    gemm_bf16_kernel<0,0,0,0,0><<<dim3(1,128), 256, 0, stream>>>(wsu+u_ucv, wxT + (size_t)l*131072,
        nullptr, wsf+f_xdbl, nullptr, nullptr, BTT, 128, 1024, 1024);
    scan_phase_kernel<0><<<dim3(64,8,16), 64, 0, stream>>>(wsu+u_ucv, wsf+f_xdbl, nullptr,
        dt_w + (size_t)l*16384, dt_b + (size_t)l*1024,
        A_log + (size_t)l*16384, nullptr, nullptr, sdt, hstate, nullptr);
    scanB_kernel<<<256, 256, 0, stream>>>(sdt, hstate, A_log + (size_t)l*16384);
    scan_phase_kernel<1><<<dim3(64,8,16), 64, 0, stream>>>(wsu+u_ucv, wsf+f_xdbl, wsu+u_xz,
        dt_w + (size_t)l*16384, dt_b + (size_t)l*1024,
        A_log + (size_t)l*16384, Dvec + (size_t)l*1024,
        hstate, nullptr, nullptr, wsu+u_xz);
    gemm_bf16_kernel<1,0,0,0,0><<<dim3(2,128), 256, 0, stream>>>(wsu+u_xz, woT + (size_t)l*262144,
        nullptr, wsf+f_xx, nullptr, nullptr, BTT, 256, 1024, 2048);
  }

  head_kernel<<<64, 256, 0, stream>>>(wsf+f_xx, w_sign, b_sign, protos, out);
  sims_kernel<<<64, 256, 0, stream>>>(wsf+f_part, phs, ploc, pmov, pori, out);
  (void)in_sizes; (void)n_in; (void)out_size; (void)ws_size;
}

// Round 6
// 1396.240 us; speedup vs baseline: 4.0605x; 1.3466x over previous
//
#include <hip/hip_runtime.h>
#include <math.h>

#define BB 64
#define TT 256
#define NNODE 21
#define HID 128
#define DMODEL 256
#define DINNER 512
#define NSIGNS 2000
#define BTT (BB*TT)   // 16384

typedef unsigned short u16;
typedef unsigned int u32;
typedef __attribute__((ext_vector_type(8))) short short8;
typedef __attribute__((ext_vector_type(4))) float f32x4;

__device__ __forceinline__ float siluf(float x){ return x/(1.f+expf(-x)); }
__device__ __forceinline__ u16 f2bf(float x){ u32 u = __float_as_uint(x); u32 r = u + 0x7FFFu + ((u>>16)&1u); return (u16)(r>>16); }
__device__ __forceinline__ float bf2f(u16 u){ return __uint_as_float(((u32)u)<<16); }
__device__ __forceinline__ void gload16(const u16* g, u16* l){
  __builtin_amdgcn_global_load_lds((const __attribute__((address_space(1))) void*)g,
                                   (__attribute__((address_space(3))) void*)l, 16, 0, 0);
}

// ---------- tiled weight transpose -> bf16 [N][K] layouts ----------
__global__ __launch_bounds__(256) void transpose_w_kernel(
    const float* __restrict__ in_proj, const float* __restrict__ out_proj,
    const float* __restrict__ x_proj, const float* __restrict__ w_out,
    const float* __restrict__ pdm_w, const float* __restrict__ w_fuse,
    const float* __restrict__ w_gat, u16* __restrict__ dst)
{
  __shared__ short tl[64*66];
  int bx = blockIdx.x, tid = threadIdx.x;
  const float* S = nullptr; size_t soff = 0; int lds = 0, Nsrc = 0;
  size_t doff = 0; int ldd = 0, Nout = 0;
  int tn = 0, tk = 0;
  bool zero = false;
  if (bx < 512) {                       // in_projT
    int j = bx >> 5, tt = bx & 31;
    int l = j >> 2, d = j & 1, zh = (j >> 1) & 1;
    tn = tt >> 2; tk = tt & 3;
    S = in_proj; soff = ((size_t)(l*2+d)*256)*1024 + zh*512; lds = 1024; Nsrc = 512;
    doff = (size_t)l*524288 + (size_t)(zh*1024 + d*512)*256; ldd = 256; Nout = 512;
  } else if (bx < 768) {                // out_projT
    int j = (bx-512) >> 5, tt = (bx-512) & 31;
    int l = j >> 1, d = j & 1;
    tn = tt >> 3; tk = tt & 7;
    S = out_proj; soff = (size_t)(l*2+d)*512*256; lds = 256; Nsrc = 256;
    doff = 2097152 + (size_t)l*262144 + d*512; ldd = 1024; Nout = 256;
  } else if (bx < 896) {                // x_projT (+ zero-fill of off-d k-half)
    int j = (bx-768) >> 3, tt = (bx-768) & 7;
    int l = j >> 2, sub = j & 3;
    tn = 0; tk = tt;
    if (sub < 2) {
      int d = sub;
      S = x_proj; soff = (size_t)(l*2+d)*512*48; lds = 48; Nsrc = 48;
      doff = 3145728 + (size_t)l*131072 + (size_t)(d*64)*1024 + d*512; ldd = 1024; Nout = 64;
    } else {
      int d = sub-2; zero = true;
      doff = 3145728 + (size_t)l*131072 + (size_t)(d*64)*1024 + (1-d)*512; ldd = 1024; Nout = 64;
    }
  } else if (bx < 904) {                // w_outT
    int tt = bx-896; tn = tt>>1; tk = tt&1;
    S = w_out; soff = 0; lds = 256; Nsrc = 256;
    doff = 3670016; ldd = 128; Nout = 256;
  } else if (bx < 920) {                // wbigT (pdm_w)
    int j = (bx-904)>>2, tt = (bx-904)&3;
    tn = 0; tk = tt;
    S = pdm_w; soff = (size_t)j*16384; lds = 64; Nsrc = 64;
    doff = 3702784 + (size_t)j*16384; ldd = 256; Nout = 64;
  } else if (bx < 936) {                // w_fuseT
    int tt = bx-920; tn = tt>>2; tk = tt&3;
    S = w_fuse; soff = 0; lds = 256; Nsrc = 256;
    doff = 3768320; ldd = 256; Nout = 256;
  } else {                              // BpT
    int j = (bx-936)>>1, tt = (bx-936)&1;
    tn = 0; tk = tt;
    S = w_gat; soff = (size_t)j*4096; lds = 32; Nsrc = 32;
    doff = 3833856 + (size_t)j*4096; ldd = 128; Nout = 32;
  }
  int n0 = tn*64, k0 = tk*64;
  if (!zero) {
    #pragma unroll
    for (int i=0;i<16;++i){
      int kk = i*4 + (tid>>6), nn = tid&63;
      float v = (n0+nn < Nsrc) ? S[soff + (size_t)(k0+kk)*lds + n0+nn] : 0.f;
      tl[nn*66+kk] = (short)f2bf(v);
    }
    __syncthreads();
    #pragma unroll
    for (int i=0;i<16;++i){
      int nn = i*4 + (tid>>6), kk = tid&63;
      if (n0+nn < Nout) dst[doff + (size_t)(n0+nn)*ldd + k0+kk] = (u16)tl[nn*66+kk];
    }
  } else {
    #pragma unroll
    for (int i=0;i<16;++i){
      int nn = i*4 + (tid>>6), kk = tid&63;
      if (n0+nn < Nout) dst[doff + (size_t)(n0+nn)*ldd + k0+kk] = 0;
    }
  }
}

// ---------- AGAN: hm and agg via MFMA, Bp in regs, fsum from acc regs ----------
__global__ __launch_bounds__(256) void agan_kernel(
    const float* __restrict__ x, const float* __restrict__ w_in, const float* __restrict__ b_in,
    const u16* __restrict__ bpt, const float* __restrict__ a_src, const float* __restrict__ a_dst,
    u16* __restrict__ fsum_out)
{
  int bt = blockIdx.x;
  int tid = threadIdx.x;
  int lane = tid & 63, wid = tid >> 6;
  int lr = lane & 15, lq = lane >> 4;
  __shared__ float xv[NNODE][4];
  __shared__ __align__(16) short sh0[32*136];
  __shared__ __align__(16) short hmT[128*40];
  __shared__ __align__(16) short alb[4*32*40];
  __shared__ float sd[2][NNODE][4];
  __shared__ float sm[4][NNODE];
  short8 bp[4][2];
  #pragma unroll
  for (int ks=0;ks<4;++ks)
    #pragma unroll
    for (int ct=0;ct<2;++ct)
      bp[ks][ct] = *(const short8*)(bpt + (size_t)(wid*32+ct*16+lr)*128 + ks*32 + lq*8);
  if (tid < NNODE*3) xv[tid/3][tid%3] = x[(size_t)bt*63 + tid];
  __syncthreads();
  for (int idx = tid; idx < 32*128; idx += 256) {
    int n = idx >> 7, i = idx & 127;
    float v = 0.f;
    if (n < NNODE)
      v = fmaxf(b_in[i] + xv[n][0]*w_in[i] + xv[n][1]*w_in[128+i] + xv[n][2]*w_in[256+i], 0.f);
    sh0[n*136 + i] = (short)f2bf(v);
  }
  __syncthreads();
  {
    f32x4 g00={},g01={},g10={},g11={};
    #pragma unroll
    for (int ks=0;ks<4;++ks){
      short8 a0 = *(const short8*)&sh0[(lr   )*136 + ks*32 + lq*8];
      short8 a1 = *(const short8*)&sh0[(16+lr)*136 + ks*32 + lq*8];
      g00 = __builtin_amdgcn_mfma_f32_16x16x32_bf16(a0, bp[ks][0], g00, 0,0,0);
      g01 = __builtin_amdgcn_mfma_f32_16x16x32_bf16(a0, bp[ks][1], g01, 0,0,0);
      g10 = __builtin_amdgcn_mfma_f32_16x16x32_bf16(a1, bp[ks][0], g10, 0,0,0);
      g11 = __builtin_amdgcn_mfma_f32_16x16x32_bf16(a1, bp[ks][1], g11, 0,0,0);
    }
    f32x4 gg[2][2] = {{g00,g01},{g10,g11}};
    #pragma unroll
    for (int mt=0;mt<2;++mt)
      #pragma unroll
      for (int ct=0;ct<2;++ct){
        int col = wid*32 + ct*16 + lr;
        int row0 = mt*16 + lq*4;
        u32 w0 = (u32)f2bf(gg[mt][ct][0]) | ((u32)f2bf(gg[mt][ct][1])<<16);
        u32 w1 = (u32)f2bf(gg[mt][ct][2]) | ((u32)f2bf(gg[mt][ct][3])<<16);
        *(uint2*)&hmT[col*40 + row0] = make_uint2(w0,w1);
      }
  }
  __syncthreads();
  if (tid < 168) {
    int which = tid >= 84;
    int r = tid - which*84;
    int n = r >> 2, h = r & 3;
    const float* av = (which ? a_dst : a_src) + h*32;
    float s = 0.f;
    #pragma unroll
    for (int o=0;o<32;++o){ int oo=(o+tid)&31; s += bf2f((u16)hmT[(h*32+oo)*40 + n])*av[oo]; }
    sd[which][n][h] = s;
  }
  __syncthreads();
  if (tid < 84) {
    int i = tid >> 2, h = tid & 3;
    float sv = sd[0][i][h], m = -1e30f;
    #pragma unroll
    for (int j=0;j<NNODE;++j){
      float e = sv + sd[1][j][h];
      e = e>=0.f ? e : 0.2f*e;
      m = fmaxf(m,e);
    }
    sm[h][i] = m;
  }
  __syncthreads();
  for (int idx = tid; idx < 84*32; idx += 256) {
    int j = idx & 31, ih = idx >> 5;
    int i = ih >> 2, h = ih & 3;
    float ex = 0.f;
    if (j < NNODE){
      float e = sd[0][i][h] + sd[1][j][h];
      e = e>=0.f ? e : 0.2f*e;
      ex = __expf(e - sm[h][i]);
    }
    alb[(h*32+i)*40 + j] = (short)f2bf(ex);
  }
  __syncthreads();
  if (tid < 84) {
    int i = tid >> 2, h = tid & 3;
    short* row = &alb[(h*32+i)*40];
    float s = 0.f;
    #pragma unroll
    for (int j=0;j<NNODE;++j) s += bf2f((u16)row[j]);
    float inv = 1.f/s;
    #pragma unroll
    for (int j=0;j<NNODE;++j) row[j] = (short)f2bf(bf2f((u16)row[j])*inv);
  }
  __syncthreads();
  {
    int h = wid;
    short8 a0 = *(const short8*)&alb[(h*32 + lr     )*40 + lq*8];
    short8 a1 = *(const short8*)&alb[(h*32 + 16 + lr)*40 + lq*8];
    short8 b0 = *(const short8*)&hmT[(h*32 + lr     )*40 + lq*8];
    short8 b1 = *(const short8*)&hmT[(h*32 + 16 + lr)*40 + lq*8];
    f32x4 c00={},c01={},c10={},c11={};
    c00 = __builtin_amdgcn_mfma_f32_16x16x32_bf16(a0,b0,c00,0,0,0);
    c01 = __builtin_amdgcn_mfma_f32_16x16x32_bf16(a0,b1,c01,0,0,0);
    c10 = __builtin_amdgcn_mfma_f32_16x16x32_bf16(a1,b0,c10,0,0,0);
    c11 = __builtin_amdgcn_mfma_f32_16x16x32_bf16(a1,b1,c11,0,0,0);
    f32x4 cc[2][2] = {{c00,c01},{c10,c11}};
    #pragma unroll
    for (int ct=0; ct<2; ++ct){
      int col = h*32 + ct*16 + lr;
      float s = 0.f;
      #pragma unroll
      for (int mt=0; mt<2; ++mt)
        #pragma unroll
        for (int r=0;r<4;++r){
          int n = mt*16 + lq*4 + r;
          if (n < NNODE)
            s += fmaxf(bf2f((u16)sh0[n*136+col]) + cc[mt][ct][r], 0.f);
        }
      s += __shfl_xor(s, 16);
      s += __shfl_xor(s, 32);
      if (lq == 0) fsum_out[(size_t)bt*128 + col] = f2bf(s*(1.f/21.f));
    }
  }
}

// ---------- bf16 MFMA GEMM, 128x128 tile, BK=64, XOR-swizzled LDS ----------
template<int ACC, int BIAS, int RELU, int SM, int POOL>
__global__ __launch_bounds__(256) void gemm_bf16_kernel(
    const u16* __restrict__ A, const u16* __restrict__ BT, const float* __restrict__ bias,
    float* __restrict__ C, u16* __restrict__ C2, float* __restrict__ pool,
    int M, int N, int K, int lda)
{
  __shared__ __align__(16) short Asl[8192];   // [128 rows][64 k], swizzled 16B slots
  __shared__ __align__(16) short Bsl[8192];
  int tid = threadIdx.x;
  int lane = tid & 63, wid = tid >> 6;
  int wm = wid >> 1, wn = wid & 1;
  int row0 = blockIdx.y*128, col0 = blockIdx.x*128;
  const u16* Ab = A  + (size_t)row0*lda;
  const u16* Bb = BT + (size_t)col0*K;
  f32x4 acc[4][4] = {};
  int lrow = lane & 15, lk = (lane>>4)*8;
  for (int k0 = 0; k0 < K; k0 += 64) {
    #pragma unroll
    for (int is=0; is<4; ++is){
      int li = is*256 + tid;
      int row = li >> 3;
      int c8  = (li & 7) ^ (row & 7);           // inverse-swizzle source
      gload16(Ab + (size_t)row*lda + k0 + c8*8, (u16*)Asl + ((is<<8)+(wid<<6))*8);
      gload16(Bb + (size_t)row*K   + k0 + c8*8, (u16*)Bsl + ((is<<8)+(wid<<6))*8);
    }
    __syncthreads();
    #pragma unroll
    for (int ksub=0; ksub<2; ++ksub){
      int slot = (ksub*32 + lk) >> 3;
      short8 a[4], b[4];
      #pragma unroll
      for (int i=0;i<4;++i){ int rr=wm*64+i*16+lrow; a[i]=*(const short8*)&Asl[rr*64+((slot^(rr&7))<<3)]; }
      #pragma unroll
      for (int j=0;j<4;++j){ int rr=wn*64+j*16+lrow; b[j]=*(const short8*)&Bsl[rr*64+((slot^(rr&7))<<3)]; }
      #pragma unroll
      for (int i=0;i<4;++i)
        #pragma unroll
        for (int j=0;j<4;++j)
          acc[i][j] = __builtin_amdgcn_mfma_f32_16x16x32_bf16(a[i], b[j], acc[i][j], 0, 0, 0);
    }
    __syncthreads();
  }
  float colsum[4] = {0.f,0.f,0.f,0.f};
  #pragma unroll
  for (int i=0;i<4;++i) {
    int row = row0 + wm*64 + i*16 + (lane>>4)*4;
    #pragma unroll
    for (int j=0;j<4;++j) {
      int col = col0 + wn*64 + j*16 + (lane&15);
      if (col < N) {
        float bv = BIAS ? bias[col] : 0.f;
        #pragma unroll
        for (int r=0;r<4;++r) {
          float v = acc[i][j][r] + bv;
          if (RELU) v = fmaxf(v, 0.f);
          size_t o = (size_t)(row+r)*N + col;
          if (ACC)           C[o] += v;
          else if (SM == 0)  C[o]  = v;
          else if (SM == 1)  C2[o] = f2bf(v);
          else             { C[o]  = v; C2[o] = f2bf(v); }
          if (POOL) colsum[j] += v;
        }
      }
    }
  }
  if (POOL) {
    float* red = (float*)Asl;
    #pragma unroll
    for (int j=0;j<4;++j) red[tid*4+j] = colsum[j];
    __syncthreads();
    if (tid < 128) {
      int wn_ = tid >> 6, j_ = (tid >> 4) & 3, l15 = tid & 15;
      float s = 0.f;
      #pragma unroll
      for (int wm_=0;wm_<2;++wm_)
        #pragma unroll
        for (int g=0;g<4;++g)
          s += red[(((wm_*2+wn_)*64) + g*16 + l15)*4 + j_];
      pool[(size_t)blockIdx.y*256 + blockIdx.x*128 + tid] = s * (1.f/256.f);
    }
  }
}

// ---------- BM=64 GEMM for x_proj: C[M,128] f32 = A[M,K] @ BT[128][K]^T ----------
__global__ __launch_bounds__(256) void gemm64_kernel(
    const u16* __restrict__ A, const u16* __restrict__ BT,
    float* __restrict__ C, int K, int lda)
{
  __shared__ __align__(16) short Asl[4096];   // [64][64]
  __shared__ __align__(16) short Bsl[8192];   // [128][64]
  int tid = threadIdx.x;
  int lane = tid & 63, wid = tid >> 6;
  int lrow = lane & 15, lq = lane >> 4, lk = lq*8;
  int row0 = blockIdx.x*64;
  const u16* Ab = A + (size_t)row0*lda;
  f32x4 acc[8] = {};
  for (int k0 = 0; k0 < K; k0 += 64) {
    #pragma unroll
    for (int is=0; is<2; ++is){
      int li = is*256 + tid;
      int row = li >> 3;
      int c8  = (li & 7) ^ (row & 7);
      gload16(Ab + (size_t)row*lda + k0 + c8*8, (u16*)Asl + ((is<<8)+(wid<<6))*8);
    }
    #pragma unroll
    for (int is=0; is<4; ++is){
      int li = is*256 + tid;
      int row = li >> 3;
      int c8  = (li & 7) ^ (row & 7);
      gload16(BT + (size_t)row*K + k0 + c8*8, (u16*)Bsl + ((is<<8)+(wid<<6))*8);
    }
    __syncthreads();
    #pragma unroll
    for (int ksub=0; ksub<2; ++ksub){
      int slot = (ksub*32 + lk) >> 3;
      int arr = wid*16 + lrow;
      short8 av = *(const short8*)&Asl[arr*64 + ((slot^(arr&7))<<3)];
      #pragma unroll
      for (int j=0;j<8;++j){
        int brr = j*16 + lrow;
        short8 bv = *(const short8*)&Bsl[brr*64 + ((slot^(brr&7))<<3)];
        acc[j] = __builtin_amdgcn_mfma_f32_16x16x32_bf16(av, bv, acc[j], 0, 0, 0);
      }
    }
    __syncthreads();
  }
  #pragma unroll
  for (int j=0;j<8;++j){
    int col = j*16 + lrow;
    #pragma unroll
    for (int r=0;r<4;++r){
      int row = row0 + wid*16 + lq*4 + r;
      C[(size_t)row*128 + col] = acc[j][r];
    }
  }
}

// ---------- LayerNorm -> bf16 ----------
__global__ __launch_bounds__(256) void ln_kernel(const float* __restrict__ x,
    const float* __restrict__ w, u16* __restrict__ o)
{
  int row = blockIdx.x*4 + (threadIdx.x>>6);
  int lane = threadIdx.x & 63;
  float4 v = *(const float4*)(x + (size_t)row*DMODEL + lane*4);
  float s = v.x+v.y+v.z+v.w;
  #pragma unroll
  for (int off=32;off>=1;off>>=1) s += __shfl_xor(s, off);
  float mu = s * (1.f/256.f);
  float d0=v.x-mu, d1=v.y-mu, d2=v.z-mu, d3=v.w-mu;
  float q = d0*d0+d1*d1+d2*d2+d3*d3;
  #pragma unroll
  for (int off=32;off>=1;off>>=1) q += __shfl_xor(q, off);
  float inv = 1.f/sqrtf(q*(1.f/256.f) + 1e-5f);
  float4 wv = *(const float4*)(w + lane*4);
  u32 lo = (u32)f2bf(d0*inv*wv.x) | ((u32)f2bf(d1*inv*wv.y) << 16);
  u32 hi = (u32)f2bf(d2*inv*wv.z) | ((u32)f2bf(d3*inv*wv.w) << 16);
  uint2 pk; pk.x = lo; pk.y = hi;
  *(uint2*)(o + (size_t)row*DMODEL + lane*4) = pk;
}

// ---------- depthwise conv + silu, 8-channel vectorized, both dirs ----------
__global__ __launch_bounds__(256) void conv_kernel(const u16* __restrict__ xz,
    const float* __restrict__ cw, const float* __restrict__ cb,
    u16* __restrict__ ucv)
{
  int idx = blockIdx.x*256 + threadIdx.x;          // BT*128
  int du8 = idx & 127, dir = du8 >> 6, d8 = (du8 & 63) << 3;
  int bt = idx >> 7, t = bt & 255;
  const u16* up = xz + (size_t)(bt - t)*2048 + dir*512 + d8;
  float w[8][4];
  #pragma unroll
  for (int j=0;j<8;++j){
    float4 wv = *(const float4*)(cw + (size_t)dir*2048 + (d8+j)*4);
    w[j][0]=wv.x; w[j][1]=wv.y; w[j][2]=wv.z; w[j][3]=wv.w;
  }
  float s[8];
  float4 cb0 = *(const float4*)(cb + dir*512 + d8);
  float4 cb1 = *(const float4*)(cb + dir*512 + d8 + 4);
  s[0]=cb0.x; s[1]=cb0.y; s[2]=cb0.z; s[3]=cb0.w;
  s[4]=cb1.x; s[5]=cb1.y; s[6]=cb1.z; s[7]=cb1.w;
  if (dir == 0) {
    #pragma unroll
    for (int k=0;k<4;++k){
      int tk = t-3+k;
      if (tk >= 0){
        short8 uv = *(const short8*)(up + (size_t)tk*2048);
        #pragma unroll
        for (int j=0;j<8;++j) s[j] += w[j][k]*bf2f((u16)uv[j]);
      }
    }
  } else {
    #pragma unroll
    for (int kk=0;kk<4;++kk){
      int tk = t+kk;
      if (tk < TT){
        short8 uv = *(const short8*)(up + (size_t)tk*2048);
        #pragma unroll
        for (int j=0;j<8;++j) s[j] += w[j][3-kk]*bf2f((u16)uv[j]);
      }
    }
  }
  short8 o;
  #pragma unroll
  for (int j=0;j<8;++j) o[j] = (short)f2bf(siluf(s[j]));
  *(short8*)(ucv + (size_t)bt*1024 + dir*512 + d8) = o;
}

// ---------- chunked selective scan, 256-thread blocks, B fused into C ----------
// grid (64 b, 8 c, 4 = d*2 + half); phase A stores Sdt + hend(bf16); phase C
// rebuilds h_in from Sdt/hend prefix, computes y and silu(z) gate.
template<int FINAL>
__global__ __launch_bounds__(256) void scan_phase_kernel(
    const u16* __restrict__ ucv, const float* __restrict__ xd, const u16* __restrict__ xz,
    const float* __restrict__ dtw, const float* __restrict__ dtb,
    const float* __restrict__ alog, const float* __restrict__ dvec,
    const u16* __restrict__ hend_r, const float* __restrict__ sdt_r,
    float* __restrict__ sdt_w, u16* __restrict__ hend_w,
    u16* __restrict__ yout)
{
  int b = blockIdx.x, c = blockIdx.y, gz = blockIdx.z;
  int d = gz >> 1;
  int tid = threadIdx.x;
  int dd = ((gz & 1) << 8) + tid;
  float wdt[16], Av[16], h[16];
  #pragma unroll
  for (int s=0;s<16;++s){
    wdt[s] = dtw[d*8192 + s*512 + dd];
    Av[s]  = -__expf(alog[d*8192 + dd*16 + s]);
    h[s]   = 0.f;
  }
  float bdt = dtb[d*512 + dd];
  __shared__ float sxd[32][48];
  __shared__ u16 su[32][256];
  __shared__ u16 sz[(FINAL?32:1)][256];
  for (int i = tid; i < 1536; i += 256){
    int q = i/48, r = i - q*48;
    int p = (c<<5)+q, t = d ? 255-p : p;
    sxd[q][r] = xd[((size_t)b*TT + t)*128 + d*64 + r];
  }
  #pragma unroll 4
  for (int q=0;q<32;++q){
    int p = (c<<5)+q, t = d ? 255-p : p;
    size_t row = (size_t)b*TT + t;
    su[q][tid] = ucv[row*1024 + d*512 + dd];
    if (FINAL) sz[q][tid] = xz[row*2048 + 1024 + d*512 + dd];
  }
  if (FINAL) {
    // h_in = prefix combine over chunks < c
    for (int cp=0; cp<c; ++cp){
      size_t cbase = (((size_t)b*8+cp)*2+d)*512 + dd;
      float S = sdt_r[cbase];
      short8 h0v = *(const short8*)(hend_r + cbase*16);
      short8 h1v = *(const short8*)(hend_r + cbase*16 + 8);
      #pragma unroll
      for (int s=0;s<8;++s)  h[s]   = fmaf(__expf(Av[s]*S),   h[s],   bf2f((u16)h0v[s]));
      #pragma unroll
      for (int s=0;s<8;++s)  h[s+8] = fmaf(__expf(Av[s+8]*S), h[s+8], bf2f((u16)h1v[s]));
    }
  }
  __syncthreads();
  float S = 0.f;
  float Dv = FINAL ? dvec[d*512 + dd] : 0.f;
  #pragma unroll 1
  for (int q=0;q<32;++q) {
    const float* sr = sxd[q];
    float p0=0.f,p1=0.f,p2=0.f,p3=0.f;
    #pragma unroll
    for (int r=0;r<16;r+=4){
      p0 = fmaf(sr[r+0],wdt[r+0],p0);
      p1 = fmaf(sr[r+1],wdt[r+1],p1);
      p2 = fmaf(sr[r+2],wdt[r+2],p2);
      p3 = fmaf(sr[r+3],wdt[r+3],p3);
    }
    float dtp = bdt + ((p0+p1)+(p2+p3));
    float dt = fmaxf(dtp,0.f) + __logf(1.f + __expf(-fabsf(dtp)));
    float uc = bf2f(su[q][tid]);
    float dtu = dt*uc;
    if (!FINAL) S += dt;
    float y0=0.f, y1=0.f;
    #pragma unroll
    for (int s=0;s<16;s+=2){
      float dA0 = __expf(dt*Av[s]);
      float dA1 = __expf(dt*Av[s+1]);
      h[s]   = fmaf(dA0, h[s],   dtu*sr[16+s]);
      h[s+1] = fmaf(dA1, h[s+1], dtu*sr[16+s+1]);
      if (FINAL){ y0 = fmaf(h[s],sr[32+s],y0); y1 = fmaf(h[s+1],sr[32+s+1],y1); }
    }
    if (FINAL){
      float zc = bf2f(sz[q][tid]);
      float yv = (y0+y1) + uc*Dv;
      float sg = zc / (1.f + __expf(-zc));
      int p4 = (c<<5)+q;
      int t4 = d ? 255-p4 : p4;
      yout[((size_t)b*TT+t4)*2048 + d*512 + dd] = f2bf(yv*sg);
    }
  }
  if (!FINAL){
    size_t co = (((size_t)b*8+c)*2+d)*512 + dd;
    sdt_w[co] = S;
    short8 o0, o1;
    #pragma unroll
    for (int s=0;s<8;++s){ o0[s] = (short)f2bf(h[s]); o1[s] = (short)f2bf(h[s+8]); }
    *(short8*)(hend_w + co*16)     = o0;
    *(short8*)(hend_w + co*16 + 8) = o1;
  }
}

// ---------- fused head (grid 64 x 4): mean -> emb -> sign logits ----------
__global__ __launch_bounds__(256) void head_kernel(const float* __restrict__ xx,
    const float* __restrict__ wsgn, const float* __restrict__ bsgn,
    const float* __restrict__ protos, float* __restrict__ out)
{
  int b = blockIdx.x, qt = blockIdx.y, tid = threadIdx.x;
  __shared__ float mt[256];
  __shared__ __align__(16) float e[256];
  __shared__ float red[4];
  float s0=0.f,s1=0.f,s2=0.f,s3=0.f;
  for (int t=0;t<TT;t+=4){
    s0 += xx[((size_t)b*TT+t  )*DMODEL + tid];
    s1 += xx[((size_t)b*TT+t+1)*DMODEL + tid];
    s2 += xx[((size_t)b*TT+t+2)*DMODEL + tid];
    s3 += xx[((size_t)b*TT+t+3)*DMODEL + tid];
  }
  mt[tid] = (s0+s1+s2+s3)*(1.f/256.f);
  __syncthreads();
  float acc = bsgn[tid];
  for (int i=0;i<DMODEL;++i) acc += mt[i]*wsgn[i*DMODEL + tid];
  e[tid] = acc;
  if (qt == 0) out[128000 + b*DMODEL + tid] = acc;
  __syncthreads();
  float v = acc*acc;
  #pragma unroll
  for (int off=32;off>=1;off>>=1) v += __shfl_xor(v, off);
  if ((tid&63)==0) red[tid>>6] = v;
  __syncthreads();
  float esc = 1.f/(sqrtf(red[0]+red[1]+red[2]+red[3]) + 1e-8f);
  int pend = qt*500 + 500;
  for (int p = qt*500 + tid; p < pend; p += 256) {
    const float* pr = protos + (size_t)p*256;
    float dot=0.f, ps=0.f;
    for (int i=0;i<256;i+=4) {
      float4 pv = *(const float4*)(pr+i);
      float4 ev = *(const float4*)(e+i);
      dot += pv.x*ev.x + pv.y*ev.y + pv.z*ev.z + pv.w*ev.w;
      ps  += pv.x*pv.x + pv.y*pv.y + pv.z*pv.z + pv.w*pv.w;
    }
    out[(size_t)b*NSIGNS + p] = dot*esc/(sqrtf(ps)+1e-8f)*(1.f/0.07f);
  }
}

__global__ __launch_bounds__(256) void sims_kernel(const float* __restrict__ part,
    const float* __restrict__ phs, const float* __restrict__ ploc,
    const float* __restrict__ pmov, const float* __restrict__ pori,
    float* __restrict__ out)
{
  int b = blockIdx.x, tid = threadIdx.x;
  __shared__ float pc[256];
  __shared__ float nk[4];
  pc[tid] = part[(size_t)(2*b)*256 + tid] + part[(size_t)(2*b+1)*256 + tid];
  __syncthreads();
  if (tid < 4) {
    float ss = 0.f;
    for (int i=0;i<64;++i){ float q = pc[tid*64+i]; ss += q*q; }
    nk[tid] = 1.f/(sqrtf(ss)+1e-8f);
  }
  __syncthreads();
  if (tid < 88) {
    int k, pi; const float* P; size_t off; int npk;
    if (tid < 40)      { k=0; pi=tid;    P=phs;  off=144384; npk=40; }
    else if (tid < 60) { k=1; pi=tid-40; P=ploc; off=146944; npk=20; }
    else if (tid < 80) { k=2; pi=tid-60; P=pmov; off=148224; npk=20; }
    else               { k=3; pi=tid-80; P=pori; off=149504; npk=8;  }
    float dot=0.f, ps=0.f;
    for (int i=0;i<64;++i){ float pv = P[pi*64+i]; dot += pv*pc[k*64+i]; ps += pv*pv; }
    out[off + (size_t)b*npk + pi] = dot*nk[k]/(sqrtf(ps)+1e-8f)*(1.f/0.07f);
  }
}

extern "C" void kernel_launch(void* const* d_in, const int* in_sizes, int n_in,
                              void* d_out, int out_size, void* d_ws, size_t ws_size,
                              hipStream_t stream) {
  const float* x         = (const float*)d_in[0];
  const float* w_in      = (const float*)d_in[1];
  const float* b_in      = (const float*)d_in[2];
  const float* w_gat     = (const float*)d_in[3];
  const float* a_src     = (const float*)d_in[4];
  const float* a_dst     = (const float*)d_in[5];
  const float* w_out     = (const float*)d_in[6];
  const float* b_out     = (const float*)d_in[7];
  const float* pdm_w     = (const float*)d_in[8];
  const float* pdm_b     = (const float*)d_in[9];
  const float* w_fuse    = (const float*)d_in[10];
  const float* b_fuse    = (const float*)d_in[11];
  const float* ln_w      = (const float*)d_in[12];
  const float* in_proj   = (const float*)d_in[13];
  const float* conv_w    = (const float*)d_in[14];
  const float* conv_b    = (const float*)d_in[15];
  const float* x_proj    = (const float*)d_in[16];
  const float* dt_w      = (const float*)d_in[17];
  const float* dt_b      = (const float*)d_in[18];
  const float* A_log     = (const float*)d_in[19];
  const float* Dvec      = (const float*)d_in[20];
  const float* out_proj  = (const float*)d_in[21];
  const float* w_sign    = (const float*)d_in[22];
  const float* b_sign    = (const float*)d_in[23];
  const float* protos    = (const float*)d_in[24];
  const float* phs       = (const float*)d_in[25];
  const float* ploc      = (const float*)d_in[26];
  const float* pmov      = (const float*)d_in[27];
  const float* pori      = (const float*)d_in[28];
  float* out = (float*)d_out;

  // ---- ws layout ----
  float* wsf = (float*)d_ws;
  const size_t f_xx    = 0;                          // 16384*256
  const size_t f_xdbl  = f_xx   + 4194304;           // 16384*128
  const size_t f_part  = f_xdbl + 2097152;           // 128*256
  const size_t f_end   = f_part + 32768;
  u16* wsu = (u16*)(wsf + f_end);
  const size_t u_xn    = 0;                          // 16384*256
  const size_t u_xz    = u_xn   + 4194304;           // 16384*2048 [u0 u1 z0 z1]; y -> u slots
  const size_t u_ucv   = u_xz   + 33554432;          // 16384*1024
  const size_t u_fsum  = u_ucv  + 16777216;          // 16384*128
  const size_t u_spat  = u_fsum + 2097152;           // 16384*256
  const size_t u_comps = u_spat + 4194304;           // 16384*256
  const size_t u_w     = u_comps+ 4194304;           // 3,850,240 weights
  u16* wiT = wsu + u_w;
  u16* woT = wiT + 2097152;
  u16* wxT = woT + 1048576;
  u16* wA  = wxT + 524288;
  u16* wB  = wA  + 32768;
  u16* wF  = wB  + 65536;
  u16* wBp = wF  + 65536;
  // scan scratch aliases fsum/spat/comps (dead during SSM loop)
  u16*   hstate = wsu + u_fsum;                      // 64*8*2*512*16 u16 = 16MB
  float* sdt    = (float*)(wsu + u_fsum + 8388608);  // 64*8*2*512 f32 = 2MB

  transpose_w_kernel<<<944, 256, 0, stream>>>(in_proj, out_proj, x_proj, w_out, pdm_w, w_fuse, w_gat, wsu + u_w);
  agan_kernel<<<BTT, 256, 0, stream>>>(x, w_in, b_in, wBp, a_src, a_dst, wsu + u_fsum);
  gemm_bf16_kernel<0,1,0,1,0><<<dim3(2,128), 256, 0, stream>>>(wsu+u_fsum, wA, b_out, nullptr, wsu+u_spat, nullptr, BTT, 256, 128, 128);
  gemm_bf16_kernel<0,1,1,1,1><<<dim3(2,128), 256, 0, stream>>>(wsu+u_spat, wB, pdm_b, nullptr, wsu+u_comps, wsf+f_part, BTT, 256, 256, 256);
  gemm_bf16_kernel<0,1,0,0,0><<<dim3(2,128), 256, 0, stream>>>(wsu+u_comps, wF, b_fuse, wsf+f_xx, nullptr, nullptr, BTT, 256, 256, 256);

  for (int l = 0; l < 4; ++l) {
    ln_kernel<<<BTT/4, 256, 0, stream>>>(wsf+f_xx, ln_w + l*DMODEL, wsu+u_xn);
    gemm_bf16_kernel<0,0,0,1,0><<<dim3(16,128), 256, 0, stream>>>(wsu+u_xn, wiT + (size_t)l*524288,
        nullptr, nullptr, wsu+u_xz, nullptr, BTT, 2048, 256, 256);
    conv_kernel<<<BTT*128/256, 256, 0, stream>>>(wsu+u_xz, conv_w + (size_t)l*4096,
        conv_b + (size_t)l*1024, wsu+u_ucv);
    gemm64_kernel<<<BTT/64, 256, 0, stream>>>(wsu+u_ucv, wxT + (size_t)l*131072,
        wsf+f_xdbl, 1024, 1024);
    scan_phase_kernel<0><<<dim3(64,8,4), 256, 0, stream>>>(wsu+u_ucv, wsf+f_xdbl, nullptr,
        dt_w + (size_t)l*16384, dt_b + (size_t)l*1024,
        A_log + (size_t)l*16384, nullptr,
        nullptr, nullptr, sdt, hstate, nullptr);
    scan_phase_kernel<1><<<dim3(64,8,4), 256, 0, stream>>>(wsu+u_ucv, wsf+f_xdbl, wsu+u_xz,
        dt_w + (size_t)l*16384, dt_b + (size_t)l*1024,
        A_log + (size_t)l*16384, Dvec + (size_t)l*1024,
        hstate, sdt, nullptr, nullptr, wsu+u_xz);
    gemm_bf16_kernel<1,0,0,0,0><<<dim3(2,128), 256, 0, stream>>>(wsu+u_xz, woT + (size_t)l*262144,
        nullptr, wsf+f_xx, nullptr, nullptr, BTT, 256, 1024, 2048);
  }

  head_kernel<<<dim3(64,4), 256, 0, stream>>>(wsf+f_xx, w_sign, b_sign, protos, out);
  sims_kernel<<<64, 256, 0, stream>>>(wsf+f_part, phs, ploc, pmov, pori, out);
  (void)in_sizes; (void)n_in; (void)out_size; (void)ws_size;
}

// Round 7
// 1331.784 us; speedup vs baseline: 4.2570x; 1.0484x over previous
//
#include <hip/hip_runtime.h>
#include <hip/hip_bf16.h>
#include <math.h>

#define BB 64
#define TT 256
#define NNODE 21
#define HID 128
#define DMODEL 256
#define DINNER 512
#define NSIGNS 2000
#define BTT (BB*TT)   // 16384

typedef unsigned short u16;
typedef unsigned int u32;
typedef __attribute__((ext_vector_type(8))) short short8;
typedef __attribute__((ext_vector_type(4))) float f32x4;

__device__ __forceinline__ float siluf(float x){ return x/(1.f+expf(-x)); }
__device__ __forceinline__ u16 f2bf(float x){ __hip_bfloat16 h = __float2bfloat16(x); return *(u16*)&h; }
__device__ __forceinline__ u32 pk2bf(float a, float b){
  float2 f2; f2.x = a; f2.y = b;
  __hip_bfloat162 h2 = __float22bfloat162_rn(f2);
  return *(u32*)&h2;
}
__device__ __forceinline__ float bf2f(u16 u){ return __uint_as_float(((u32)u)<<16); }
__device__ __forceinline__ void gload16(const u16* g, u16* l){
  __builtin_amdgcn_global_load_lds((const __attribute__((address_space(1))) void*)g,
                                   (__attribute__((address_space(3))) void*)l, 16, 0, 0);
}

// ---------- tiled weight transpose -> bf16 [N][K] layouts ----------
__global__ __launch_bounds__(256) void transpose_w_kernel(
    const float* __restrict__ in_proj, const float* __restrict__ out_proj,
    const float* __restrict__ x_proj, const float* __restrict__ w_out,
    const float* __restrict__ pdm_w, const float* __restrict__ w_fuse,
    const float* __restrict__ w_gat, u16* __restrict__ dst)
{
  __shared__ short tl[64*66];
  int bx = blockIdx.x, tid = threadIdx.x;
  const float* S = nullptr; size_t soff = 0; int lds = 0, Nsrc = 0;
  size_t doff = 0; int ldd = 0, Nout = 0;
  int tn = 0, tk = 0;
  bool zero = false;
  if (bx < 512) {                       // in_projT
    int j = bx >> 5, tt = bx & 31;
    int l = j >> 2, d = j & 1, zh = (j >> 1) & 1;
    tn = tt >> 2; tk = tt & 3;
    S = in_proj; soff = ((size_t)(l*2+d)*256)*1024 + zh*512; lds = 1024; Nsrc = 512;
    doff = (size_t)l*524288 + (size_t)(zh*1024 + d*512)*256; ldd = 256; Nout = 512;
  } else if (bx < 768) {                // out_projT
    int j = (bx-512) >> 5, tt = (bx-512) & 31;
    int l = j >> 1, d = j & 1;
    tn = tt >> 3; tk = tt & 7;
    S = out_proj; soff = (size_t)(l*2+d)*512*256; lds = 256; Nsrc = 256;
    doff = 2097152 + (size_t)l*262144 + d*512; ldd = 1024; Nout = 256;
  } else if (bx < 896) {                // x_projT (+ zero-fill of off-d k-half)
    int j = (bx-768) >> 3, tt = (bx-768) & 7;
    int l = j >> 2, sub = j & 3;
    tn = 0; tk = tt;
    if (sub < 2) {
      int d = sub;
      S = x_proj; soff = (size_t)(l*2+d)*512*48; lds = 48; Nsrc = 48;
      doff = 3145728 + (size_t)l*131072 + (size_t)(d*64)*1024 + d*512; ldd = 1024; Nout = 64;
    } else {
      int d = sub-2; zero = true;
      doff = 3145728 + (size_t)l*131072 + (size_t)(d*64)*1024 + (1-d)*512; ldd = 1024; Nout = 64;
    }
  } else if (bx < 904) {                // w_outT
    int tt = bx-896; tn = tt>>1; tk = tt&1;
    S = w_out; soff = 0; lds = 256; Nsrc = 256;
    doff = 3670016; ldd = 128; Nout = 256;
  } else if (bx < 920) {                // wbigT (pdm_w)
    int j = (bx-904)>>2, tt = (bx-904)&3;
    tn = 0; tk = tt;
    S = pdm_w; soff = (size_t)j*16384; lds = 64; Nsrc = 64;
    doff = 3702784 + (size_t)j*16384; ldd = 256; Nout = 64;
  } else if (bx < 936) {                // w_fuseT
    int tt = bx-920; tn = tt>>2; tk = tt&3;
    S = w_fuse; soff = 0; lds = 256; Nsrc = 256;
    doff = 3768320; ldd = 256; Nout = 256;
  } else {                              // BpT
    int j = (bx-936)>>1, tt = (bx-936)&1;
    tn = 0; tk = tt;
    S = w_gat; soff = (size_t)j*4096; lds = 32; Nsrc = 32;
    doff = 3833856 + (size_t)j*4096; ldd = 128; Nout = 32;
  }
  int n0 = tn*64, k0 = tk*64;
  if (!zero) {
    #pragma unroll
    for (int i=0;i<16;++i){
      int kk = i*4 + (tid>>6), nn = tid&63;
      float v = (n0+nn < Nsrc) ? S[soff + (size_t)(k0+kk)*lds + n0+nn] : 0.f;
      tl[nn*66+kk] = (short)f2bf(v);
    }
    __syncthreads();
    #pragma unroll
    for (int i=0;i<16;++i){
      int nn = i*4 + (tid>>6), kk = tid&63;
      if (n0+nn < Nout) dst[doff + (size_t)(n0+nn)*ldd + k0+kk] = (u16)tl[nn*66+kk];
    }
  } else {
    #pragma unroll
    for (int i=0;i<16;++i){
      int nn = i*4 + (tid>>6), kk = tid&63;
      if (n0+nn < Nout) dst[doff + (size_t)(n0+nn)*ldd + k0+kk] = 0;
    }
  }
}

// ---------- AGAN: hm and agg via MFMA, Bp in regs, no-normalize softmax ----------
__global__ __launch_bounds__(256) void agan_kernel(
    const float* __restrict__ x, const float* __restrict__ w_in, const float* __restrict__ b_in,
    const u16* __restrict__ bpt, const float* __restrict__ a_src, const float* __restrict__ a_dst,
    u16* __restrict__ fsum_out)
{
  int bt = blockIdx.x;
  int tid = threadIdx.x;
  int lane = tid & 63, wid = tid >> 6;
  int lr = lane & 15, lq = lane >> 4;
  __shared__ float xv[NNODE][4];
  __shared__ __align__(16) short sh0[32*136];
  __shared__ __align__(16) short hmT[128*40];
  __shared__ __align__(16) short alb[4*32*40];
  __shared__ float sd[2][NNODE][4];
  __shared__ float sm[4][NNODE];
  short8 bp[4][2];
  #pragma unroll
  for (int ks=0;ks<4;++ks)
    #pragma unroll
    for (int ct=0;ct<2;++ct)
      bp[ks][ct] = *(const short8*)(bpt + (size_t)(wid*32+ct*16+lr)*128 + ks*32 + lq*8);
  if (tid < NNODE*3) xv[tid/3][tid%3] = x[(size_t)bt*63 + tid];
  __syncthreads();
  for (int idx = tid; idx < 32*128; idx += 256) {
    int n = idx >> 7, i = idx & 127;
    float v = 0.f;
    if (n < NNODE)
      v = fmaxf(b_in[i] + xv[n][0]*w_in[i] + xv[n][1]*w_in[128+i] + xv[n][2]*w_in[256+i], 0.f);
    sh0[n*136 + i] = (short)f2bf(v);
  }
  __syncthreads();
  {
    f32x4 g00={},g01={},g10={},g11={};
    #pragma unroll
    for (int ks=0;ks<4;++ks){
      short8 a0 = *(const short8*)&sh0[(lr   )*136 + ks*32 + lq*8];
      short8 a1 = *(const short8*)&sh0[(16+lr)*136 + ks*32 + lq*8];
      g00 = __builtin_amdgcn_mfma_f32_16x16x32_bf16(a0, bp[ks][0], g00, 0,0,0);
      g01 = __builtin_amdgcn_mfma_f32_16x16x32_bf16(a0, bp[ks][1], g01, 0,0,0);
      g10 = __builtin_amdgcn_mfma_f32_16x16x32_bf16(a1, bp[ks][0], g10, 0,0,0);
      g11 = __builtin_amdgcn_mfma_f32_16x16x32_bf16(a1, bp[ks][1], g11, 0,0,0);
    }
    f32x4 gg[2][2] = {{g00,g01},{g10,g11}};
    #pragma unroll
    for (int mt=0;mt<2;++mt)
      #pragma unroll
      for (int ct=0;ct<2;++ct){
        int col = wid*32 + ct*16 + lr;
        int row0 = mt*16 + lq*4;
        u32 w0 = pk2bf(gg[mt][ct][0], gg[mt][ct][1]);
        u32 w1 = pk2bf(gg[mt][ct][2], gg[mt][ct][3]);
        *(uint2*)&hmT[col*40 + row0] = make_uint2(w0,w1);
      }
  }
  __syncthreads();
  if (tid < 168) {
    int which = tid >= 84;
    int r = tid - which*84;
    int n = r >> 2, h = r & 3;
    const float* av = (which ? a_dst : a_src) + h*32;
    float s = 0.f;
    #pragma unroll
    for (int o=0;o<32;++o){ int oo=(o+tid)&31; s += bf2f((u16)hmT[(h*32+oo)*40 + n])*av[oo]; }
    sd[which][n][h] = s;
  }
  __syncthreads();
  if (tid < 84) {
    int i = tid >> 2, h = tid & 3;
    float sv = sd[0][i][h], m = -1e30f;
    #pragma unroll
    for (int j=0;j<NNODE;++j){
      float e = sv + sd[1][j][h];
      e = e>=0.f ? e : 0.2f*e;
      m = fmaxf(m,e);
    }
    sm[h][i] = m;
  }
  __syncthreads();
  for (int idx = tid; idx < 84*32; idx += 256) {
    int j = idx & 31, ih = idx >> 5;
    int i = ih >> 2, h = ih & 3;
    float ex = 0.f;
    if (j < NNODE){
      float e = sd[0][i][h] + sd[1][j][h];
      e = e>=0.f ? e : 0.2f*e;
      ex = __expf(e - sm[h][i]);
    }
    alb[(h*32+i)*40 + j] = (short)f2bf(ex);
  }
  __syncthreads();
  // rowsum -> inverse (normalization folded into agg epilogue)
  if (tid < 84) {
    int i = tid >> 2, h = tid & 3;
    const short* row = &alb[(h*32+i)*40];
    float s = 0.f;
    #pragma unroll
    for (int j=0;j<NNODE;++j) s += bf2f((u16)row[j]);
    sm[h][i] = 1.f/s;
  }
  __syncthreads();
  {
    int h = wid;
    short8 a0 = *(const short8*)&alb[(h*32 + lr     )*40 + lq*8];
    short8 a1 = *(const short8*)&alb[(h*32 + 16 + lr)*40 + lq*8];
    short8 b0 = *(const short8*)&hmT[(h*32 + lr     )*40 + lq*8];
    short8 b1 = *(const short8*)&hmT[(h*32 + 16 + lr)*40 + lq*8];
    f32x4 c00={},c01={},c10={},c11={};
    c00 = __builtin_amdgcn_mfma_f32_16x16x32_bf16(a0,b0,c00,0,0,0);
    c01 = __builtin_amdgcn_mfma_f32_16x16x32_bf16(a0,b1,c01,0,0,0);
    c10 = __builtin_amdgcn_mfma_f32_16x16x32_bf16(a1,b0,c10,0,0,0);
    c11 = __builtin_amdgcn_mfma_f32_16x16x32_bf16(a1,b1,c11,0,0,0);
    f32x4 cc[2][2] = {{c00,c01},{c10,c11}};
    #pragma unroll
    for (int ct=0; ct<2; ++ct){
      int col = h*32 + ct*16 + lr;
      float s = 0.f;
      #pragma unroll
      for (int mt=0; mt<2; ++mt)
        #pragma unroll
        for (int r=0;r<4;++r){
          int n = mt*16 + lq*4 + r;
          if (n < NNODE)
            s += fmaxf(bf2f((u16)sh0[n*136+col]) + cc[mt][ct][r]*sm[h][n], 0.f);
        }
      s += __shfl_xor(s, 16);
      s += __shfl_xor(s, 32);
      if (lq == 0) fsum_out[(size_t)bt*128 + col] = f2bf(s*(1.f/21.f));
    }
  }
}

// ---------- bf16 MFMA GEMM, 128x128 tile, BK=64, XOR-swizzled LDS ----------
template<int ACC, int BIAS, int RELU, int SM>
__global__ __launch_bounds__(256) void gemm_bf16_kernel(
    const u16* __restrict__ A, const u16* __restrict__ BT, const float* __restrict__ bias,
    float* __restrict__ C, u16* __restrict__ C2,
    int M, int N, int K, int lda)
{
  __shared__ __align__(16) short Asl[8192];
  __shared__ __align__(16) short Bsl[8192];
  int tid = threadIdx.x;
  int lane = tid & 63, wid = tid >> 6;
  int wm = wid >> 1, wn = wid & 1;
  int row0 = blockIdx.y*128, col0 = blockIdx.x*128;
  const u16* Ab = A  + (size_t)row0*lda;
  const u16* Bb = BT + (size_t)col0*K;
  f32x4 acc[4][4] = {};
  int lrow = lane & 15, lk = (lane>>4)*8;
  for (int k0 = 0; k0 < K; k0 += 64) {
    #pragma unroll
    for (int is=0; is<4; ++is){
      int li = is*256 + tid;
      int row = li >> 3;
      int c8  = (li & 7) ^ (row & 7);
      gload16(Ab + (size_t)row*lda + k0 + c8*8, (u16*)Asl + ((is<<8)+(wid<<6))*8);
      gload16(Bb + (size_t)row*K   + k0 + c8*8, (u16*)Bsl + ((is<<8)+(wid<<6))*8);
    }
    __syncthreads();
    #pragma unroll
    for (int ksub=0; ksub<2; ++ksub){
      int slot = (ksub*32 + lk) >> 3;
      short8 a[4], b[4];
      #pragma unroll
      for (int i=0;i<4;++i){ int rr=wm*64+i*16+lrow; a[i]=*(const short8*)&Asl[rr*64+((slot^(rr&7))<<3)]; }
      #pragma unroll
      for (int j=0;j<4;++j){ int rr=wn*64+j*16+lrow; b[j]=*(const short8*)&Bsl[rr*64+((slot^(rr&7))<<3)]; }
      #pragma unroll
      for (int i=0;i<4;++i)
        #pragma unroll
        for (int j=0;j<4;++j)
          acc[i][j] = __builtin_amdgcn_mfma_f32_16x16x32_bf16(a[i], b[j], acc[i][j], 0, 0, 0);
    }
    __syncthreads();
  }
  #pragma unroll
  for (int i=0;i<4;++i) {
    int row = row0 + wm*64 + i*16 + (lane>>4)*4;
    #pragma unroll
    for (int j=0;j<4;++j) {
      int col = col0 + wn*64 + j*16 + (lane&15);
      if (col < N) {
        float bv = BIAS ? bias[col] : 0.f;
        #pragma unroll
        for (int r=0;r<4;++r) {
          float v = acc[i][j][r] + bv;
          if (RELU) v = fmaxf(v, 0.f);
          size_t o = (size_t)(row+r)*N + col;
          if (ACC)           C[o] += v;
          else if (SM == 0)  C[o]  = v;
          else               C2[o] = f2bf(v);
        }
      }
    }
  }
}

// ---------- bf16 MFMA GEMM, BM=64 x BN=128, BK=64 (occupancy tile) ----------
template<int ACC, int BIAS, int RELU, int SM, int POOL>
__global__ __launch_bounds__(256) void gemm_bm64_kernel(
    const u16* __restrict__ A, const u16* __restrict__ BT, const float* __restrict__ bias,
    float* __restrict__ C, u16* __restrict__ C2, float* __restrict__ pool,
    int M, int N, int K, int lda)
{
  __shared__ __align__(16) short Asl[4096];    // [64][64]
  __shared__ __align__(16) short Bsl[8192];    // [128][64]
  int tid = threadIdx.x;
  int lane = tid & 63, wid = tid >> 6;
  int wm = wid >> 1, wn = wid & 1;
  int row0 = blockIdx.y*64, col0 = blockIdx.x*128;
  const u16* Ab = A  + (size_t)row0*lda;
  const u16* Bb = BT + (size_t)col0*K;
  f32x4 acc[2][4] = {};
  int lrow = lane & 15, lq = lane >> 4, lk = lq*8;
  for (int k0 = 0; k0 < K; k0 += 64) {
    #pragma unroll
    for (int is=0; is<2; ++is){
      int li = is*256 + tid;
      int row = li >> 3;
      int c8  = (li & 7) ^ (row & 7);
      gload16(Ab + (size_t)row*lda + k0 + c8*8, (u16*)Asl + ((is<<8)+(wid<<6))*8);
    }
    #pragma unroll
    for (int is=0; is<4; ++is){
      int li = is*256 + tid;
      int row = li >> 3;
      int c8  = (li & 7) ^ (row & 7);
      gload16(Bb + (size_t)row*K + k0 + c8*8, (u16*)Bsl + ((is<<8)+(wid<<6))*8);
    }
    __syncthreads();
    #pragma unroll
    for (int ksub=0; ksub<2; ++ksub){
      int slot = (ksub*32 + lk) >> 3;
      short8 a[2], b[4];
      #pragma unroll
      for (int i=0;i<2;++i){ int rr=wm*32+i*16+lrow; a[i]=*(const short8*)&Asl[rr*64+((slot^(rr&7))<<3)]; }
      #pragma unroll
      for (int j=0;j<4;++j){ int rr=wn*64+j*16+lrow; b[j]=*(const short8*)&Bsl[rr*64+((slot^(rr&7))<<3)]; }
      #pragma unroll
      for (int i=0;i<2;++i)
        #pragma unroll
        for (int j=0;j<4;++j)
          acc[i][j] = __builtin_amdgcn_mfma_f32_16x16x32_bf16(a[i], b[j], acc[i][j], 0, 0, 0);
    }
    __syncthreads();
  }
  float colsum[4] = {0.f,0.f,0.f,0.f};
  #pragma unroll
  for (int i=0;i<2;++i) {
    int row = row0 + wm*32 + i*16 + lq*4;
    #pragma unroll
    for (int j=0;j<4;++j) {
      int col = col0 + wn*64 + j*16 + lrow;
      if (col < N) {
        float bv = BIAS ? bias[col] : 0.f;
        #pragma unroll
        for (int r=0;r<4;++r) {
          float v = acc[i][j][r] + bv;
          if (RELU) v = fmaxf(v, 0.f);
          size_t o = (size_t)(row+r)*N + col;
          if (ACC)           C[o] += v;
          else if (SM == 0)  C[o]  = v;
          else               C2[o] = f2bf(v);
          if (POOL) colsum[j] += v;
        }
      }
    }
  }
  if (POOL) {
    float* red = (float*)Asl;
    #pragma unroll
    for (int j=0;j<4;++j) red[tid*4+j] = colsum[j];
    __syncthreads();
    if (tid < 128) {
      int wn_ = tid >> 6, j_ = (tid >> 4) & 3, l15 = tid & 15;
      float s = 0.f;
      #pragma unroll
      for (int wm_=0;wm_<2;++wm_)
        #pragma unroll
        for (int g=0;g<4;++g)
          s += red[(((wm_*2+wn_)*64) + g*16 + l15)*4 + j_];
      pool[(size_t)blockIdx.y*256 + blockIdx.x*128 + tid] = s * (1.f/256.f);
    }
  }
}

// ---------- LayerNorm -> bf16 ----------
__global__ __launch_bounds__(256) void ln_kernel(const float* __restrict__ x,
    const float* __restrict__ w, u16* __restrict__ o)
{
  int row = blockIdx.x*4 + (threadIdx.x>>6);
  int lane = threadIdx.x & 63;
  float4 v = *(const float4*)(x + (size_t)row*DMODEL + lane*4);
  float s = v.x+v.y+v.z+v.w;
  #pragma unroll
  for (int off=32;off>=1;off>>=1) s += __shfl_xor(s, off);
  float mu = s * (1.f/256.f);
  float d0=v.x-mu, d1=v.y-mu, d2=v.z-mu, d3=v.w-mu;
  float q = d0*d0+d1*d1+d2*d2+d3*d3;
  #pragma unroll
  for (int off=32;off>=1;off>>=1) q += __shfl_xor(q, off);
  float inv = 1.f/sqrtf(q*(1.f/256.f) + 1e-5f);
  float4 wv = *(const float4*)(w + lane*4);
  uint2 pk; pk.x = pk2bf(d0*inv*wv.x, d1*inv*wv.y); pk.y = pk2bf(d2*inv*wv.z, d3*inv*wv.w);
  *(uint2*)(o + (size_t)row*DMODEL + lane*4) = pk;
}

// ---------- depthwise conv + silu, 8-channel vectorized, both dirs ----------
__global__ __launch_bounds__(256) void conv_kernel(const u16* __restrict__ xz,
    const float* __restrict__ cw, const float* __restrict__ cb,
    u16* __restrict__ ucv)
{
  int idx = blockIdx.x*256 + threadIdx.x;          // BT*128
  int du8 = idx & 127, dir = du8 >> 6, d8 = (du8 & 63) << 3;
  int bt = idx >> 7, t = bt & 255;
  const u16* up = xz + (size_t)(bt - t)*2048 + dir*512 + d8;
  float w[8][4];
  #pragma unroll
  for (int j=0;j<8;++j){
    float4 wv = *(const float4*)(cw + (size_t)dir*2048 + (d8+j)*4);
    w[j][0]=wv.x; w[j][1]=wv.y; w[j][2]=wv.z; w[j][3]=wv.w;
  }
  float s[8];
  float4 cb0 = *(const float4*)(cb + dir*512 + d8);
  float4 cb1 = *(const float4*)(cb + dir*512 + d8 + 4);
  s[0]=cb0.x; s[1]=cb0.y; s[2]=cb0.z; s[3]=cb0.w;
  s[4]=cb1.x; s[5]=cb1.y; s[6]=cb1.z; s[7]=cb1.w;
  if (dir == 0) {
    #pragma unroll
    for (int k=0;k<4;++k){
      int tk = t-3+k;
      if (tk >= 0){
        short8 uv = *(const short8*)(up + (size_t)tk*2048);
        #pragma unroll
        for (int j=0;j<8;++j) s[j] += w[j][k]*bf2f((u16)uv[j]);
      }
    }
  } else {
    #pragma unroll
    for (int kk=0;kk<4;++kk){
      int tk = t+kk;
      if (tk < TT){
        short8 uv = *(const short8*)(up + (size_t)tk*2048);
        #pragma unroll
        for (int j=0;j<8;++j) s[j] += w[j][3-kk]*bf2f((u16)uv[j]);
      }
    }
  }
  short8 o;
  #pragma unroll
  for (int j=0;j<8;++j) o[j] = (short)f2bf(siluf(s[j]));
  *(short8*)(ucv + (size_t)bt*1024 + dir*512 + d8) = o;
}

// ---------- chunked selective scan, 256-thread blocks, direct u/z reads ----------
// grid (64 b, 8 c, 4 = d*2 + half)
template<int FINAL>
__global__ __launch_bounds__(256) void scan_phase_kernel(
    const u16* __restrict__ ucv, const float* __restrict__ xd, const u16* __restrict__ xz,
    const float* __restrict__ dtw, const float* __restrict__ dtb,
    const float* __restrict__ alog, const float* __restrict__ dvec,
    const u16* __restrict__ hend_r, const float* __restrict__ sdt_r,
    float* __restrict__ sdt_w, u16* __restrict__ hend_w,
    u16* __restrict__ yout)
{
  int b = blockIdx.x, c = blockIdx.y, gz = blockIdx.z;
  int d = gz >> 1;
  int tid = threadIdx.x;
  int dd = ((gz & 1) << 8) + tid;
  float wdt[16], Av[16], h[16];
  #pragma unroll
  for (int s=0;s<16;++s){
    wdt[s] = dtw[d*8192 + s*512 + dd];
    Av[s]  = -__expf(alog[d*8192 + dd*16 + s]);
    h[s]   = 0.f;
  }
  float bdt = dtb[d*512 + dd];
  __shared__ float sxd[32][48];
  for (int i = tid; i < 1536; i += 256){
    int q = i/48, r = i - q*48;
    int p = (c<<5)+q, t = d ? 255-p : p;
    sxd[q][r] = xd[((size_t)b*TT + t)*128 + d*64 + r];
  }
  if (FINAL) {
    for (int cp=0; cp<c; ++cp){
      size_t cbase = (((size_t)b*8+cp)*2+d)*512 + dd;
      float S = sdt_r[cbase];
      short8 h0v = *(const short8*)(hend_r + cbase*16);
      short8 h1v = *(const short8*)(hend_r + cbase*16 + 8);
      #pragma unroll
      for (int s=0;s<8;++s)  h[s]   = fmaf(__expf(Av[s]*S),   h[s],   bf2f((u16)h0v[s]));
      #pragma unroll
      for (int s=0;s<8;++s)  h[s+8] = fmaf(__expf(Av[s+8]*S), h[s+8], bf2f((u16)h1v[s]));
    }
  }
  __syncthreads();
  float S = 0.f;
  float Dv = FINAL ? dvec[d*512 + dd] : 0.f;
  const u16* ub = ucv + d*512 + dd;
  const u16* zb = xz + 1024 + d*512 + dd;
  u16* yb = yout + d*512 + dd;
  #pragma unroll 4
  for (int q=0;q<32;++q) {
    int p = (c<<5)+q, t = d ? 255-p : p;
    size_t row = (size_t)b*TT + t;
    float uc = bf2f(ub[row*1024]);
    float zc = FINAL ? bf2f(zb[row*2048]) : 0.f;
    const float* sr = sxd[q];
    float p0=0.f,p1=0.f,p2=0.f,p3=0.f;
    #pragma unroll
    for (int r=0;r<16;r+=4){
      p0 = fmaf(sr[r+0],wdt[r+0],p0);
      p1 = fmaf(sr[r+1],wdt[r+1],p1);
      p2 = fmaf(sr[r+2],wdt[r+2],p2);
      p3 = fmaf(sr[r+3],wdt[r+3],p3);
    }
    float dtp = bdt + ((p0+p1)+(p2+p3));
    float dt = fmaxf(dtp,0.f) + __logf(1.f + __expf(-fabsf(dtp)));
    float dtu = dt*uc;
    if (!FINAL) S += dt;
    float y0=0.f, y1=0.f;
    #pragma unroll
    for (int s=0;s<16;s+=2){
      float dA0 = __expf(dt*Av[s]);
      float dA1 = __expf(dt*Av[s+1]);
      h[s]   = fmaf(dA0, h[s],   dtu*sr[16+s]);
      h[s+1] = fmaf(dA1, h[s+1], dtu*sr[16+s+1]);
      if (FINAL){ y0 = fmaf(h[s],sr[32+s],y0); y1 = fmaf(h[s+1],sr[32+s+1],y1); }
    }
    if (FINAL){
      float yv = (y0+y1) + uc*Dv;
      float sg = zc / (1.f + __expf(-zc));
      yb[row*2048] = f2bf(yv*sg);
    }
  }
  if (!FINAL){
    size_t co = (((size_t)b*8+c)*2+d)*512 + dd;
    sdt_w[co] = S;
    short8 o0, o1;
    #pragma unroll
    for (int s=0;s<8;++s){ o0[s] = (short)f2bf(h[s]); o1[s] = (short)f2bf(h[s+8]); }
    *(short8*)(hend_w + co*16)     = o0;
    *(short8*)(hend_w + co*16 + 8) = o1;
  }
}

// ---------- fused head (grid 64 x 4): mean -> emb -> sign logits ----------
__global__ __launch_bounds__(256) void head_kernel(const float* __restrict__ xx,
    const float* __restrict__ wsgn, const float* __restrict__ bsgn,
    const float* __restrict__ protos, float* __restrict__ out)
{
  int b = blockIdx.x, qt = blockIdx.y, tid = threadIdx.x;
  __shared__ float mt[256];
  __shared__ __align__(16) float e[256];
  __shared__ float red[4];
  float s0=0.f,s1=0.f,s2=0.f,s3=0.f;
  for (int t=0;t<TT;t+=4){
    s0 += xx[((size_t)b*TT+t  )*DMODEL + tid];
    s1 += xx[((size_t)b*TT+t+1)*DMODEL + tid];
    s2 += xx[((size_t)b*TT+t+2)*DMODEL + tid];
    s3 += xx[((size_t)b*TT+t+3)*DMODEL + tid];
  }
  mt[tid] = (s0+s1+s2+s3)*(1.f/256.f);
  __syncthreads();
  float acc = bsgn[tid];
  for (int i=0;i<DMODEL;++i) acc += mt[i]*wsgn[i*DMODEL + tid];
  e[tid] = acc;
  if (qt == 0) out[128000 + b*DMODEL + tid] = acc;
  __syncthreads();
  float v = acc*acc;
  #pragma unroll
  for (int off=32;off>=1;off>>=1) v += __shfl_xor(v, off);
  if ((tid&63)==0) red[tid>>6] = v;
  __syncthreads();
  float esc = 1.f/(sqrtf(red[0]+red[1]+red[2]+red[3]) + 1e-8f);
  int pend = qt*500 + 500;
  for (int p = qt*500 + tid; p < pend; p += 256) {
    const float* pr = protos + (size_t)p*256;
    float dot=0.f, ps=0.f;
    for (int i=0;i<256;i+=4) {
      float4 pv = *(const float4*)(pr+i);
      float4 ev = *(const float4*)(e+i);
      dot += pv.x*ev.x + pv.y*ev.y + pv.z*ev.z + pv.w*ev.w;
      ps  += pv.x*pv.x + pv.y*pv.y + pv.z*pv.z + pv.w*pv.w;
    }
    out[(size_t)b*NSIGNS + p] = dot*esc/(sqrtf(ps)+1e-8f)*(1.f/0.07f);
  }
}

__global__ __launch_bounds__(256) void sims_kernel(const float* __restrict__ part,
    const float* __restrict__ phs, const float* __restrict__ ploc,
    const float* __restrict__ pmov, const float* __restrict__ pori,
    float* __restrict__ out)
{
  int b = blockIdx.x, tid = threadIdx.x;
  __shared__ float pc[256];
  __shared__ float nk[4];
  pc[tid] = part[(size_t)(4*b)*256 + tid] + part[(size_t)(4*b+1)*256 + tid]
          + part[(size_t)(4*b+2)*256 + tid] + part[(size_t)(4*b+3)*256 + tid];
  __syncthreads();
  if (tid < 4) {
    float ss = 0.f;
    for (int i=0;i<64;++i){ float q = pc[tid*64+i]; ss += q*q; }
    nk[tid] = 1.f/(sqrtf(ss)+1e-8f);
  }
  __syncthreads();
  if (tid < 88) {
    int k, pi; const float* P; size_t off; int npk;
    if (tid < 40)      { k=0; pi=tid;    P=phs;  off=144384; npk=40; }
    else if (tid < 60) { k=1; pi=tid-40; P=ploc; off=146944; npk=20; }
    else if (tid < 80) { k=2; pi=tid-60; P=pmov; off=148224; npk=20; }
    else               { k=3; pi=tid-80; P=pori; off=149504; npk=8;  }
    float dot=0.f, ps=0.f;
    for (int i=0;i<64;++i){ float pv = P[pi*64+i]; dot += pv*pc[k*64+i]; ps += pv*pv; }
    out[off + (size_t)b*npk + pi] = dot*nk[k]/(sqrtf(ps)+1e-8f)*(1.f/0.07f);
  }
}

extern "C" void kernel_launch(void* const* d_in, const int* in_sizes, int n_in,
                              void* d_out, int out_size, void* d_ws, size_t ws_size,
                              hipStream_t stream) {
  const float* x         = (const float*)d_in[0];
  const float* w_in      = (const float*)d_in[1];
  const float* b_in      = (const float*)d_in[2];
  const float* w_gat     = (const float*)d_in[3];
  const float* a_src     = (const float*)d_in[4];
  const float* a_dst     = (const float*)d_in[5];
  const float* w_out     = (const float*)d_in[6];
  const float* b_out     = (const float*)d_in[7];
  const float* pdm_w     = (const float*)d_in[8];
  const float* pdm_b     = (const float*)d_in[9];
  const float* w_fuse    = (const float*)d_in[10];
  const float* b_fuse    = (const float*)d_in[11];
  const float* ln_w      = (const float*)d_in[12];
  const float* in_proj   = (const float*)d_in[13];
  const float* conv_w    = (const float*)d_in[14];
  const float* conv_b    = (const float*)d_in[15];
  const float* x_proj    = (const float*)d_in[16];
  const float* dt_w      = (const float*)d_in[17];
  const float* dt_b      = (const float*)d_in[18];
  const float* A_log     = (const float*)d_in[19];
  const float* Dvec      = (const float*)d_in[20];
  const float* out_proj  = (const float*)d_in[21];
  const float* w_sign    = (const float*)d_in[22];
  const float* b_sign    = (const float*)d_in[23];
  const float* protos    = (const float*)d_in[24];
  const float* phs       = (const float*)d_in[25];
  const float* ploc      = (const float*)d_in[26];
  const float* pmov      = (const float*)d_in[27];
  const float* pori      = (const float*)d_in[28];
  float* out = (float*)d_out;

  // ---- ws layout ----
  float* wsf = (float*)d_ws;
  const size_t f_xx    = 0;                          // 16384*256
  const size_t f_xdbl  = f_xx   + 4194304;           // 16384*128
  const size_t f_part  = f_xdbl + 2097152;           // 256*256
  const size_t f_end   = f_part + 65536;
  u16* wsu = (u16*)(wsf + f_end);
  const size_t u_xn    = 0;                          // 16384*256
  const size_t u_xz    = u_xn   + 4194304;           // 16384*2048 [u0 u1 z0 z1]; y -> u slots
  const size_t u_ucv   = u_xz   + 33554432;          // 16384*1024
  const size_t u_fsum  = u_ucv  + 16777216;          // 16384*128
  const size_t u_spat  = u_fsum + 2097152;           // 16384*256
  const size_t u_comps = u_spat + 4194304;           // 16384*256
  const size_t u_w     = u_comps+ 4194304;           // 3,850,240 weights
  u16* wiT = wsu + u_w;
  u16* woT = wiT + 2097152;
  u16* wxT = woT + 1048576;
  u16* wA  = wxT + 524288;
  u16* wB  = wA  + 32768;
  u16* wF  = wB  + 65536;
  u16* wBp = wF  + 65536;
  // scan scratch aliases fsum/spat/comps (dead during SSM loop)
  u16*   hstate = wsu + u_fsum;                      // 64*8*2*512*16 u16 = 16MB
  float* sdt    = (float*)(wsu + u_fsum + 8388608);  // 64*8*2*512 f32 = 2MB

  transpose_w_kernel<<<944, 256, 0, stream>>>(in_proj, out_proj, x_proj, w_out, pdm_w, w_fuse, w_gat, wsu + u_w);
  agan_kernel<<<BTT, 256, 0, stream>>>(x, w_in, b_in, wBp, a_src, a_dst, wsu + u_fsum);
  gemm_bm64_kernel<0,1,0,1,0><<<dim3(2,256), 256, 0, stream>>>(wsu+u_fsum, wA, b_out, nullptr, wsu+u_spat, nullptr, BTT, 256, 128, 128);
  gemm_bm64_kernel<0,1,1,1,1><<<dim3(2,256), 256, 0, stream>>>(wsu+u_spat, wB, pdm_b, nullptr, wsu+u_comps, wsf+f_part, BTT, 256, 256, 256);
  gemm_bm64_kernel<0,1,0,0,0><<<dim3(2,256), 256, 0, stream>>>(wsu+u_comps, wF, b_fuse, wsf+f_xx, nullptr, nullptr, BTT, 256, 256, 256);

  for (int l = 0; l < 4; ++l) {
    ln_kernel<<<BTT/4, 256, 0, stream>>>(wsf+f_xx, ln_w + l*DMODEL, wsu+u_xn);
    gemm_bf16_kernel<0,0,0,1><<<dim3(16,128), 256, 0, stream>>>(wsu+u_xn, wiT + (size_t)l*524288,
        nullptr, nullptr, wsu+u_xz, BTT, 2048, 256, 256);
    conv_kernel<<<BTT*128/256, 256, 0, stream>>>(wsu+u_xz, conv_w + (size_t)l*4096,
        conv_b + (size_t)l*1024, wsu+u_ucv);
    gemm_bm64_kernel<0,0,0,0,0><<<dim3(1,256), 256, 0, stream>>>(wsu+u_ucv, wxT + (size_t)l*131072,
        nullptr, wsf+f_xdbl, nullptr, nullptr, BTT, 128, 1024, 1024);
    scan_phase_kernel<0><<<dim3(64,8,4), 256, 0, stream>>>(wsu+u_ucv, wsf+f_xdbl, nullptr,
        dt_w + (size_t)l*16384, dt_b + (size_t)l*1024,
        A_log + (size_t)l*16384, nullptr,
        nullptr, nullptr, sdt, hstate, nullptr);
    scan_phase_kernel<1><<<dim3(64,8,4), 256, 0, stream>>>(wsu+u_ucv, wsf+f_xdbl, wsu+u_xz,
        dt_w + (size_t)l*16384, dt_b + (size_t)l*1024,
        A_log + (size_t)l*16384, Dvec + (size_t)l*1024,
        hstate, sdt, nullptr, nullptr, wsu+u_xz);
    gemm_bm64_kernel<1,0,0,0,0><<<dim3(2,256), 256, 0, stream>>>(wsu+u_xz, woT + (size_t)l*262144,
        nullptr, wsf+f_xx, nullptr, nullptr, BTT, 256, 1024, 2048);
  }

  head_kernel<<<dim3(64,4), 256, 0, stream>>>(wsf+f_xx, w_sign, b_sign, protos, out);
  sims_kernel<<<64, 256, 0, stream>>>(wsf+f_part, phs, ploc, pmov, pori, out);
  (void)in_sizes; (void)n_in; (void)out_size; (void)ws_size;
}